// Round 8
// baseline (769.227 us; speedup 1.0000x reference)
//
#include <hip/hip_runtime.h>
#include <hip/hip_bf16.h>
#include <math.h>

#define BATCH 8192
#define IMG 784   // 28*28
#define KP 800    // fc1 K padded to multiple of 32

typedef short  bf16x8 __attribute__((ext_vector_type(8)));
typedef float  f32x4  __attribute__((ext_vector_type(4)));

// ---------------------------------------------------------------------------
// K0: precompute (a) per-class conv0 one-hot tables T[10][3][784],
// (b) parity-folded deconv1 weights WF4, (c) fc1_w -> bf16 [400][800] padded.
// ---------------------------------------------------------------------------
__global__ __launch_bounds__(256) void precompute_kernel(
    const float* __restrict__ w0,    // [3,11,3,3]
    const float* __restrict__ dw1,   // [3,11,3,3]
    const float* __restrict__ fc1w,  // [400,784]
    float* __restrict__ T,           // [10,3,784]
    float* __restrict__ WF4,         // 576 floats
    __hip_bfloat16* __restrict__ wbf) // [400,800]
{
    const int blk = blockIdx.x, tid = threadIdx.x;
    if (blk < 10) {
        const int t = blk;
        for (int idx = tid; idx < 3 * 784; idx += 256) {
            int o = idx / 784, pix = idx % 784;
            int r = pix / 28, c = pix % 28;
            float acc = 0.f;
#pragma unroll
            for (int dr = 0; dr < 3; ++dr)
#pragma unroll
                for (int dc = 0; dc < 3; ++dc) {
                    int rr = r + dr - 1, cc = c + dc - 1;
                    if (rr < 0 || rr > 27 || cc < 0 || cc > 27) continue;
                    int s = rr * 28 + cc;
                    int i = ((4 * (t + 1 - s)) % 11 + 11) % 11;
                    acc += w0[(o * 11 + i) * 9 + dr * 3 + dc];
                }
            T[(t * 3 + o) * 784 + pix] = acc;
        }
    } else if (blk == 10) {
        // WF4 flat idx = (((par*3+o)*4+uv)*3+cb)*4+j ; channel = 4*cb+j
        for (int idx = tid; idx < 576; idx += 256) {
            int j = idx & 3;
            int rest = idx >> 2;
            int cb = rest % 3;
            int rest2 = rest / 3;
            int uv = rest2 % 4;
            int rest3 = rest2 / 4;
            int o = rest3 % 3;
            int par = rest3 / 3;
            int ch = cb * 4 + j;
            float acc = 0.f;
            if (ch < 11) {
                int u = uv >> 1, v = uv & 1;
                int pr = par >> 1, pc = par & 1;
                for (int dr = 0; dr < 3; ++dr) {
                    bool rin = (pr == 0) ? (u == 0 ? dr == 0 : dr >= 1)
                                         : (u == 0 ? dr <= 1 : dr == 2);
                    if (!rin) continue;
                    for (int dc = 0; dc < 3; ++dc) {
                        bool cin = (pc == 0) ? (v == 0 ? dc == 0 : dc >= 1)
                                             : (v == 0 ? dc <= 1 : dc == 2);
                        if (cin) acc += dw1[(o * 11 + ch) * 9 + dr * 3 + dc];
                    }
                }
            }
            WF4[idx] = acc;
        }
    } else {
        // fc1_w fp32 [400,784] -> bf16 [400,800] (cols 784..799 zero)
        const int base = (blk - 11) * 8000;
        for (int i = tid; i < 8000; i += 256) {
            int flat = base + i;
            int n = flat / KP, k = flat % KP;
            float v = (k < 784) ? fc1w[n * 784 + k] : 0.f;
            wbf[flat] = __float2bfloat16(v);
        }
    }
}

// ---------------------------------------------------------------------------
// K1: encoder — sparse-x conv0 (9 taps) + class table T + conv1 (float4 LDS)
// writes h as bf16 [B][800] (K-padded for MFMA fc1)
// ---------------------------------------------------------------------------
__global__ __launch_bounds__(256, 4) void encoder_kernel(
    const float* __restrict__ x, const int* __restrict__ cls,
    const float* __restrict__ w0,   // [3,11,3,3]
    const float* __restrict__ w1,   // [1,3,3,3]
    const float* __restrict__ T,    // [10,3,784]
    __hip_bfloat16* __restrict__ h_bf)  // [B,800]
{
    __shared__ float  xs[30 * 30];      // scattered x image, zero border
    __shared__ float4 hs0[30 * 30];     // conv0 out (3ch + pad), zero border
    __shared__ float4 wt[99];           // [tap][ch] -> (w_o0, w_o1, w_o2, 0)

    const int b = blockIdx.x, tid = threadIdx.x;
    const int myc = cls[b];

    // border-only zero (interior fully overwritten)
    for (int i = tid; i < 116; i += 256) {
        int r, c;
        if (i < 30)      { r = 0;  c = i; }
        else if (i < 60) { r = 29; c = i - 30; }
        else if (i < 88) { r = 1 + (i - 60); c = 0; }
        else             { r = 1 + (i - 88); c = 29; }
        xs[r * 30 + c] = 0.f;
        hs0[r * 30 + c] = make_float4(0.f, 0.f, 0.f, 0.f);
    }
    for (int i = tid; i < 99; i += 256) {
        int tap = i / 11, ch = i % 11;
        wt[i] = make_float4(w0[ch * 9 + tap], w0[(11 + ch) * 9 + tap],
                            w0[(22 + ch) * 9 + tap], 0.f);
    }
    // scatter x: xs[s] = x value living at spatial position s
    for (int s = tid; s < 784; s += 256) {
        int ch = (7 * s) % 11;
        int p = (ch * 784 + s) / 11;
        xs[(s / 28 + 1) * 30 + s % 28 + 1] = x[(size_t)b * IMG + p];
    }
    // zero the K-pad columns
    if (tid < 16) h_bf[(size_t)b * KP + 784 + tid] = __float2bfloat16(0.f);
    __syncthreads();

    const float* Tc = T + myc * 2352;
    for (int pix = tid; pix < 784; pix += 256) {
        int r = pix / 28, c = pix % 28;
        float a0 = Tc[pix], a1 = Tc[784 + pix], a2 = Tc[1568 + pix];
        int chbase = (9 * r + 7 * c + 6) % 11;
#pragma unroll
        for (int dr = 0; dr < 3; ++dr)
#pragma unroll
            for (int dc = 0; dc < 3; ++dc) {
                const int kk = (9 * dr + 7 * dc) % 11;  // compile-time
                int ch = chbase + kk;
                if (ch >= 11) ch -= 11;
                float v = xs[(r + dr) * 30 + c + dc];
                float4 w = wt[(dr * 3 + dc) * 11 + ch];
                a0 += v * w.x; a1 += v * w.y; a2 += v * w.z;
            }
        hs0[(r + 1) * 30 + c + 1] =
            make_float4(fmaxf(a0, 0.f), fmaxf(a1, 0.f), fmaxf(a2, 0.f), 0.f);
    }
    __syncthreads();

    for (int pix = tid; pix < 784; pix += 256) {
        int r = pix / 28, c = pix % 28;
        float a = 0.f;
#pragma unroll
        for (int dr = 0; dr < 3; ++dr)
#pragma unroll
            for (int dc = 0; dc < 3; ++dc) {
                int t = dr * 3 + dc;
                float4 v = hs0[(r + dr) * 30 + c + dc];
                a += v.x * w1[t] + v.y * w1[9 + t] + v.z * w1[18 + t];
            }
        h_bf[(size_t)b * KP + pix] = __float2bfloat16(fmaxf(a, 0.f));
    }
}

// ---------------------------------------------------------------------------
// K2: fc1 via bf16 MFMA.  h1[8192,400] = relu(h @ w^T + b)
// ---------------------------------------------------------------------------
__global__ __launch_bounds__(256) void fc1_mfma(
    const ushort* __restrict__ h_bf,  // [8192,800] bf16
    const ushort* __restrict__ w_bf,  // [400,800] bf16
    const float* __restrict__ bias,   // [400]
    float* __restrict__ h1)           // [8192,400]
{
    __shared__ ushort Bs[80][40];   // B tile [n][k], stride 40 (pad)

    const int tid  = threadIdx.x;
    const int wid  = tid >> 6;
    const int lane = tid & 63;
    const int l15  = lane & 15;
    const int lq   = lane >> 4;       // k-quadrant 0..3
    const int bm   = blockIdx.x * 128;
    const int bn   = blockIdx.y * 80;

    f32x4 acc[2][5] = {};

    const int n0 = tid >> 2;          // 0..63  (staging row)
    const int kq0 = tid & 3;          // staging k-quadrant

    for (int k0 = 0; k0 < KP; k0 += 32) {
        bf16x8 s0 = *(const bf16x8*)&w_bf[(size_t)(bn + n0) * KP + k0 + kq0 * 8];
        bf16x8 s1;
        if (tid < 64)
            s1 = *(const bf16x8*)&w_bf[(size_t)(bn + 64 + n0) * KP + k0 + kq0 * 8];
        bf16x8 a0 = *(const bf16x8*)&h_bf[(size_t)(bm + wid * 32 + l15) * KP + k0 + lq * 8];
        bf16x8 a1 = *(const bf16x8*)&h_bf[(size_t)(bm + wid * 32 + 16 + l15) * KP + k0 + lq * 8];
        __syncthreads();
        *(bf16x8*)&Bs[n0][kq0 * 8] = s0;
        if (tid < 64) *(bf16x8*)&Bs[64 + n0][kq0 * 8] = s1;
        __syncthreads();
#pragma unroll
        for (int nf = 0; nf < 5; ++nf) {
            bf16x8 bfr = *(const bf16x8*)&Bs[nf * 16 + l15][lq * 8];
            acc[0][nf] = __builtin_amdgcn_mfma_f32_16x16x32_bf16(a0, bfr, acc[0][nf], 0, 0, 0);
            acc[1][nf] = __builtin_amdgcn_mfma_f32_16x16x32_bf16(a1, bfr, acc[1][nf], 0, 0, 0);
        }
    }

#pragma unroll
    for (int nf = 0; nf < 5; ++nf) {
        int col = bn + nf * 16 + l15;
        float bv = bias[col];
#pragma unroll
        for (int mr = 0; mr < 2; ++mr)
#pragma unroll
            for (int v = 0; v < 4; ++v) {
                int row = bm + wid * 32 + mr * 16 + lq * 4 + v;
                h1[(size_t)row * 400 + col] = fmaxf(acc[mr][nf][v] + bv, 0.f);
            }
    }
}

// ---------------------------------------------------------------------------
// K3: fc21 + fc22 fused
// ---------------------------------------------------------------------------
__global__ __launch_bounds__(320) void fc2_kernel(
    const float* __restrict__ h1,
    const float* __restrict__ w21, const float* __restrict__ b21,
    const float* __restrict__ w22, const float* __restrict__ b22,
    float* __restrict__ out)
{
    __shared__ float hs[16 * 400];
    const int b0 = blockIdx.x * 16;
    const int tid = threadIdx.x;

    for (int i = tid; i < 16 * 400; i += 320)
        hs[i] = h1[(size_t)b0 * 400 + i];
    __syncthreads();

    const int row = tid / 20;
    const int j = tid % 20;

    float a1 = b21[j], a2 = b22[j];
    const float4* hrow = (const float4*)&hs[row * 400];
    const float4* wa = (const float4*)&w21[j * 400];
    const float4* wb = (const float4*)&w22[j * 400];
#pragma unroll 4
    for (int k = 0; k < 100; ++k) {
        float4 hv = hrow[k];
        float4 va = wa[k];
        float4 vb = wb[k];
        a1 += hv.x * va.x + hv.y * va.y + hv.z * va.z + hv.w * va.w;
        a2 += hv.x * vb.x + hv.y * vb.y + hv.z * vb.z + hv.w * vb.w;
    }
    size_t base = (size_t)BATCH * IMG;
    out[base + (size_t)(b0 + row) * 20 + j] = a1;
    out[base + (size_t)BATCH * 20 + (size_t)(b0 + row) * 20 + j] = a2;
}

// ---------------------------------------------------------------------------
// K4: decoder — fc3 + deconv0 + wave-parity deconv1 (cb-outer, weight f4
// hoisted to VGPRs, reused across q) + deconv2 + sigmoid
// ---------------------------------------------------------------------------
__global__ __launch_bounds__(256, 4) void decoder_kernel(
    const int* __restrict__ cls,
    const float* __restrict__ fc3_w,  // [392,30]
    const float* __restrict__ fc3_b,  // [392]
    const float* __restrict__ dw0,    // [11,2,3,3]
    const float* __restrict__ dw2,    // [1,3,3,3]
    const float* __restrict__ WF4g,   // 576 floats = 144 float4
    float* __restrict__ out)
{
    __shared__ float  z[32];
    __shared__ float  d0inS[2 * 16 * 17];  // [2][16][17]
    __shared__ float4 d0sp[3][16 * 16];    // per-cblk planes, ch-minor float4
    __shared__ float4 d1s[30 * 30];        // [30][30] (3ch + pad)
    __shared__ float4 we[144];             // WF copy

    const int b = blockIdx.x;
    const int tid = threadIdx.x;
    const int myc = cls[b];
    const float* mu = out + (size_t)BATCH * IMG + (size_t)b * 20;

    // zero d0in fully; d0sp + d1s borders only
    for (int i = tid; i < 2 * 16 * 17; i += 256) d0inS[i] = 0.f;
    for (int i = tid; i < 60; i += 256) {
        int r, c;
        if (i < 16)      { r = 0;  c = i; }
        else if (i < 32) { r = 15; c = i - 16; }
        else if (i < 46) { r = 1 + (i - 32); c = 0; }
        else             { r = 1 + (i - 46); c = 15; }
        int p = r * 16 + c;
        d0sp[0][p] = d0sp[1][p] = d0sp[2][p] = make_float4(0.f, 0.f, 0.f, 0.f);
    }
    for (int i = tid; i < 116; i += 256) {
        int r, c;
        if (i < 30)      { r = 0;  c = i; }
        else if (i < 60) { r = 29; c = i - 30; }
        else if (i < 88) { r = 1 + (i - 60); c = 0; }
        else             { r = 1 + (i - 88); c = 29; }
        d1s[r * 30 + c] = make_float4(0.f, 0.f, 0.f, 0.f);
    }
    for (int i = tid; i < 144; i += 256) we[i] = ((const float4*)WF4g)[i];
    if (tid < 20) z[tid] = mu[tid];
    else if (tid < 30) z[tid] = (tid - 20 == myc) ? 1.f : 0.f;
    __syncthreads();

    // fc3: [30] -> [392] + relu -> d0in [2][16][17] padded
    for (int j = tid; j < 392; j += 256) {
        float acc = fc3_b[j];
        const float2* wrow = (const float2*)&fc3_w[j * 30];
#pragma unroll
        for (int k = 0; k < 15; ++k) {
            float2 wv = wrow[k];
            acc += z[2 * k] * wv.x + z[2 * k + 1] * wv.y;
        }
        int ch = j / 196, rem = j % 196;
        d0inS[ch * 272 + (rem / 14 + 1) * 17 + (rem % 14 + 1)] = fmaxf(acc, 0.f);
    }
    __syncthreads();

    // deconv0: one thread per position, all 11 channels; weights -> s_loads
    if (tid < 196) {
        int r = tid / 14, c = tid % 14;
        float a[12] = {};
#pragma unroll
        for (int i = 0; i < 2; ++i)
#pragma unroll
            for (int dr = 0; dr < 3; ++dr)
#pragma unroll
                for (int dc = 0; dc < 3; ++dc) {
                    float v = d0inS[i * 272 + (r + dr) * 17 + (c + dc)];
#pragma unroll
                    for (int o = 0; o < 11; ++o)
                        a[o] += v * dw0[((o * 2 + i) * 3 + dr) * 3 + dc];
                }
        int p = (r + 1) * 16 + (c + 1);
        d0sp[0][p] = make_float4(fmaxf(a[0], 0.f), fmaxf(a[1], 0.f),
                                 fmaxf(a[2], 0.f), fmaxf(a[3], 0.f));
        d0sp[1][p] = make_float4(fmaxf(a[4], 0.f), fmaxf(a[5], 0.f),
                                 fmaxf(a[6], 0.f), fmaxf(a[7], 0.f));
        d0sp[2][p] = make_float4(fmaxf(a[8], 0.f), fmaxf(a[9], 0.f),
                                 fmaxf(a[10], 0.f), 0.f);
    }
    __syncthreads();

    // deconv1: wave w owns parity w. cb-outer; 12 weight float4 hoisted to
    // VGPRs per cb and reused across all 4 q-iterations.
    // LDS reads/lane: 36 weight + 48 window (was 192).
    {
        const int wid  = tid >> 6;
        const int lane = tid & 63;
        const int pr = wid >> 1, pc = wid & 1;
        const float4* wbase = &we[wid * 36];

        float accq[4][3] = {};
        int base0[4];
        bool val[4];
#pragma unroll
        for (int p = 0; p < 4; ++p) {
            int q = p * 64 + lane;
            val[p] = (q < 196);
            int qr = q / 14, qc = q - qr * 14;
            base0[p] = (qr + pr) * 16 + qc + pc;
        }
#pragma unroll
        for (int cb = 0; cb < 3; ++cb) {
            float4 W[12];  // j = o*4 + uv
#pragma unroll
            for (int j = 0; j < 12; ++j)
                W[j] = wbase[j * 3 + cb];
#pragma unroll
            for (int p = 0; p < 4; ++p) {
                if (!val[p]) continue;
                int b0 = base0[p];
                float4 v00 = d0sp[cb][b0],      v01 = d0sp[cb][b0 + 1];
                float4 v10 = d0sp[cb][b0 + 16], v11 = d0sp[cb][b0 + 17];
#pragma unroll
                for (int o = 0; o < 3; ++o)
                    accq[p][o] +=
                        v00.x * W[o * 4 + 0].x + v00.y * W[o * 4 + 0].y +
                        v00.z * W[o * 4 + 0].z + v00.w * W[o * 4 + 0].w +
                        v01.x * W[o * 4 + 1].x + v01.y * W[o * 4 + 1].y +
                        v01.z * W[o * 4 + 1].z + v01.w * W[o * 4 + 1].w +
                        v10.x * W[o * 4 + 2].x + v10.y * W[o * 4 + 2].y +
                        v10.z * W[o * 4 + 2].z + v10.w * W[o * 4 + 2].w +
                        v11.x * W[o * 4 + 3].x + v11.y * W[o * 4 + 3].y +
                        v11.z * W[o * 4 + 3].z + v11.w * W[o * 4 + 3].w;
            }
        }
#pragma unroll
        for (int p = 0; p < 4; ++p) {
            if (val[p]) {
                int q = p * 64 + lane;
                int qr = q / 14, qc = q - qr * 14;
                int r = 2 * qr + pr, c = 2 * qc + pc;
                d1s[(r + 1) * 30 + c + 1] =
                    make_float4(fmaxf(accq[p][0], 0.f), fmaxf(accq[p][1], 0.f),
                                fmaxf(accq[p][2], 0.f), 0.f);
            }
        }
    }
    __syncthreads();

    // deconv2 (3->1) + sigmoid
    for (int pix = tid; pix < 784; pix += 256) {
        int r = pix / 28, c = pix % 28;
        float a = 0.f;
#pragma unroll
        for (int dr = 0; dr < 3; ++dr)
#pragma unroll
            for (int dc = 0; dc < 3; ++dc) {
                int t = dr * 3 + dc;
                float4 v = d1s[(r + dr) * 30 + c + dc];
                a += v.x * dw2[t] + v.y * dw2[9 + t] + v.z * dw2[18 + t];
            }
        out[(size_t)b * IMG + pix] = 1.f / (1.f + expf(-a));
    }
}

// ---------------------------------------------------------------------------
extern "C" void kernel_launch(void* const* d_in, const int* in_sizes, int n_in,
                              void* d_out, int out_size, void* d_ws, size_t ws_size,
                              hipStream_t stream) {
    const float* x     = (const float*)d_in[0];
    const int*   cls   = (const int*)d_in[1];
    const float* w0    = (const float*)d_in[2];
    const float* w1    = (const float*)d_in[3];
    const float* fc1_w = (const float*)d_in[4];
    const float* fc1_b = (const float*)d_in[5];
    const float* w21   = (const float*)d_in[6];
    const float* b21   = (const float*)d_in[7];
    const float* w22   = (const float*)d_in[8];
    const float* b22   = (const float*)d_in[9];
    const float* fc3_w = (const float*)d_in[10];
    const float* fc3_b = (const float*)d_in[11];
    const float* dw0   = (const float*)d_in[12];
    const float* dw1   = (const float*)d_in[13];
    const float* dw2   = (const float*)d_in[14];

    float* out = (float*)d_out;
    char*  ws  = (char*)d_ws;
    __hip_bfloat16* h_bf = (__hip_bfloat16*)ws;
    float* h1   = (float*)(ws + (size_t)BATCH * KP * 2);
    float* T    = h1 + (size_t)BATCH * 400;
    float* WF4  = T + 10 * 3 * 784;
    __hip_bfloat16* w_bf = (__hip_bfloat16*)(WF4 + 576);

    precompute_kernel<<<51, 256, 0, stream>>>(w0, dw1, fc1_w, T, WF4, w_bf);
    encoder_kernel<<<BATCH, 256, 0, stream>>>(x, cls, w0, w1, T, h_bf);
    fc1_mfma<<<dim3(64, 5), 256, 0, stream>>>((const ushort*)h_bf,
                                              (const ushort*)w_bf, fc1_b, h1);
    fc2_kernel<<<BATCH / 16, 320, 0, stream>>>(h1, w21, b21, w22, b22, out);
    decoder_kernel<<<BATCH, 256, 0, stream>>>(cls, fc3_w, fc3_b, dw0, dw2, WF4, out);
}

// Round 9
// 208.058 us; speedup vs baseline: 3.6972x; 3.6972x over previous
//
#include <hip/hip_runtime.h>
#include <hip/hip_bf16.h>
#include <math.h>

#define BATCH 8192
#define IMG 784   // 28*28
#define KP 800    // fc1 K padded to multiple of 32

typedef short  bf16x8 __attribute__((ext_vector_type(8)));
typedef float  f32x4  __attribute__((ext_vector_type(4)));

// ---------------------------------------------------------------------------
// K0: precompute (a) per-class conv0 one-hot tables T[10][3][784],
// (b) parity-folded deconv1 weights WF4, (c) fc1_w -> bf16 [400][800] padded.
// ---------------------------------------------------------------------------
__global__ __launch_bounds__(256) void precompute_kernel(
    const float* __restrict__ w0,    // [3,11,3,3]
    const float* __restrict__ dw1,   // [3,11,3,3]
    const float* __restrict__ fc1w,  // [400,784]
    float* __restrict__ T,           // [10,3,784]
    float* __restrict__ WF4,         // 576 floats
    __hip_bfloat16* __restrict__ wbf) // [400,800]
{
    const int blk = blockIdx.x, tid = threadIdx.x;
    if (blk < 10) {
        const int t = blk;
        for (int idx = tid; idx < 3 * 784; idx += 256) {
            int o = idx / 784, pix = idx % 784;
            int r = pix / 28, c = pix % 28;
            float acc = 0.f;
#pragma unroll
            for (int dr = 0; dr < 3; ++dr)
#pragma unroll
                for (int dc = 0; dc < 3; ++dc) {
                    int rr = r + dr - 1, cc = c + dc - 1;
                    if (rr < 0 || rr > 27 || cc < 0 || cc > 27) continue;
                    int s = rr * 28 + cc;
                    int i = ((4 * (t + 1 - s)) % 11 + 11) % 11;
                    acc += w0[(o * 11 + i) * 9 + dr * 3 + dc];
                }
            T[(t * 3 + o) * 784 + pix] = acc;
        }
    } else if (blk == 10) {
        // WF4 flat idx = (((par*3+o)*4+uv)*3+cb)*4+j ; channel = 4*cb+j
        for (int idx = tid; idx < 576; idx += 256) {
            int j = idx & 3;
            int rest = idx >> 2;
            int cb = rest % 3;
            int rest2 = rest / 3;
            int uv = rest2 % 4;
            int rest3 = rest2 / 4;
            int o = rest3 % 3;
            int par = rest3 / 3;
            int ch = cb * 4 + j;
            float acc = 0.f;
            if (ch < 11) {
                int u = uv >> 1, v = uv & 1;
                int pr = par >> 1, pc = par & 1;
                for (int dr = 0; dr < 3; ++dr) {
                    bool rin = (pr == 0) ? (u == 0 ? dr == 0 : dr >= 1)
                                         : (u == 0 ? dr <= 1 : dr == 2);
                    if (!rin) continue;
                    for (int dc = 0; dc < 3; ++dc) {
                        bool cin = (pc == 0) ? (v == 0 ? dc == 0 : dc >= 1)
                                             : (v == 0 ? dc <= 1 : dc == 2);
                        if (cin) acc += dw1[(o * 11 + ch) * 9 + dr * 3 + dc];
                    }
                }
            }
            WF4[idx] = acc;
        }
    } else {
        // fc1_w fp32 [400,784] -> bf16 [400,800] (cols 784..799 zero)
        const int base = (blk - 11) * 8000;
        for (int i = tid; i < 8000; i += 256) {
            int flat = base + i;
            int n = flat / KP, k = flat % KP;
            float v = (k < 784) ? fc1w[n * 784 + k] : 0.f;
            wbf[flat] = __float2bfloat16(v);
        }
    }
}

// ---------------------------------------------------------------------------
// K1: encoder — sparse-x conv0 (9 taps) + class table T + conv1 (float4 LDS)
// writes h as bf16 [B][800] (K-padded for MFMA fc1)
// ---------------------------------------------------------------------------
__global__ __launch_bounds__(256, 4) void encoder_kernel(
    const float* __restrict__ x, const int* __restrict__ cls,
    const float* __restrict__ w0,   // [3,11,3,3]
    const float* __restrict__ w1,   // [1,3,3,3]
    const float* __restrict__ T,    // [10,3,784]
    __hip_bfloat16* __restrict__ h_bf)  // [B,800]
{
    __shared__ float  xs[30 * 30];      // scattered x image, zero border
    __shared__ float4 hs0[30 * 30];     // conv0 out (3ch + pad), zero border
    __shared__ float4 wt[99];           // [tap][ch] -> (w_o0, w_o1, w_o2, 0)

    const int b = blockIdx.x, tid = threadIdx.x;
    const int myc = cls[b];

    // border-only zero (interior fully overwritten)
    for (int i = tid; i < 116; i += 256) {
        int r, c;
        if (i < 30)      { r = 0;  c = i; }
        else if (i < 60) { r = 29; c = i - 30; }
        else if (i < 88) { r = 1 + (i - 60); c = 0; }
        else             { r = 1 + (i - 88); c = 29; }
        xs[r * 30 + c] = 0.f;
        hs0[r * 30 + c] = make_float4(0.f, 0.f, 0.f, 0.f);
    }
    for (int i = tid; i < 99; i += 256) {
        int tap = i / 11, ch = i % 11;
        wt[i] = make_float4(w0[ch * 9 + tap], w0[(11 + ch) * 9 + tap],
                            w0[(22 + ch) * 9 + tap], 0.f);
    }
    // scatter x: xs[s] = x value living at spatial position s
    for (int s = tid; s < 784; s += 256) {
        int ch = (7 * s) % 11;
        int p = (ch * 784 + s) / 11;
        xs[(s / 28 + 1) * 30 + s % 28 + 1] = x[(size_t)b * IMG + p];
    }
    // zero the K-pad columns
    if (tid < 16) h_bf[(size_t)b * KP + 784 + tid] = __float2bfloat16(0.f);
    __syncthreads();

    const float* Tc = T + myc * 2352;
    for (int pix = tid; pix < 784; pix += 256) {
        int r = pix / 28, c = pix % 28;
        float a0 = Tc[pix], a1 = Tc[784 + pix], a2 = Tc[1568 + pix];
        int chbase = (9 * r + 7 * c + 6) % 11;
#pragma unroll
        for (int dr = 0; dr < 3; ++dr)
#pragma unroll
            for (int dc = 0; dc < 3; ++dc) {
                const int kk = (9 * dr + 7 * dc) % 11;  // compile-time
                int ch = chbase + kk;
                if (ch >= 11) ch -= 11;
                float v = xs[(r + dr) * 30 + c + dc];
                float4 w = wt[(dr * 3 + dc) * 11 + ch];
                a0 += v * w.x; a1 += v * w.y; a2 += v * w.z;
            }
        hs0[(r + 1) * 30 + c + 1] =
            make_float4(fmaxf(a0, 0.f), fmaxf(a1, 0.f), fmaxf(a2, 0.f), 0.f);
    }
    __syncthreads();

    for (int pix = tid; pix < 784; pix += 256) {
        int r = pix / 28, c = pix % 28;
        float a = 0.f;
#pragma unroll
        for (int dr = 0; dr < 3; ++dr)
#pragma unroll
            for (int dc = 0; dc < 3; ++dc) {
                int t = dr * 3 + dc;
                float4 v = hs0[(r + dr) * 30 + c + dc];
                a += v.x * w1[t] + v.y * w1[9 + t] + v.z * w1[18 + t];
            }
        h_bf[(size_t)b * KP + pix] = __float2bfloat16(fmaxf(a, 0.f));
    }
}

// ---------------------------------------------------------------------------
// K2: fc1 via bf16 MFMA.  h1[8192,400] = relu(h @ w^T + b)
// ---------------------------------------------------------------------------
__global__ __launch_bounds__(256) void fc1_mfma(
    const ushort* __restrict__ h_bf,  // [8192,800] bf16
    const ushort* __restrict__ w_bf,  // [400,800] bf16
    const float* __restrict__ bias,   // [400]
    float* __restrict__ h1)           // [8192,400]
{
    __shared__ ushort Bs[80][40];   // B tile [n][k], stride 40 (pad)

    const int tid  = threadIdx.x;
    const int wid  = tid >> 6;
    const int lane = tid & 63;
    const int l15  = lane & 15;
    const int lq   = lane >> 4;       // k-quadrant 0..3
    const int bm   = blockIdx.x * 128;
    const int bn   = blockIdx.y * 80;

    f32x4 acc[2][5] = {};

    const int n0 = tid >> 2;          // 0..63  (staging row)
    const int kq0 = tid & 3;          // staging k-quadrant

    for (int k0 = 0; k0 < KP; k0 += 32) {
        bf16x8 s0 = *(const bf16x8*)&w_bf[(size_t)(bn + n0) * KP + k0 + kq0 * 8];
        bf16x8 s1;
        if (tid < 64)
            s1 = *(const bf16x8*)&w_bf[(size_t)(bn + 64 + n0) * KP + k0 + kq0 * 8];
        bf16x8 a0 = *(const bf16x8*)&h_bf[(size_t)(bm + wid * 32 + l15) * KP + k0 + lq * 8];
        bf16x8 a1 = *(const bf16x8*)&h_bf[(size_t)(bm + wid * 32 + 16 + l15) * KP + k0 + lq * 8];
        __syncthreads();
        *(bf16x8*)&Bs[n0][kq0 * 8] = s0;
        if (tid < 64) *(bf16x8*)&Bs[64 + n0][kq0 * 8] = s1;
        __syncthreads();
#pragma unroll
        for (int nf = 0; nf < 5; ++nf) {
            bf16x8 bfr = *(const bf16x8*)&Bs[nf * 16 + l15][lq * 8];
            acc[0][nf] = __builtin_amdgcn_mfma_f32_16x16x32_bf16(a0, bfr, acc[0][nf], 0, 0, 0);
            acc[1][nf] = __builtin_amdgcn_mfma_f32_16x16x32_bf16(a1, bfr, acc[1][nf], 0, 0, 0);
        }
    }

#pragma unroll
    for (int nf = 0; nf < 5; ++nf) {
        int col = bn + nf * 16 + l15;
        float bv = bias[col];
#pragma unroll
        for (int mr = 0; mr < 2; ++mr)
#pragma unroll
            for (int v = 0; v < 4; ++v) {
                int row = bm + wid * 32 + mr * 16 + lq * 4 + v;
                h1[(size_t)row * 400 + col] = fmaxf(acc[mr][nf][v] + bv, 0.f);
            }
    }
}

// ---------------------------------------------------------------------------
// K3: fc21 + fc22 fused
// ---------------------------------------------------------------------------
__global__ __launch_bounds__(320) void fc2_kernel(
    const float* __restrict__ h1,
    const float* __restrict__ w21, const float* __restrict__ b21,
    const float* __restrict__ w22, const float* __restrict__ b22,
    float* __restrict__ out)
{
    __shared__ float hs[16 * 400];
    const int b0 = blockIdx.x * 16;
    const int tid = threadIdx.x;

    for (int i = tid; i < 16 * 400; i += 320)
        hs[i] = h1[(size_t)b0 * 400 + i];
    __syncthreads();

    const int row = tid / 20;
    const int j = tid % 20;

    float a1 = b21[j], a2 = b22[j];
    const float4* hrow = (const float4*)&hs[row * 400];
    const float4* wa = (const float4*)&w21[j * 400];
    const float4* wb = (const float4*)&w22[j * 400];
#pragma unroll 4
    for (int k = 0; k < 100; ++k) {
        float4 hv = hrow[k];
        float4 va = wa[k];
        float4 vb = wb[k];
        a1 += hv.x * va.x + hv.y * va.y + hv.z * va.z + hv.w * va.w;
        a2 += hv.x * vb.x + hv.y * vb.y + hv.z * vb.z + hv.w * vb.w;
    }
    size_t base = (size_t)BATCH * IMG;
    out[base + (size_t)(b0 + row) * 20 + j] = a1;
    out[base + (size_t)BATCH * 20 + (size_t)(b0 + row) * 20 + j] = a2;
}

// ---------------------------------------------------------------------------
// K4: decoder — fc3 + deconv0 + wave-parity deconv1 (vertical q-pairs:
// shared middle window row, weights re-read as LDS broadcasts) + deconv2
// ---------------------------------------------------------------------------
__global__ __launch_bounds__(256, 4) void decoder_kernel(
    const int* __restrict__ cls,
    const float* __restrict__ fc3_w,  // [392,30]
    const float* __restrict__ fc3_b,  // [392]
    const float* __restrict__ dw0,    // [11,2,3,3]
    const float* __restrict__ dw2,    // [1,3,3,3]
    const float* __restrict__ WF4g,   // 576 floats = 144 float4
    float* __restrict__ out)
{
    __shared__ float  z[32];
    __shared__ float  d0inS[2 * 16 * 17];  // [2][16][17]
    __shared__ float4 d0sp[3][16 * 16];    // per-cblk planes, ch-minor float4
    __shared__ float4 d1s[30 * 30];        // [30][30] (3ch + pad)
    __shared__ float4 we[144];             // WF copy

    const int b = blockIdx.x;
    const int tid = threadIdx.x;
    const int myc = cls[b];
    const float* mu = out + (size_t)BATCH * IMG + (size_t)b * 20;

    // zero d0in fully; d0sp + d1s borders only
    for (int i = tid; i < 2 * 16 * 17; i += 256) d0inS[i] = 0.f;
    for (int i = tid; i < 60; i += 256) {
        int r, c;
        if (i < 16)      { r = 0;  c = i; }
        else if (i < 32) { r = 15; c = i - 16; }
        else if (i < 46) { r = 1 + (i - 32); c = 0; }
        else             { r = 1 + (i - 46); c = 15; }
        int p = r * 16 + c;
        d0sp[0][p] = d0sp[1][p] = d0sp[2][p] = make_float4(0.f, 0.f, 0.f, 0.f);
    }
    for (int i = tid; i < 116; i += 256) {
        int r, c;
        if (i < 30)      { r = 0;  c = i; }
        else if (i < 60) { r = 29; c = i - 30; }
        else if (i < 88) { r = 1 + (i - 60); c = 0; }
        else             { r = 1 + (i - 88); c = 29; }
        d1s[r * 30 + c] = make_float4(0.f, 0.f, 0.f, 0.f);
    }
    for (int i = tid; i < 144; i += 256) we[i] = ((const float4*)WF4g)[i];
    if (tid < 20) z[tid] = mu[tid];
    else if (tid < 30) z[tid] = (tid - 20 == myc) ? 1.f : 0.f;
    __syncthreads();

    // fc3: [30] -> [392] + relu -> d0in [2][16][17] padded
    for (int j = tid; j < 392; j += 256) {
        float acc = fc3_b[j];
        const float2* wrow = (const float2*)&fc3_w[j * 30];
#pragma unroll
        for (int k = 0; k < 15; ++k) {
            float2 wv = wrow[k];
            acc += z[2 * k] * wv.x + z[2 * k + 1] * wv.y;
        }
        int ch = j / 196, rem = j % 196;
        d0inS[ch * 272 + (rem / 14 + 1) * 17 + (rem % 14 + 1)] = fmaxf(acc, 0.f);
    }
    __syncthreads();

    // deconv0: one thread per position, all 11 channels; weights -> s_loads
    if (tid < 196) {
        int r = tid / 14, c = tid % 14;
        float a[12] = {};
#pragma unroll
        for (int i = 0; i < 2; ++i)
#pragma unroll
            for (int dr = 0; dr < 3; ++dr)
#pragma unroll
                for (int dc = 0; dc < 3; ++dc) {
                    float v = d0inS[i * 272 + (r + dr) * 17 + (c + dc)];
#pragma unroll
                    for (int o = 0; o < 11; ++o)
                        a[o] += v * dw0[((o * 2 + i) * 3 + dr) * 3 + dc];
                }
        int p = (r + 1) * 16 + (c + 1);
        d0sp[0][p] = make_float4(fmaxf(a[0], 0.f), fmaxf(a[1], 0.f),
                                 fmaxf(a[2], 0.f), fmaxf(a[3], 0.f));
        d0sp[1][p] = make_float4(fmaxf(a[4], 0.f), fmaxf(a[5], 0.f),
                                 fmaxf(a[6], 0.f), fmaxf(a[7], 0.f));
        d0sp[2][p] = make_float4(fmaxf(a[8], 0.f), fmaxf(a[9], 0.f),
                                 fmaxf(a[10], 0.f), 0.f);
    }
    __syncthreads();

    // deconv1: wave w owns parity w. Vertical q-pair per thread:
    // q0=(2*qpr, qc), q1=(2*qpr+1, qc) share the middle window row ->
    // 6 window b128 reads per cb per pair (vs 8); weight reads are
    // wave-uniform LDS broadcasts. 98 pairs over 2 lane-iterations.
    {
        const int wid  = tid >> 6;          // parity, wave-uniform
        const int lane = tid & 63;
        const int pr = wid >> 1, pc = wid & 1;
        const float4* wbase = &we[wid * 36];
#pragma unroll 1
        for (int pp = 0; pp < 2; ++pp) {
            int pi = pp * 64 + lane;
            if (pi < 98) {
                int qpr = pi / 14, qc = pi - qpr * 14;
                int qr0 = qpr * 2;
                int base = (qr0 + pr) * 16 + qc + pc;
                float a00 = 0.f, a01 = 0.f, a02 = 0.f;
                float a10 = 0.f, a11 = 0.f, a12 = 0.f;
#pragma unroll
                for (int cb = 0; cb < 3; ++cb) {
                    float4 v0 = d0sp[cb][base];
                    float4 v1 = d0sp[cb][base + 1];
                    float4 v2 = d0sp[cb][base + 16];
                    float4 v3 = d0sp[cb][base + 17];
                    float4 v4 = d0sp[cb][base + 32];
                    float4 v5 = d0sp[cb][base + 33];
#pragma unroll
                    for (int o = 0; o < 3; ++o) {
                        float4 w00 = wbase[(o * 4 + 0) * 3 + cb];
                        float4 w01 = wbase[(o * 4 + 1) * 3 + cb];
                        float4 w10 = wbase[(o * 4 + 2) * 3 + cb];
                        float4 w11 = wbase[(o * 4 + 3) * 3 + cb];
                        float s0 = v0.x * w00.x + v0.y * w00.y +
                                   v0.z * w00.z + v0.w * w00.w +
                                   v1.x * w01.x + v1.y * w01.y +
                                   v1.z * w01.z + v1.w * w01.w +
                                   v2.x * w10.x + v2.y * w10.y +
                                   v2.z * w10.z + v2.w * w10.w +
                                   v3.x * w11.x + v3.y * w11.y +
                                   v3.z * w11.z + v3.w * w11.w;
                        float s1 = v2.x * w00.x + v2.y * w00.y +
                                   v2.z * w00.z + v2.w * w00.w +
                                   v3.x * w01.x + v3.y * w01.y +
                                   v3.z * w01.z + v3.w * w01.w +
                                   v4.x * w10.x + v4.y * w10.y +
                                   v4.z * w10.z + v4.w * w10.w +
                                   v5.x * w11.x + v5.y * w11.y +
                                   v5.z * w11.z + v5.w * w11.w;
                        if (o == 0)      { a00 += s0; a10 += s1; }
                        else if (o == 1) { a01 += s0; a11 += s1; }
                        else             { a02 += s0; a12 += s1; }
                    }
                }
                int r0 = 2 * qr0 + pr, c = 2 * qc + pc;
                d1s[(r0 + 1) * 30 + c + 1] =
                    make_float4(fmaxf(a00, 0.f), fmaxf(a01, 0.f),
                                fmaxf(a02, 0.f), 0.f);
                d1s[(r0 + 3) * 30 + c + 1] =
                    make_float4(fmaxf(a10, 0.f), fmaxf(a11, 0.f),
                                fmaxf(a12, 0.f), 0.f);
            }
        }
    }
    __syncthreads();

    // deconv2 (3->1) + sigmoid
    for (int pix = tid; pix < 784; pix += 256) {
        int r = pix / 28, c = pix % 28;
        float a = 0.f;
#pragma unroll
        for (int dr = 0; dr < 3; ++dr)
#pragma unroll
            for (int dc = 0; dc < 3; ++dc) {
                int t = dr * 3 + dc;
                float4 v = d1s[(r + dr) * 30 + c + dc];
                a += v.x * dw2[t] + v.y * dw2[9 + t] + v.z * dw2[18 + t];
            }
        out[(size_t)b * IMG + pix] = 1.f / (1.f + expf(-a));
    }
}

// ---------------------------------------------------------------------------
extern "C" void kernel_launch(void* const* d_in, const int* in_sizes, int n_in,
                              void* d_out, int out_size, void* d_ws, size_t ws_size,
                              hipStream_t stream) {
    const float* x     = (const float*)d_in[0];
    const int*   cls   = (const int*)d_in[1];
    const float* w0    = (const float*)d_in[2];
    const float* w1    = (const float*)d_in[3];
    const float* fc1_w = (const float*)d_in[4];
    const float* fc1_b = (const float*)d_in[5];
    const float* w21   = (const float*)d_in[6];
    const float* b21   = (const float*)d_in[7];
    const float* w22   = (const float*)d_in[8];
    const float* b22   = (const float*)d_in[9];
    const float* fc3_w = (const float*)d_in[10];
    const float* fc3_b = (const float*)d_in[11];
    const float* dw0   = (const float*)d_in[12];
    const float* dw1   = (const float*)d_in[13];
    const float* dw2   = (const float*)d_in[14];

    float* out = (float*)d_out;
    char*  ws  = (char*)d_ws;
    __hip_bfloat16* h_bf = (__hip_bfloat16*)ws;
    float* h1   = (float*)(ws + (size_t)BATCH * KP * 2);
    float* T    = h1 + (size_t)BATCH * 400;
    float* WF4  = T + 10 * 3 * 784;
    __hip_bfloat16* w_bf = (__hip_bfloat16*)(WF4 + 576);

    precompute_kernel<<<51, 256, 0, stream>>>(w0, dw1, fc1_w, T, WF4, w_bf);
    encoder_kernel<<<BATCH, 256, 0, stream>>>(x, cls, w0, w1, T, h_bf);
    fc1_mfma<<<dim3(64, 5), 256, 0, stream>>>((const ushort*)h_bf,
                                              (const ushort*)w_bf, fc1_b, h1);
    fc2_kernel<<<BATCH / 16, 320, 0, stream>>>(h1, w21, b21, w22, b22, out);
    decoder_kernel<<<BATCH, 256, 0, stream>>>(cls, fc3_w, fc3_b, dw0, dw2, WF4, out);
}

// Round 10
// 183.436 us; speedup vs baseline: 4.1934x; 1.1342x over previous
//
#include <hip/hip_runtime.h>
#include <hip/hip_bf16.h>
#include <math.h>

#define BATCH 8192
#define IMG 784   // 28*28
#define KP 800    // fc1 K padded to multiple of 32
#define KP2 416   // fc2 K padded (400 -> 416)

typedef short  bf16x8 __attribute__((ext_vector_type(8)));
typedef float  f32x4  __attribute__((ext_vector_type(4)));

// ---------------------------------------------------------------------------
// K0: precompute (a) per-class conv0 one-hot tables T[10][3][784],
// (b) parity-folded deconv1 weights WF4, (c) fc1_w -> bf16 [400][800],
// (d) fc2 weights [w21;w22;0] -> bf16 [48][416].
// ---------------------------------------------------------------------------
__global__ __launch_bounds__(256) void precompute_kernel(
    const float* __restrict__ w0,    // [3,11,3,3]
    const float* __restrict__ dw1,   // [3,11,3,3]
    const float* __restrict__ fc1w,  // [400,784]
    const float* __restrict__ w21,   // [20,400]
    const float* __restrict__ w22,   // [20,400]
    float* __restrict__ T,           // [10,3,784]
    float* __restrict__ WF4,         // 576 floats
    __hip_bfloat16* __restrict__ wbf,  // [400,800]
    __hip_bfloat16* __restrict__ w2bf) // [48,416]
{
    const int blk = blockIdx.x, tid = threadIdx.x;
    if (blk < 10) {
        const int t = blk;
        for (int idx = tid; idx < 3 * 784; idx += 256) {
            int o = idx / 784, pix = idx % 784;
            int r = pix / 28, c = pix % 28;
            float acc = 0.f;
#pragma unroll
            for (int dr = 0; dr < 3; ++dr)
#pragma unroll
                for (int dc = 0; dc < 3; ++dc) {
                    int rr = r + dr - 1, cc = c + dc - 1;
                    if (rr < 0 || rr > 27 || cc < 0 || cc > 27) continue;
                    int s = rr * 28 + cc;
                    int i = ((4 * (t + 1 - s)) % 11 + 11) % 11;
                    acc += w0[(o * 11 + i) * 9 + dr * 3 + dc];
                }
            T[(t * 3 + o) * 784 + pix] = acc;
        }
    } else if (blk == 10) {
        // WF4 flat idx = (((par*3+o)*4+uv)*3+cb)*4+j ; channel = 4*cb+j
        for (int idx = tid; idx < 576; idx += 256) {
            int j = idx & 3;
            int rest = idx >> 2;
            int cb = rest % 3;
            int rest2 = rest / 3;
            int uv = rest2 % 4;
            int rest3 = rest2 / 4;
            int o = rest3 % 3;
            int par = rest3 / 3;
            int ch = cb * 4 + j;
            float acc = 0.f;
            if (ch < 11) {
                int u = uv >> 1, v = uv & 1;
                int pr = par >> 1, pc = par & 1;
                for (int dr = 0; dr < 3; ++dr) {
                    bool rin = (pr == 0) ? (u == 0 ? dr == 0 : dr >= 1)
                                         : (u == 0 ? dr <= 1 : dr == 2);
                    if (!rin) continue;
                    for (int dc = 0; dc < 3; ++dc) {
                        bool cin = (pc == 0) ? (v == 0 ? dc == 0 : dc >= 1)
                                             : (v == 0 ? dc <= 1 : dc == 2);
                        if (cin) acc += dw1[(o * 11 + ch) * 9 + dr * 3 + dc];
                    }
                }
            }
            WF4[idx] = acc;
        }
    } else if (blk < 51) {
        // fc1_w fp32 [400,784] -> bf16 [400,800] (cols 784..799 zero)
        const int base = (blk - 11) * 8000;
        for (int i = tid; i < 8000; i += 256) {
            int flat = base + i;
            int n = flat / KP, k = flat % KP;
            float v = (k < 784) ? fc1w[n * 784 + k] : 0.f;
            wbf[flat] = __float2bfloat16(v);
        }
    } else {
        // fc2 weights -> bf16 [48,416]: rows 0-19 w21, 20-39 w22, 40-47 zero
        const int base = (blk - 51) * 2496;   // 8 blocks x 2496 = 19968
        for (int i = tid; i < 2496; i += 256) {
            int flat = base + i;
            int j = flat / KP2, k = flat % KP2;
            float v = 0.f;
            if (k < 400) {
                if (j < 20)      v = w21[j * 400 + k];
                else if (j < 40) v = w22[(j - 20) * 400 + k];
            }
            w2bf[flat] = __float2bfloat16(v);
        }
    }
}

// ---------------------------------------------------------------------------
// K1: encoder — sparse-x conv0 (9 taps) + class table T + conv1 (float4 LDS)
// writes h as bf16 [B][800] (K-padded for MFMA fc1)
// ---------------------------------------------------------------------------
__global__ __launch_bounds__(256, 4) void encoder_kernel(
    const float* __restrict__ x, const int* __restrict__ cls,
    const float* __restrict__ w0,   // [3,11,3,3]
    const float* __restrict__ w1,   // [1,3,3,3]
    const float* __restrict__ T,    // [10,3,784]
    __hip_bfloat16* __restrict__ h_bf)  // [B,800]
{
    __shared__ float  xs[30 * 30];      // scattered x image, zero border
    __shared__ float4 hs0[30 * 30];     // conv0 out (3ch + pad), zero border
    __shared__ float4 wt[99];           // [tap][ch] -> (w_o0, w_o1, w_o2, 0)

    const int b = blockIdx.x, tid = threadIdx.x;
    const int myc = cls[b];

    // border-only zero (interior fully overwritten)
    for (int i = tid; i < 116; i += 256) {
        int r, c;
        if (i < 30)      { r = 0;  c = i; }
        else if (i < 60) { r = 29; c = i - 30; }
        else if (i < 88) { r = 1 + (i - 60); c = 0; }
        else             { r = 1 + (i - 88); c = 29; }
        xs[r * 30 + c] = 0.f;
        hs0[r * 30 + c] = make_float4(0.f, 0.f, 0.f, 0.f);
    }
    for (int i = tid; i < 99; i += 256) {
        int tap = i / 11, ch = i % 11;
        wt[i] = make_float4(w0[ch * 9 + tap], w0[(11 + ch) * 9 + tap],
                            w0[(22 + ch) * 9 + tap], 0.f);
    }
    // scatter x: xs[s] = x value living at spatial position s
    for (int s = tid; s < 784; s += 256) {
        int ch = (7 * s) % 11;
        int p = (ch * 784 + s) / 11;
        xs[(s / 28 + 1) * 30 + s % 28 + 1] = x[(size_t)b * IMG + p];
    }
    // zero the K-pad columns
    if (tid < 16) h_bf[(size_t)b * KP + 784 + tid] = __float2bfloat16(0.f);
    __syncthreads();

    const float* Tc = T + myc * 2352;
    for (int pix = tid; pix < 784; pix += 256) {
        int r = pix / 28, c = pix % 28;
        float a0 = Tc[pix], a1 = Tc[784 + pix], a2 = Tc[1568 + pix];
        int chbase = (9 * r + 7 * c + 6) % 11;
#pragma unroll
        for (int dr = 0; dr < 3; ++dr)
#pragma unroll
            for (int dc = 0; dc < 3; ++dc) {
                const int kk = (9 * dr + 7 * dc) % 11;  // compile-time
                int ch = chbase + kk;
                if (ch >= 11) ch -= 11;
                float v = xs[(r + dr) * 30 + c + dc];
                float4 w = wt[(dr * 3 + dc) * 11 + ch];
                a0 += v * w.x; a1 += v * w.y; a2 += v * w.z;
            }
        hs0[(r + 1) * 30 + c + 1] =
            make_float4(fmaxf(a0, 0.f), fmaxf(a1, 0.f), fmaxf(a2, 0.f), 0.f);
    }
    __syncthreads();

    for (int pix = tid; pix < 784; pix += 256) {
        int r = pix / 28, c = pix % 28;
        float a = 0.f;
#pragma unroll
        for (int dr = 0; dr < 3; ++dr)
#pragma unroll
            for (int dc = 0; dc < 3; ++dc) {
                int t = dr * 3 + dc;
                float4 v = hs0[(r + dr) * 30 + c + dc];
                a += v.x * w1[t] + v.y * w1[9 + t] + v.z * w1[18 + t];
            }
        h_bf[(size_t)b * KP + pix] = __float2bfloat16(fmaxf(a, 0.f));
    }
}

// ---------------------------------------------------------------------------
// K2: fc1 via bf16 MFMA.  h1b[8192,416] = bf16(relu(h @ w^T + b))
// ---------------------------------------------------------------------------
__global__ __launch_bounds__(256) void fc1_mfma(
    const ushort* __restrict__ h_bf,  // [8192,800] bf16
    const ushort* __restrict__ w_bf,  // [400,800] bf16
    const float* __restrict__ bias,   // [400]
    __hip_bfloat16* __restrict__ h1b) // [8192,416] bf16
{
    __shared__ ushort Bs[80][40];   // B tile [n][k], stride 40 (pad)

    const int tid  = threadIdx.x;
    const int wid  = tid >> 6;
    const int lane = tid & 63;
    const int l15  = lane & 15;
    const int lq   = lane >> 4;       // k-quadrant 0..3
    const int bm   = blockIdx.x * 128;
    const int bn   = blockIdx.y * 80;

    f32x4 acc[2][5] = {};

    const int n0 = tid >> 2;          // 0..63  (staging row)
    const int kq0 = tid & 3;          // staging k-quadrant

    for (int k0 = 0; k0 < KP; k0 += 32) {
        bf16x8 s0 = *(const bf16x8*)&w_bf[(size_t)(bn + n0) * KP + k0 + kq0 * 8];
        bf16x8 s1;
        if (tid < 64)
            s1 = *(const bf16x8*)&w_bf[(size_t)(bn + 64 + n0) * KP + k0 + kq0 * 8];
        bf16x8 a0 = *(const bf16x8*)&h_bf[(size_t)(bm + wid * 32 + l15) * KP + k0 + lq * 8];
        bf16x8 a1 = *(const bf16x8*)&h_bf[(size_t)(bm + wid * 32 + 16 + l15) * KP + k0 + lq * 8];
        __syncthreads();
        *(bf16x8*)&Bs[n0][kq0 * 8] = s0;
        if (tid < 64) *(bf16x8*)&Bs[64 + n0][kq0 * 8] = s1;
        __syncthreads();
#pragma unroll
        for (int nf = 0; nf < 5; ++nf) {
            bf16x8 bfr = *(const bf16x8*)&Bs[nf * 16 + l15][lq * 8];
            acc[0][nf] = __builtin_amdgcn_mfma_f32_16x16x32_bf16(a0, bfr, acc[0][nf], 0, 0, 0);
            acc[1][nf] = __builtin_amdgcn_mfma_f32_16x16x32_bf16(a1, bfr, acc[1][nf], 0, 0, 0);
        }
    }

#pragma unroll
    for (int nf = 0; nf < 5; ++nf) {
        int col = bn + nf * 16 + l15;
        float bv = bias[col];
#pragma unroll
        for (int mr = 0; mr < 2; ++mr)
#pragma unroll
            for (int v = 0; v < 4; ++v) {
                int row = bm + wid * 32 + mr * 16 + lq * 4 + v;
                h1b[(size_t)row * KP2 + col] =
                    __float2bfloat16(fmaxf(acc[mr][nf][v] + bv, 0.f));
            }
    }
    // last N-block zeroes the K-pad cols 400..415
    if (blockIdx.y == 4) {
#pragma unroll
        for (int mr = 0; mr < 2; ++mr)
#pragma unroll
            for (int v = 0; v < 4; ++v) {
                int row = bm + wid * 32 + mr * 16 + lq * 4 + v;
                h1b[(size_t)row * KP2 + 400 + l15] = __float2bfloat16(0.f);
            }
    }
}

// ---------------------------------------------------------------------------
// K3: fc21 + fc22 via bf16 MFMA, no LDS.
// out cols: 0..19 -> mu, 20..39 -> logvar, 40..47 -> discarded (zero rows)
// ---------------------------------------------------------------------------
__global__ __launch_bounds__(256) void fc2_mfma(
    const ushort* __restrict__ h1b,   // [8192,416] bf16
    const ushort* __restrict__ w2bf,  // [48,416] bf16
    const float* __restrict__ b21, const float* __restrict__ b22,
    float* __restrict__ out)
{
    const int tid  = threadIdx.x;
    const int wid  = tid >> 6;
    const int lane = tid & 63;
    const int l15  = lane & 15;
    const int lq   = lane >> 4;
    const int bm   = blockIdx.x * 128;

    f32x4 acc[2][3] = {};

    for (int k0 = 0; k0 < KP2; k0 += 32) {
        bf16x8 a0 = *(const bf16x8*)&h1b[(size_t)(bm + wid * 32 + l15) * KP2 + k0 + lq * 8];
        bf16x8 a1 = *(const bf16x8*)&h1b[(size_t)(bm + wid * 32 + 16 + l15) * KP2 + k0 + lq * 8];
#pragma unroll
        for (int nf = 0; nf < 3; ++nf) {
            bf16x8 bfr = *(const bf16x8*)&w2bf[(size_t)(nf * 16 + l15) * KP2 + k0 + lq * 8];
            acc[0][nf] = __builtin_amdgcn_mfma_f32_16x16x32_bf16(a0, bfr, acc[0][nf], 0, 0, 0);
            acc[1][nf] = __builtin_amdgcn_mfma_f32_16x16x32_bf16(a1, bfr, acc[1][nf], 0, 0, 0);
        }
    }

    const size_t base = (size_t)BATCH * IMG;
#pragma unroll
    for (int nf = 0; nf < 3; ++nf) {
        int col = nf * 16 + l15;
        if (col < 40) {
            bool is_mu = (col < 20);
            int ccol = is_mu ? col : col - 20;
            float bv = is_mu ? b21[ccol] : b22[ccol];
            size_t obase = is_mu ? base : base + (size_t)BATCH * 20;
#pragma unroll
            for (int mr = 0; mr < 2; ++mr)
#pragma unroll
                for (int v = 0; v < 4; ++v) {
                    int row = bm + wid * 32 + mr * 16 + lq * 4 + v;
                    out[obase + (size_t)row * 20 + ccol] = acc[mr][nf][v] + bv;
                }
        }
    }
}

// ---------------------------------------------------------------------------
// K4: decoder — fc3 + deconv0 + wave-parity deconv1 (vertical q-pairs) +
// deconv2 + sigmoid   (identical to R9)
// ---------------------------------------------------------------------------
__global__ __launch_bounds__(256, 4) void decoder_kernel(
    const int* __restrict__ cls,
    const float* __restrict__ fc3_w,  // [392,30]
    const float* __restrict__ fc3_b,  // [392]
    const float* __restrict__ dw0,    // [11,2,3,3]
    const float* __restrict__ dw2,    // [1,3,3,3]
    const float* __restrict__ WF4g,   // 576 floats = 144 float4
    float* __restrict__ out)
{
    __shared__ float  z[32];
    __shared__ float  d0inS[2 * 16 * 17];  // [2][16][17]
    __shared__ float4 d0sp[3][16 * 16];    // per-cblk planes, ch-minor float4
    __shared__ float4 d1s[30 * 30];        // [30][30] (3ch + pad)
    __shared__ float4 we[144];             // WF copy

    const int b = blockIdx.x;
    const int tid = threadIdx.x;
    const int myc = cls[b];
    const float* mu = out + (size_t)BATCH * IMG + (size_t)b * 20;

    // zero d0in fully; d0sp + d1s borders only
    for (int i = tid; i < 2 * 16 * 17; i += 256) d0inS[i] = 0.f;
    for (int i = tid; i < 60; i += 256) {
        int r, c;
        if (i < 16)      { r = 0;  c = i; }
        else if (i < 32) { r = 15; c = i - 16; }
        else if (i < 46) { r = 1 + (i - 32); c = 0; }
        else             { r = 1 + (i - 46); c = 15; }
        int p = r * 16 + c;
        d0sp[0][p] = d0sp[1][p] = d0sp[2][p] = make_float4(0.f, 0.f, 0.f, 0.f);
    }
    for (int i = tid; i < 116; i += 256) {
        int r, c;
        if (i < 30)      { r = 0;  c = i; }
        else if (i < 60) { r = 29; c = i - 30; }
        else if (i < 88) { r = 1 + (i - 60); c = 0; }
        else             { r = 1 + (i - 88); c = 29; }
        d1s[r * 30 + c] = make_float4(0.f, 0.f, 0.f, 0.f);
    }
    for (int i = tid; i < 144; i += 256) we[i] = ((const float4*)WF4g)[i];
    if (tid < 20) z[tid] = mu[tid];
    else if (tid < 30) z[tid] = (tid - 20 == myc) ? 1.f : 0.f;
    __syncthreads();

    // fc3: [30] -> [392] + relu -> d0in [2][16][17] padded
    for (int j = tid; j < 392; j += 256) {
        float acc = fc3_b[j];
        const float2* wrow = (const float2*)&fc3_w[j * 30];
#pragma unroll
        for (int k = 0; k < 15; ++k) {
            float2 wv = wrow[k];
            acc += z[2 * k] * wv.x + z[2 * k + 1] * wv.y;
        }
        int ch = j / 196, rem = j % 196;
        d0inS[ch * 272 + (rem / 14 + 1) * 17 + (rem % 14 + 1)] = fmaxf(acc, 0.f);
    }
    __syncthreads();

    // deconv0: one thread per position, all 11 channels; weights -> s_loads
    if (tid < 196) {
        int r = tid / 14, c = tid % 14;
        float a[12] = {};
#pragma unroll
        for (int i = 0; i < 2; ++i)
#pragma unroll
            for (int dr = 0; dr < 3; ++dr)
#pragma unroll
                for (int dc = 0; dc < 3; ++dc) {
                    float v = d0inS[i * 272 + (r + dr) * 17 + (c + dc)];
#pragma unroll
                    for (int o = 0; o < 11; ++o)
                        a[o] += v * dw0[((o * 2 + i) * 3 + dr) * 3 + dc];
                }
        int p = (r + 1) * 16 + (c + 1);
        d0sp[0][p] = make_float4(fmaxf(a[0], 0.f), fmaxf(a[1], 0.f),
                                 fmaxf(a[2], 0.f), fmaxf(a[3], 0.f));
        d0sp[1][p] = make_float4(fmaxf(a[4], 0.f), fmaxf(a[5], 0.f),
                                 fmaxf(a[6], 0.f), fmaxf(a[7], 0.f));
        d0sp[2][p] = make_float4(fmaxf(a[8], 0.f), fmaxf(a[9], 0.f),
                                 fmaxf(a[10], 0.f), 0.f);
    }
    __syncthreads();

    // deconv1: wave w owns parity w. Vertical q-pair per thread.
    {
        const int wid  = tid >> 6;          // parity, wave-uniform
        const int lane = tid & 63;
        const int pr = wid >> 1, pc = wid & 1;
        const float4* wbase = &we[wid * 36];
#pragma unroll 1
        for (int pp = 0; pp < 2; ++pp) {
            int pi = pp * 64 + lane;
            if (pi < 98) {
                int qpr = pi / 14, qc = pi - qpr * 14;
                int qr0 = qpr * 2;
                int base = (qr0 + pr) * 16 + qc + pc;
                float a00 = 0.f, a01 = 0.f, a02 = 0.f;
                float a10 = 0.f, a11 = 0.f, a12 = 0.f;
#pragma unroll
                for (int cb = 0; cb < 3; ++cb) {
                    float4 v0 = d0sp[cb][base];
                    float4 v1 = d0sp[cb][base + 1];
                    float4 v2 = d0sp[cb][base + 16];
                    float4 v3 = d0sp[cb][base + 17];
                    float4 v4 = d0sp[cb][base + 32];
                    float4 v5 = d0sp[cb][base + 33];
#pragma unroll
                    for (int o = 0; o < 3; ++o) {
                        float4 w00 = wbase[(o * 4 + 0) * 3 + cb];
                        float4 w01 = wbase[(o * 4 + 1) * 3 + cb];
                        float4 w10 = wbase[(o * 4 + 2) * 3 + cb];
                        float4 w11 = wbase[(o * 4 + 3) * 3 + cb];
                        float s0 = v0.x * w00.x + v0.y * w00.y +
                                   v0.z * w00.z + v0.w * w00.w +
                                   v1.x * w01.x + v1.y * w01.y +
                                   v1.z * w01.z + v1.w * w01.w +
                                   v2.x * w10.x + v2.y * w10.y +
                                   v2.z * w10.z + v2.w * w10.w +
                                   v3.x * w11.x + v3.y * w11.y +
                                   v3.z * w11.z + v3.w * w11.w;
                        float s1 = v2.x * w00.x + v2.y * w00.y +
                                   v2.z * w00.z + v2.w * w00.w +
                                   v3.x * w01.x + v3.y * w01.y +
                                   v3.z * w01.z + v3.w * w01.w +
                                   v4.x * w10.x + v4.y * w10.y +
                                   v4.z * w10.z + v4.w * w10.w +
                                   v5.x * w11.x + v5.y * w11.y +
                                   v5.z * w11.z + v5.w * w11.w;
                        if (o == 0)      { a00 += s0; a10 += s1; }
                        else if (o == 1) { a01 += s0; a11 += s1; }
                        else             { a02 += s0; a12 += s1; }
                    }
                }
                int r0 = 2 * qr0 + pr, c = 2 * qc + pc;
                d1s[(r0 + 1) * 30 + c + 1] =
                    make_float4(fmaxf(a00, 0.f), fmaxf(a01, 0.f),
                                fmaxf(a02, 0.f), 0.f);
                d1s[(r0 + 3) * 30 + c + 1] =
                    make_float4(fmaxf(a10, 0.f), fmaxf(a11, 0.f),
                                fmaxf(a12, 0.f), 0.f);
            }
        }
    }
    __syncthreads();

    // deconv2 (3->1) + sigmoid
    for (int pix = tid; pix < 784; pix += 256) {
        int r = pix / 28, c = pix % 28;
        float a = 0.f;
#pragma unroll
        for (int dr = 0; dr < 3; ++dr)
#pragma unroll
            for (int dc = 0; dc < 3; ++dc) {
                int t = dr * 3 + dc;
                float4 v = d1s[(r + dr) * 30 + c + dc];
                a += v.x * dw2[t] + v.y * dw2[9 + t] + v.z * dw2[18 + t];
            }
        out[(size_t)b * IMG + pix] = 1.f / (1.f + expf(-a));
    }
}

// ---------------------------------------------------------------------------
extern "C" void kernel_launch(void* const* d_in, const int* in_sizes, int n_in,
                              void* d_out, int out_size, void* d_ws, size_t ws_size,
                              hipStream_t stream) {
    const float* x     = (const float*)d_in[0];
    const int*   cls   = (const int*)d_in[1];
    const float* w0    = (const float*)d_in[2];
    const float* w1    = (const float*)d_in[3];
    const float* fc1_w = (const float*)d_in[4];
    const float* fc1_b = (const float*)d_in[5];
    const float* w21   = (const float*)d_in[6];
    const float* b21   = (const float*)d_in[7];
    const float* w22   = (const float*)d_in[8];
    const float* b22   = (const float*)d_in[9];
    const float* fc3_w = (const float*)d_in[10];
    const float* fc3_b = (const float*)d_in[11];
    const float* dw0   = (const float*)d_in[12];
    const float* dw1   = (const float*)d_in[13];
    const float* dw2   = (const float*)d_in[14];

    float* out = (float*)d_out;
    char*  ws  = (char*)d_ws;
    __hip_bfloat16* h_bf = (__hip_bfloat16*)ws;                       // 8192*800 bf16
    __hip_bfloat16* h1b  = (__hip_bfloat16*)(ws + (size_t)BATCH * KP * 2);  // 8192*416 bf16
    float* T    = (float*)(ws + (size_t)BATCH * KP * 2 + (size_t)BATCH * KP2 * 2);
    float* WF4  = T + 10 * 3 * 784;
    __hip_bfloat16* w_bf  = (__hip_bfloat16*)(WF4 + 576);             // 400*800
    __hip_bfloat16* w2bf  = w_bf + 400 * KP;                          // 48*416

    precompute_kernel<<<59, 256, 0, stream>>>(w0, dw1, fc1_w, w21, w22,
                                              T, WF4, w_bf, w2bf);
    encoder_kernel<<<BATCH, 256, 0, stream>>>(x, cls, w0, w1, T, h_bf);
    fc1_mfma<<<dim3(64, 5), 256, 0, stream>>>((const ushort*)h_bf,
                                              (const ushort*)w_bf, fc1_b, h1b);
    fc2_mfma<<<64, 256, 0, stream>>>((const ushort*)h1b, (const ushort*)w2bf,
                                     b21, b22, out);
    decoder_kernel<<<BATCH, 256, 0, stream>>>(cls, fc3_w, fc3_b, dw0, dw2, WF4, out);
}

// Round 11
// 147.253 us; speedup vs baseline: 5.2239x; 1.2457x over previous
//
#include <hip/hip_runtime.h>
#include <hip/hip_bf16.h>
#include <math.h>

#define BATCH 8192
#define IMG 784   // 28*28
#define KP 800    // fc1 K padded to multiple of 32
#define KP2 416   // fc2 K padded (400 -> 416)

typedef short  bf16x8 __attribute__((ext_vector_type(8)));
typedef float  f32x4  __attribute__((ext_vector_type(4)));
typedef float  f32x2  __attribute__((ext_vector_type(2)));

// ---------------------------------------------------------------------------
// K0: precompute (a) per-class conv0 one-hot tables T[10][3][784],
// (b) parity-folded deconv1 weights WF4 + per-tap packed w1p/dw2p,
// (c) fc1_w -> bf16 [400][800], (d) fc2 weights -> bf16 [48][416].
// ---------------------------------------------------------------------------
__global__ __launch_bounds__(256) void precompute_kernel(
    const float* __restrict__ w0,    // [3,11,3,3]
    const float* __restrict__ w1,    // [1,3,3,3]
    const float* __restrict__ dw1,   // [3,11,3,3]
    const float* __restrict__ dw2,   // [1,3,3,3]
    const float* __restrict__ fc1w,  // [400,784]
    const float* __restrict__ w21,   // [20,400]
    const float* __restrict__ w22,   // [20,400]
    float* __restrict__ T,           // [10,3,784]
    float* __restrict__ WF4,         // 576 floats
    float* __restrict__ w1p,         // [9]*4 floats
    float* __restrict__ dw2p,        // [9]*4 floats
    __hip_bfloat16* __restrict__ wbf,  // [400,800]
    __hip_bfloat16* __restrict__ w2bf) // [48,416]
{
    const int blk = blockIdx.x, tid = threadIdx.x;
    if (blk < 10) {
        const int t = blk;
        for (int idx = tid; idx < 3 * 784; idx += 256) {
            int o = idx / 784, pix = idx % 784;
            int r = pix / 28, c = pix % 28;
            float acc = 0.f;
#pragma unroll
            for (int dr = 0; dr < 3; ++dr)
#pragma unroll
                for (int dc = 0; dc < 3; ++dc) {
                    int rr = r + dr - 1, cc = c + dc - 1;
                    if (rr < 0 || rr > 27 || cc < 0 || cc > 27) continue;
                    int s = rr * 28 + cc;
                    int i = ((4 * (t + 1 - s)) % 11 + 11) % 11;
                    acc += w0[(o * 11 + i) * 9 + dr * 3 + dc];
                }
            T[(t * 3 + o) * 784 + pix] = acc;
        }
    } else if (blk == 10) {
        // WF4 flat idx = (((par*3+o)*4+uv)*3+cb)*4+j ; channel = 4*cb+j
        for (int idx = tid; idx < 576; idx += 256) {
            int j = idx & 3;
            int rest = idx >> 2;
            int cb = rest % 3;
            int rest2 = rest / 3;
            int uv = rest2 % 4;
            int rest3 = rest2 / 4;
            int o = rest3 % 3;
            int par = rest3 / 3;
            int ch = cb * 4 + j;
            float acc = 0.f;
            if (ch < 11) {
                int u = uv >> 1, v = uv & 1;
                int pr = par >> 1, pc = par & 1;
                for (int dr = 0; dr < 3; ++dr) {
                    bool rin = (pr == 0) ? (u == 0 ? dr == 0 : dr >= 1)
                                         : (u == 0 ? dr <= 1 : dr == 2);
                    if (!rin) continue;
                    for (int dc = 0; dc < 3; ++dc) {
                        bool cin = (pc == 0) ? (v == 0 ? dc == 0 : dc >= 1)
                                             : (v == 0 ? dc <= 1 : dc == 2);
                        if (cin) acc += dw1[(o * 11 + ch) * 9 + dr * 3 + dc];
                    }
                }
            }
            WF4[idx] = acc;
        }
        // per-tap packed conv1 / deconv2 weights: {w[t], w[9+t], w[18+t], 0}
        if (tid < 9) {
            w1p[tid * 4 + 0] = w1[tid];
            w1p[tid * 4 + 1] = w1[9 + tid];
            w1p[tid * 4 + 2] = w1[18 + tid];
            w1p[tid * 4 + 3] = 0.f;
        } else if (tid < 18) {
            int t = tid - 9;
            dw2p[t * 4 + 0] = dw2[t];
            dw2p[t * 4 + 1] = dw2[9 + t];
            dw2p[t * 4 + 2] = dw2[18 + t];
            dw2p[t * 4 + 3] = 0.f;
        }
    } else if (blk < 51) {
        // fc1_w fp32 [400,784] -> bf16 [400,800] (cols 784..799 zero)
        const int base = (blk - 11) * 8000;
        for (int i = tid; i < 8000; i += 256) {
            int flat = base + i;
            int n = flat / KP, k = flat % KP;
            float v = (k < 784) ? fc1w[n * 784 + k] : 0.f;
            wbf[flat] = __float2bfloat16(v);
        }
    } else {
        // fc2 weights -> bf16 [48,416]: rows 0-19 w21, 20-39 w22, 40-47 zero
        const int base = (blk - 51) * 2496;
        for (int i = tid; i < 2496; i += 256) {
            int flat = base + i;
            int j = flat / KP2, k = flat % KP2;
            float v = 0.f;
            if (k < 400) {
                if (j < 20)      v = w21[j * 400 + k];
                else if (j < 40) v = w22[(j - 20) * 400 + k];
            }
            w2bf[flat] = __float2bfloat16(v);
        }
    }
}

// ---------------------------------------------------------------------------
// K1: encoder — sparse-x conv0 (9 taps, packed f32) + class table T +
// conv1 (packed f32). writes h as bf16 [B][800]
// ---------------------------------------------------------------------------
__global__ __launch_bounds__(256, 4) void encoder_kernel(
    const float* __restrict__ x, const int* __restrict__ cls,
    const float* __restrict__ w0,    // [3,11,3,3]
    const float* __restrict__ w1p,   // [9] float4 packed
    const float* __restrict__ T,     // [10,3,784]
    __hip_bfloat16* __restrict__ h_bf)  // [B,800]
{
    __shared__ float  xs[30 * 30];      // scattered x image, zero border
    __shared__ float4 hs0[30 * 30];     // conv0 out (3ch + pad), zero border
    __shared__ float4 wt[99];           // [tap][ch] -> (w_o0, w_o1, w_o2, 0)

    const int b = blockIdx.x, tid = threadIdx.x;
    const int myc = cls[b];

    for (int i = tid; i < 116; i += 256) {
        int r, c;
        if (i < 30)      { r = 0;  c = i; }
        else if (i < 60) { r = 29; c = i - 30; }
        else if (i < 88) { r = 1 + (i - 60); c = 0; }
        else             { r = 1 + (i - 88); c = 29; }
        xs[r * 30 + c] = 0.f;
        hs0[r * 30 + c] = make_float4(0.f, 0.f, 0.f, 0.f);
    }
    for (int i = tid; i < 99; i += 256) {
        int tap = i / 11, ch = i % 11;
        wt[i] = make_float4(w0[ch * 9 + tap], w0[(11 + ch) * 9 + tap],
                            w0[(22 + ch) * 9 + tap], 0.f);
    }
    for (int s = tid; s < 784; s += 256) {
        int ch = (7 * s) % 11;
        int p = (ch * 784 + s) / 11;
        xs[(s / 28 + 1) * 30 + s % 28 + 1] = x[(size_t)b * IMG + p];
    }
    if (tid < 16) h_bf[(size_t)b * KP + 784 + tid] = __float2bfloat16(0.f);
    __syncthreads();

    const float* Tc = T + myc * 2352;
    for (int pix = tid; pix < 784; pix += 256) {
        int r = pix / 28, c = pix % 28;
        f32x4 A = {Tc[pix], Tc[784 + pix], Tc[1568 + pix], 0.f};
        int chbase = (9 * r + 7 * c + 6) % 11;
#pragma unroll
        for (int dr = 0; dr < 3; ++dr)
#pragma unroll
            for (int dc = 0; dc < 3; ++dc) {
                const int kk = (9 * dr + 7 * dc) % 11;  // compile-time
                int ch = chbase + kk;
                if (ch >= 11) ch -= 11;
                float v = xs[(r + dr) * 30 + c + dc];
                f32x4 w = *(const f32x4*)&wt[(dr * 3 + dc) * 11 + ch];
                f32x4 vv = {v, v, v, v};
                A = __builtin_elementwise_fma(vv, w, A);
            }
        hs0[(r + 1) * 30 + c + 1] =
            make_float4(fmaxf(A.x, 0.f), fmaxf(A.y, 0.f), fmaxf(A.z, 0.f), 0.f);
    }
    __syncthreads();

    const f32x4* w1v = (const f32x4*)w1p;
    for (int pix = tid; pix < 784; pix += 256) {
        int r = pix / 28, c = pix % 28;
        f32x4 A = {0.f, 0.f, 0.f, 0.f};
#pragma unroll
        for (int dr = 0; dr < 3; ++dr)
#pragma unroll
            for (int dc = 0; dc < 3; ++dc) {
                f32x4 v = *(const f32x4*)&hs0[(r + dr) * 30 + c + dc];
                A = __builtin_elementwise_fma(v, w1v[dr * 3 + dc], A);
            }
        float a = A.x + A.y + A.z;
        h_bf[(size_t)b * KP + pix] = __float2bfloat16(fmaxf(a, 0.f));
    }
}

// ---------------------------------------------------------------------------
// K2: fc1 via bf16 MFMA.  h1b[8192,416] = bf16(relu(h @ w^T + b))
// ---------------------------------------------------------------------------
__global__ __launch_bounds__(256) void fc1_mfma(
    const ushort* __restrict__ h_bf,  // [8192,800] bf16
    const ushort* __restrict__ w_bf,  // [400,800] bf16
    const float* __restrict__ bias,   // [400]
    __hip_bfloat16* __restrict__ h1b) // [8192,416] bf16
{
    __shared__ ushort Bs[80][40];   // B tile [n][k], stride 40 (pad)

    const int tid  = threadIdx.x;
    const int wid  = tid >> 6;
    const int lane = tid & 63;
    const int l15  = lane & 15;
    const int lq   = lane >> 4;       // k-quadrant 0..3
    const int bm   = blockIdx.x * 128;
    const int bn   = blockIdx.y * 80;

    f32x4 acc[2][5] = {};

    const int n0 = tid >> 2;          // 0..63  (staging row)
    const int kq0 = tid & 3;          // staging k-quadrant

    for (int k0 = 0; k0 < KP; k0 += 32) {
        bf16x8 s0 = *(const bf16x8*)&w_bf[(size_t)(bn + n0) * KP + k0 + kq0 * 8];
        bf16x8 s1;
        if (tid < 64)
            s1 = *(const bf16x8*)&w_bf[(size_t)(bn + 64 + n0) * KP + k0 + kq0 * 8];
        bf16x8 a0 = *(const bf16x8*)&h_bf[(size_t)(bm + wid * 32 + l15) * KP + k0 + lq * 8];
        bf16x8 a1 = *(const bf16x8*)&h_bf[(size_t)(bm + wid * 32 + 16 + l15) * KP + k0 + lq * 8];
        __syncthreads();
        *(bf16x8*)&Bs[n0][kq0 * 8] = s0;
        if (tid < 64) *(bf16x8*)&Bs[64 + n0][kq0 * 8] = s1;
        __syncthreads();
#pragma unroll
        for (int nf = 0; nf < 5; ++nf) {
            bf16x8 bfr = *(const bf16x8*)&Bs[nf * 16 + l15][lq * 8];
            acc[0][nf] = __builtin_amdgcn_mfma_f32_16x16x32_bf16(a0, bfr, acc[0][nf], 0, 0, 0);
            acc[1][nf] = __builtin_amdgcn_mfma_f32_16x16x32_bf16(a1, bfr, acc[1][nf], 0, 0, 0);
        }
    }

#pragma unroll
    for (int nf = 0; nf < 5; ++nf) {
        int col = bn + nf * 16 + l15;
        float bv = bias[col];
#pragma unroll
        for (int mr = 0; mr < 2; ++mr)
#pragma unroll
            for (int v = 0; v < 4; ++v) {
                int row = bm + wid * 32 + mr * 16 + lq * 4 + v;
                h1b[(size_t)row * KP2 + col] =
                    __float2bfloat16(fmaxf(acc[mr][nf][v] + bv, 0.f));
            }
    }
    if (blockIdx.y == 4) {
#pragma unroll
        for (int mr = 0; mr < 2; ++mr)
#pragma unroll
            for (int v = 0; v < 4; ++v) {
                int row = bm + wid * 32 + mr * 16 + lq * 4 + v;
                h1b[(size_t)row * KP2 + 400 + l15] = __float2bfloat16(0.f);
            }
    }
}

// ---------------------------------------------------------------------------
// K3: fc21 + fc22 via bf16 MFMA, no LDS.
// ---------------------------------------------------------------------------
__global__ __launch_bounds__(256) void fc2_mfma(
    const ushort* __restrict__ h1b,   // [8192,416] bf16
    const ushort* __restrict__ w2bf,  // [48,416] bf16
    const float* __restrict__ b21, const float* __restrict__ b22,
    float* __restrict__ out)
{
    const int tid  = threadIdx.x;
    const int wid  = tid >> 6;
    const int lane = tid & 63;
    const int l15  = lane & 15;
    const int lq   = lane >> 4;
    const int bm   = blockIdx.x * 128;

    f32x4 acc[2][3] = {};

    for (int k0 = 0; k0 < KP2; k0 += 32) {
        bf16x8 a0 = *(const bf16x8*)&h1b[(size_t)(bm + wid * 32 + l15) * KP2 + k0 + lq * 8];
        bf16x8 a1 = *(const bf16x8*)&h1b[(size_t)(bm + wid * 32 + 16 + l15) * KP2 + k0 + lq * 8];
#pragma unroll
        for (int nf = 0; nf < 3; ++nf) {
            bf16x8 bfr = *(const bf16x8*)&w2bf[(size_t)(nf * 16 + l15) * KP2 + k0 + lq * 8];
            acc[0][nf] = __builtin_amdgcn_mfma_f32_16x16x32_bf16(a0, bfr, acc[0][nf], 0, 0, 0);
            acc[1][nf] = __builtin_amdgcn_mfma_f32_16x16x32_bf16(a1, bfr, acc[1][nf], 0, 0, 0);
        }
    }

    const size_t base = (size_t)BATCH * IMG;
#pragma unroll
    for (int nf = 0; nf < 3; ++nf) {
        int col = nf * 16 + l15;
        if (col < 40) {
            bool is_mu = (col < 20);
            int ccol = is_mu ? col : col - 20;
            float bv = is_mu ? b21[ccol] : b22[ccol];
            size_t obase = is_mu ? base : base + (size_t)BATCH * 20;
#pragma unroll
            for (int mr = 0; mr < 2; ++mr)
#pragma unroll
                for (int v = 0; v < 4; ++v) {
                    int row = bm + wid * 32 + mr * 16 + lq * 4 + v;
                    out[obase + (size_t)row * 20 + ccol] = acc[mr][nf][v] + bv;
                }
        }
    }
}

// ---------------------------------------------------------------------------
// K4: decoder — fc3 + deconv0 + wave-parity deconv1 (packed f32x2 accum) +
// deconv2 (packed) + sigmoid
// ---------------------------------------------------------------------------
__global__ __launch_bounds__(256, 4) void decoder_kernel(
    const int* __restrict__ cls,
    const float* __restrict__ fc3_w,  // [392,30]
    const float* __restrict__ fc3_b,  // [392]
    const float* __restrict__ dw0,    // [11,2,3,3]
    const float* __restrict__ dw2p,   // [9] float4 packed
    const float* __restrict__ WF4g,   // 576 floats = 144 float4
    float* __restrict__ out)
{
    __shared__ float  z[32];
    __shared__ float  d0inS[2 * 16 * 17];  // [2][16][17]
    __shared__ float4 d0sp[3][16 * 16];    // per-cblk planes, ch-minor float4
    __shared__ float4 d1s[30 * 30];        // [30][30] (3ch + pad)
    __shared__ float4 we[144];             // WF copy

    const int b = blockIdx.x;
    const int tid = threadIdx.x;
    const int myc = cls[b];
    const float* mu = out + (size_t)BATCH * IMG + (size_t)b * 20;

    for (int i = tid; i < 2 * 16 * 17; i += 256) d0inS[i] = 0.f;
    for (int i = tid; i < 60; i += 256) {
        int r, c;
        if (i < 16)      { r = 0;  c = i; }
        else if (i < 32) { r = 15; c = i - 16; }
        else if (i < 46) { r = 1 + (i - 32); c = 0; }
        else             { r = 1 + (i - 46); c = 15; }
        int p = r * 16 + c;
        d0sp[0][p] = d0sp[1][p] = d0sp[2][p] = make_float4(0.f, 0.f, 0.f, 0.f);
    }
    for (int i = tid; i < 116; i += 256) {
        int r, c;
        if (i < 30)      { r = 0;  c = i; }
        else if (i < 60) { r = 29; c = i - 30; }
        else if (i < 88) { r = 1 + (i - 60); c = 0; }
        else             { r = 1 + (i - 88); c = 29; }
        d1s[r * 30 + c] = make_float4(0.f, 0.f, 0.f, 0.f);
    }
    for (int i = tid; i < 144; i += 256) we[i] = ((const float4*)WF4g)[i];
    if (tid < 20) z[tid] = mu[tid];
    else if (tid < 30) z[tid] = (tid - 20 == myc) ? 1.f : 0.f;
    __syncthreads();

    // fc3: [30] -> [392] + relu -> d0in [2][16][17] padded
    for (int j = tid; j < 392; j += 256) {
        float acc = fc3_b[j];
        const float2* wrow = (const float2*)&fc3_w[j * 30];
#pragma unroll
        for (int k = 0; k < 15; ++k) {
            float2 wv = wrow[k];
            acc += z[2 * k] * wv.x + z[2 * k + 1] * wv.y;
        }
        int ch = j / 196, rem = j % 196;
        d0inS[ch * 272 + (rem / 14 + 1) * 17 + (rem % 14 + 1)] = fmaxf(acc, 0.f);
    }
    __syncthreads();

    // deconv0: one thread per position, all 11 channels; weights -> s_loads
    if (tid < 196) {
        int r = tid / 14, c = tid % 14;
        float a[12] = {};
#pragma unroll
        for (int i = 0; i < 2; ++i)
#pragma unroll
            for (int dr = 0; dr < 3; ++dr)
#pragma unroll
                for (int dc = 0; dc < 3; ++dc) {
                    float v = d0inS[i * 272 + (r + dr) * 17 + (c + dc)];
#pragma unroll
                    for (int o = 0; o < 11; ++o)
                        a[o] += v * dw0[((o * 2 + i) * 3 + dr) * 3 + dc];
                }
        int p = (r + 1) * 16 + (c + 1);
        d0sp[0][p] = make_float4(fmaxf(a[0], 0.f), fmaxf(a[1], 0.f),
                                 fmaxf(a[2], 0.f), fmaxf(a[3], 0.f));
        d0sp[1][p] = make_float4(fmaxf(a[4], 0.f), fmaxf(a[5], 0.f),
                                 fmaxf(a[6], 0.f), fmaxf(a[7], 0.f));
        d0sp[2][p] = make_float4(fmaxf(a[8], 0.f), fmaxf(a[9], 0.f),
                                 fmaxf(a[10], 0.f), 0.f);
    }
    __syncthreads();

    // deconv1: wave w owns parity w. Vertical q-pair per thread; f32x2
    // accumulators so mul+add pairs lower to v_pk_fma_f32.
    {
        const int wid  = tid >> 6;          // parity, wave-uniform
        const int lane = tid & 63;
        const int pr = wid >> 1, pc = wid & 1;
        const float4* wbase = &we[wid * 36];
#pragma unroll 1
        for (int pp = 0; pp < 2; ++pp) {
            int pi = pp * 64 + lane;
            if (pi < 98) {
                int qpr = pi / 14, qc = pi - qpr * 14;
                int qr0 = qpr * 2;
                int base = (qr0 + pr) * 16 + qc + pc;
                f32x2 A0[3] = {{0.f, 0.f}, {0.f, 0.f}, {0.f, 0.f}};
                f32x2 A1[3] = {{0.f, 0.f}, {0.f, 0.f}, {0.f, 0.f}};
#pragma unroll
                for (int cb = 0; cb < 3; ++cb) {
                    f32x4 v0 = *(const f32x4*)&d0sp[cb][base];
                    f32x4 v1 = *(const f32x4*)&d0sp[cb][base + 1];
                    f32x4 v2 = *(const f32x4*)&d0sp[cb][base + 16];
                    f32x4 v3 = *(const f32x4*)&d0sp[cb][base + 17];
                    f32x4 v4 = *(const f32x4*)&d0sp[cb][base + 32];
                    f32x4 v5 = *(const f32x4*)&d0sp[cb][base + 33];
#pragma unroll
                    for (int o = 0; o < 3; ++o) {
                        f32x4 w00 = *(const f32x4*)&wbase[(o * 4 + 0) * 3 + cb];
                        f32x4 w01 = *(const f32x4*)&wbase[(o * 4 + 1) * 3 + cb];
                        f32x4 w10 = *(const f32x4*)&wbase[(o * 4 + 2) * 3 + cb];
                        f32x4 w11 = *(const f32x4*)&wbase[(o * 4 + 3) * 3 + cb];
                        A0[o] = __builtin_elementwise_fma(v0.lo, w00.lo, A0[o]);
                        A0[o] = __builtin_elementwise_fma(v0.hi, w00.hi, A0[o]);
                        A0[o] = __builtin_elementwise_fma(v1.lo, w01.lo, A0[o]);
                        A0[o] = __builtin_elementwise_fma(v1.hi, w01.hi, A0[o]);
                        A0[o] = __builtin_elementwise_fma(v2.lo, w10.lo, A0[o]);
                        A0[o] = __builtin_elementwise_fma(v2.hi, w10.hi, A0[o]);
                        A0[o] = __builtin_elementwise_fma(v3.lo, w11.lo, A0[o]);
                        A0[o] = __builtin_elementwise_fma(v3.hi, w11.hi, A0[o]);
                        A1[o] = __builtin_elementwise_fma(v2.lo, w00.lo, A1[o]);
                        A1[o] = __builtin_elementwise_fma(v2.hi, w00.hi, A1[o]);
                        A1[o] = __builtin_elementwise_fma(v3.lo, w01.lo, A1[o]);
                        A1[o] = __builtin_elementwise_fma(v3.hi, w01.hi, A1[o]);
                        A1[o] = __builtin_elementwise_fma(v4.lo, w10.lo, A1[o]);
                        A1[o] = __builtin_elementwise_fma(v4.hi, w10.hi, A1[o]);
                        A1[o] = __builtin_elementwise_fma(v5.lo, w11.lo, A1[o]);
                        A1[o] = __builtin_elementwise_fma(v5.hi, w11.hi, A1[o]);
                    }
                }
                int r0 = 2 * qr0 + pr, c = 2 * qc + pc;
                d1s[(r0 + 1) * 30 + c + 1] =
                    make_float4(fmaxf(A0[0].x + A0[0].y, 0.f),
                                fmaxf(A0[1].x + A0[1].y, 0.f),
                                fmaxf(A0[2].x + A0[2].y, 0.f), 0.f);
                d1s[(r0 + 3) * 30 + c + 1] =
                    make_float4(fmaxf(A1[0].x + A1[0].y, 0.f),
                                fmaxf(A1[1].x + A1[1].y, 0.f),
                                fmaxf(A1[2].x + A1[2].y, 0.f), 0.f);
            }
        }
    }
    __syncthreads();

    // deconv2 (3->1, packed per-tap weights) + sigmoid
    const f32x4* dw2v = (const f32x4*)dw2p;
    for (int pix = tid; pix < 784; pix += 256) {
        int r = pix / 28, c = pix % 28;
        f32x4 A = {0.f, 0.f, 0.f, 0.f};
#pragma unroll
        for (int dr = 0; dr < 3; ++dr)
#pragma unroll
            for (int dc = 0; dc < 3; ++dc) {
                f32x4 v = *(const f32x4*)&d1s[(r + dr) * 30 + c + dc];
                A = __builtin_elementwise_fma(v, dw2v[dr * 3 + dc], A);
            }
        float a = A.x + A.y + A.z;
        out[(size_t)b * IMG + pix] = 1.f / (1.f + expf(-a));
    }
}

// ---------------------------------------------------------------------------
extern "C" void kernel_launch(void* const* d_in, const int* in_sizes, int n_in,
                              void* d_out, int out_size, void* d_ws, size_t ws_size,
                              hipStream_t stream) {
    const float* x     = (const float*)d_in[0];
    const int*   cls   = (const int*)d_in[1];
    const float* w0    = (const float*)d_in[2];
    const float* w1    = (const float*)d_in[3];
    const float* fc1_w = (const float*)d_in[4];
    const float* fc1_b = (const float*)d_in[5];
    const float* w21   = (const float*)d_in[6];
    const float* b21   = (const float*)d_in[7];
    const float* w22   = (const float*)d_in[8];
    const float* b22   = (const float*)d_in[9];
    const float* fc3_w = (const float*)d_in[10];
    const float* fc3_b = (const float*)d_in[11];
    const float* dw0   = (const float*)d_in[12];
    const float* dw1   = (const float*)d_in[13];
    const float* dw2   = (const float*)d_in[14];

    float* out = (float*)d_out;
    char*  ws  = (char*)d_ws;
    __hip_bfloat16* h_bf = (__hip_bfloat16*)ws;                       // 8192*800 bf16
    __hip_bfloat16* h1b  = (__hip_bfloat16*)(ws + (size_t)BATCH * KP * 2);  // 8192*416 bf16
    float* T    = (float*)(ws + (size_t)BATCH * KP * 2 + (size_t)BATCH * KP2 * 2);
    float* WF4  = T + 10 * 3 * 784;
    __hip_bfloat16* w_bf  = (__hip_bfloat16*)(WF4 + 576);             // 400*800
    __hip_bfloat16* w2bf  = w_bf + 400 * KP;                          // 48*416
    float* w1p  = (float*)(w2bf + 48 * KP2);                          // 36 floats
    float* dw2p = w1p + 36;                                           // 36 floats

    precompute_kernel<<<59, 256, 0, stream>>>(w0, w1, dw1, dw2, fc1_w, w21, w22,
                                              T, WF4, w1p, dw2p, w_bf, w2bf);
    encoder_kernel<<<BATCH, 256, 0, stream>>>(x, cls, w0, w1p, T, h_bf);
    fc1_mfma<<<dim3(64, 5), 256, 0, stream>>>((const ushort*)h_bf,
                                              (const ushort*)w_bf, fc1_b, h1b);
    fc2_mfma<<<64, 256, 0, stream>>>((const ushort*)h1b, (const ushort*)w2bf,
                                     b21, b22, out);
    decoder_kernel<<<BATCH, 256, 0, stream>>>(cls, fc3_w, fc3_b, dw0, dw2p, WF4, out);
}

// Round 12
// 143.069 us; speedup vs baseline: 5.3766x; 1.0292x over previous
//
#include <hip/hip_runtime.h>
#include <hip/hip_bf16.h>
#include <math.h>

#define BATCH 8192
#define IMG 784   // 28*28
#define KP 800    // fc1 K padded to multiple of 32
#define KP2 416   // fc2 K padded (400 -> 416)

typedef short  bf16x8 __attribute__((ext_vector_type(8)));
typedef float  f32x4  __attribute__((ext_vector_type(4)));
typedef float  f32x2  __attribute__((ext_vector_type(2)));

// ---------------------------------------------------------------------------
// K0: precompute (a) per-class conv0 one-hot tables T[10][3][784],
// (b) parity-folded deconv1 weights WF4 + per-tap packed w1p/dw2p,
// (c) fc1_w -> bf16 [400][800], (d) fc2 weights -> bf16 [48][416].
// ---------------------------------------------------------------------------
__global__ __launch_bounds__(256) void precompute_kernel(
    const float* __restrict__ w0,    // [3,11,3,3]
    const float* __restrict__ w1,    // [1,3,3,3]
    const float* __restrict__ dw1,   // [3,11,3,3]
    const float* __restrict__ dw2,   // [1,3,3,3]
    const float* __restrict__ fc1w,  // [400,784]
    const float* __restrict__ w21,   // [20,400]
    const float* __restrict__ w22,   // [20,400]
    float* __restrict__ T,           // [10,3,784]
    float* __restrict__ WF4,         // 576 floats
    float* __restrict__ w1p,         // [9]*4 floats
    float* __restrict__ dw2p,        // [9]*4 floats
    __hip_bfloat16* __restrict__ wbf,  // [400,800]
    __hip_bfloat16* __restrict__ w2bf) // [48,416]
{
    const int blk = blockIdx.x, tid = threadIdx.x;
    if (blk < 10) {
        const int t = blk;
        for (int idx = tid; idx < 3 * 784; idx += 256) {
            int o = idx / 784, pix = idx % 784;
            int r = pix / 28, c = pix % 28;
            float acc = 0.f;
#pragma unroll
            for (int dr = 0; dr < 3; ++dr)
#pragma unroll
                for (int dc = 0; dc < 3; ++dc) {
                    int rr = r + dr - 1, cc = c + dc - 1;
                    if (rr < 0 || rr > 27 || cc < 0 || cc > 27) continue;
                    int s = rr * 28 + cc;
                    int i = ((4 * (t + 1 - s)) % 11 + 11) % 11;
                    acc += w0[(o * 11 + i) * 9 + dr * 3 + dc];
                }
            T[(t * 3 + o) * 784 + pix] = acc;
        }
    } else if (blk == 10) {
        // WF4 flat idx = (((par*3+o)*4+uv)*3+cb)*4+j ; channel = 4*cb+j
        for (int idx = tid; idx < 576; idx += 256) {
            int j = idx & 3;
            int rest = idx >> 2;
            int cb = rest % 3;
            int rest2 = rest / 3;
            int uv = rest2 % 4;
            int rest3 = rest2 / 4;
            int o = rest3 % 3;
            int par = rest3 / 3;
            int ch = cb * 4 + j;
            float acc = 0.f;
            if (ch < 11) {
                int u = uv >> 1, v = uv & 1;
                int pr = par >> 1, pc = par & 1;
                for (int dr = 0; dr < 3; ++dr) {
                    bool rin = (pr == 0) ? (u == 0 ? dr == 0 : dr >= 1)
                                         : (u == 0 ? dr <= 1 : dr == 2);
                    if (!rin) continue;
                    for (int dc = 0; dc < 3; ++dc) {
                        bool cin = (pc == 0) ? (v == 0 ? dc == 0 : dc >= 1)
                                             : (v == 0 ? dc <= 1 : dc == 2);
                        if (cin) acc += dw1[(o * 11 + ch) * 9 + dr * 3 + dc];
                    }
                }
            }
            WF4[idx] = acc;
        }
        // per-tap packed conv1 / deconv2 weights: {w[t], w[9+t], w[18+t], 0}
        if (tid < 9) {
            w1p[tid * 4 + 0] = w1[tid];
            w1p[tid * 4 + 1] = w1[9 + tid];
            w1p[tid * 4 + 2] = w1[18 + tid];
            w1p[tid * 4 + 3] = 0.f;
        } else if (tid < 18) {
            int t = tid - 9;
            dw2p[t * 4 + 0] = dw2[t];
            dw2p[t * 4 + 1] = dw2[9 + t];
            dw2p[t * 4 + 2] = dw2[18 + t];
            dw2p[t * 4 + 3] = 0.f;
        }
    } else if (blk < 51) {
        // fc1_w fp32 [400,784] -> bf16 [400,800] (cols 784..799 zero)
        const int base = (blk - 11) * 8000;
        for (int i = tid; i < 8000; i += 256) {
            int flat = base + i;
            int n = flat / KP, k = flat % KP;
            float v = (k < 784) ? fc1w[n * 784 + k] : 0.f;
            wbf[flat] = __float2bfloat16(v);
        }
    } else {
        // fc2 weights -> bf16 [48,416]: rows 0-19 w21, 20-39 w22, 40-47 zero
        const int base = (blk - 51) * 2496;
        for (int i = tid; i < 2496; i += 256) {
            int flat = base + i;
            int j = flat / KP2, k = flat % KP2;
            float v = 0.f;
            if (k < 400) {
                if (j < 20)      v = w21[j * 400 + k];
                else if (j < 40) v = w22[(j - 20) * 400 + k];
            }
            w2bf[flat] = __float2bfloat16(v);
        }
    }
}

// ---------------------------------------------------------------------------
// K1: encoder — sparse-x conv0 (9 taps, packed f32) + class table T +
// conv1 (packed f32). writes h as bf16 [B][800]
// ---------------------------------------------------------------------------
__global__ __launch_bounds__(256, 4) void encoder_kernel(
    const float* __restrict__ x, const int* __restrict__ cls,
    const float* __restrict__ w0,    // [3,11,3,3]
    const float* __restrict__ w1p,   // [9] float4 packed
    const float* __restrict__ T,     // [10,3,784]
    __hip_bfloat16* __restrict__ h_bf)  // [B,800]
{
    __shared__ float  xs[30 * 30];      // scattered x image, zero border
    __shared__ float4 hs0[30 * 30];     // conv0 out (3ch + pad), zero border
    __shared__ float4 wt[99];           // [tap][ch] -> (w_o0, w_o1, w_o2, 0)

    const int b = blockIdx.x, tid = threadIdx.x;
    const int myc = cls[b];

    for (int i = tid; i < 116; i += 256) {
        int r, c;
        if (i < 30)      { r = 0;  c = i; }
        else if (i < 60) { r = 29; c = i - 30; }
        else if (i < 88) { r = 1 + (i - 60); c = 0; }
        else             { r = 1 + (i - 88); c = 29; }
        xs[r * 30 + c] = 0.f;
        hs0[r * 30 + c] = make_float4(0.f, 0.f, 0.f, 0.f);
    }
    for (int i = tid; i < 99; i += 256) {
        int tap = i / 11, ch = i % 11;
        wt[i] = make_float4(w0[ch * 9 + tap], w0[(11 + ch) * 9 + tap],
                            w0[(22 + ch) * 9 + tap], 0.f);
    }
    for (int s = tid; s < 784; s += 256) {
        int ch = (7 * s) % 11;
        int p = (ch * 784 + s) / 11;
        xs[(s / 28 + 1) * 30 + s % 28 + 1] = x[(size_t)b * IMG + p];
    }
    if (tid < 16) h_bf[(size_t)b * KP + 784 + tid] = __float2bfloat16(0.f);
    __syncthreads();

    const float* Tc = T + myc * 2352;
    for (int pix = tid; pix < 784; pix += 256) {
        int r = pix / 28, c = pix % 28;
        f32x4 A = {Tc[pix], Tc[784 + pix], Tc[1568 + pix], 0.f};
        int chbase = (9 * r + 7 * c + 6) % 11;
#pragma unroll
        for (int dr = 0; dr < 3; ++dr)
#pragma unroll
            for (int dc = 0; dc < 3; ++dc) {
                const int kk = (9 * dr + 7 * dc) % 11;  // compile-time
                int ch = chbase + kk;
                if (ch >= 11) ch -= 11;
                float v = xs[(r + dr) * 30 + c + dc];
                f32x4 w = *(const f32x4*)&wt[(dr * 3 + dc) * 11 + ch];
                f32x4 vv = {v, v, v, v};
                A = __builtin_elementwise_fma(vv, w, A);
            }
        hs0[(r + 1) * 30 + c + 1] =
            make_float4(fmaxf(A.x, 0.f), fmaxf(A.y, 0.f), fmaxf(A.z, 0.f), 0.f);
    }
    __syncthreads();

    const f32x4* w1v = (const f32x4*)w1p;
    for (int pix = tid; pix < 784; pix += 256) {
        int r = pix / 28, c = pix % 28;
        f32x4 A = {0.f, 0.f, 0.f, 0.f};
#pragma unroll
        for (int dr = 0; dr < 3; ++dr)
#pragma unroll
            for (int dc = 0; dc < 3; ++dc) {
                f32x4 v = *(const f32x4*)&hs0[(r + dr) * 30 + c + dc];
                A = __builtin_elementwise_fma(v, w1v[dr * 3 + dc], A);
            }
        float a = A.x + A.y + A.z;
        h_bf[(size_t)b * KP + pix] = __float2bfloat16(fmaxf(a, 0.f));
    }
}

// ---------------------------------------------------------------------------
// K2: fc1 via bf16 MFMA.  h1b[8192,416] = bf16(relu(h @ w^T + b))
// ---------------------------------------------------------------------------
__global__ __launch_bounds__(256) void fc1_mfma(
    const ushort* __restrict__ h_bf,  // [8192,800] bf16
    const ushort* __restrict__ w_bf,  // [400,800] bf16
    const float* __restrict__ bias,   // [400]
    __hip_bfloat16* __restrict__ h1b) // [8192,416] bf16
{
    __shared__ ushort Bs[80][40];   // B tile [n][k], stride 40 (pad)

    const int tid  = threadIdx.x;
    const int wid  = tid >> 6;
    const int lane = tid & 63;
    const int l15  = lane & 15;
    const int lq   = lane >> 4;       // k-quadrant 0..3
    const int bm   = blockIdx.x * 128;
    const int bn   = blockIdx.y * 80;

    f32x4 acc[2][5] = {};

    const int n0 = tid >> 2;          // 0..63  (staging row)
    const int kq0 = tid & 3;          // staging k-quadrant

    for (int k0 = 0; k0 < KP; k0 += 32) {
        bf16x8 s0 = *(const bf16x8*)&w_bf[(size_t)(bn + n0) * KP + k0 + kq0 * 8];
        bf16x8 s1;
        if (tid < 64)
            s1 = *(const bf16x8*)&w_bf[(size_t)(bn + 64 + n0) * KP + k0 + kq0 * 8];
        bf16x8 a0 = *(const bf16x8*)&h_bf[(size_t)(bm + wid * 32 + l15) * KP + k0 + lq * 8];
        bf16x8 a1 = *(const bf16x8*)&h_bf[(size_t)(bm + wid * 32 + 16 + l15) * KP + k0 + lq * 8];
        __syncthreads();
        *(bf16x8*)&Bs[n0][kq0 * 8] = s0;
        if (tid < 64) *(bf16x8*)&Bs[64 + n0][kq0 * 8] = s1;
        __syncthreads();
#pragma unroll
        for (int nf = 0; nf < 5; ++nf) {
            bf16x8 bfr = *(const bf16x8*)&Bs[nf * 16 + l15][lq * 8];
            acc[0][nf] = __builtin_amdgcn_mfma_f32_16x16x32_bf16(a0, bfr, acc[0][nf], 0, 0, 0);
            acc[1][nf] = __builtin_amdgcn_mfma_f32_16x16x32_bf16(a1, bfr, acc[1][nf], 0, 0, 0);
        }
    }

#pragma unroll
    for (int nf = 0; nf < 5; ++nf) {
        int col = bn + nf * 16 + l15;
        float bv = bias[col];
#pragma unroll
        for (int mr = 0; mr < 2; ++mr)
#pragma unroll
            for (int v = 0; v < 4; ++v) {
                int row = bm + wid * 32 + mr * 16 + lq * 4 + v;
                h1b[(size_t)row * KP2 + col] =
                    __float2bfloat16(fmaxf(acc[mr][nf][v] + bv, 0.f));
            }
    }
    if (blockIdx.y == 4) {
#pragma unroll
        for (int mr = 0; mr < 2; ++mr)
#pragma unroll
            for (int v = 0; v < 4; ++v) {
                int row = bm + wid * 32 + mr * 16 + lq * 4 + v;
                h1b[(size_t)row * KP2 + 400 + l15] = __float2bfloat16(0.f);
            }
    }
}

// ---------------------------------------------------------------------------
// K3: fc21 + fc22 via bf16 MFMA, no LDS.
// ---------------------------------------------------------------------------
__global__ __launch_bounds__(256) void fc2_mfma(
    const ushort* __restrict__ h1b,   // [8192,416] bf16
    const ushort* __restrict__ w2bf,  // [48,416] bf16
    const float* __restrict__ b21, const float* __restrict__ b22,
    float* __restrict__ out)
{
    const int tid  = threadIdx.x;
    const int wid  = tid >> 6;
    const int lane = tid & 63;
    const int l15  = lane & 15;
    const int lq   = lane >> 4;
    const int bm   = blockIdx.x * 128;

    f32x4 acc[2][3] = {};

    for (int k0 = 0; k0 < KP2; k0 += 32) {
        bf16x8 a0 = *(const bf16x8*)&h1b[(size_t)(bm + wid * 32 + l15) * KP2 + k0 + lq * 8];
        bf16x8 a1 = *(const bf16x8*)&h1b[(size_t)(bm + wid * 32 + 16 + l15) * KP2 + k0 + lq * 8];
#pragma unroll
        for (int nf = 0; nf < 3; ++nf) {
            bf16x8 bfr = *(const bf16x8*)&w2bf[(size_t)(nf * 16 + l15) * KP2 + k0 + lq * 8];
            acc[0][nf] = __builtin_amdgcn_mfma_f32_16x16x32_bf16(a0, bfr, acc[0][nf], 0, 0, 0);
            acc[1][nf] = __builtin_amdgcn_mfma_f32_16x16x32_bf16(a1, bfr, acc[1][nf], 0, 0, 0);
        }
    }

    const size_t base = (size_t)BATCH * IMG;
#pragma unroll
    for (int nf = 0; nf < 3; ++nf) {
        int col = nf * 16 + l15;
        if (col < 40) {
            bool is_mu = (col < 20);
            int ccol = is_mu ? col : col - 20;
            float bv = is_mu ? b21[ccol] : b22[ccol];
            size_t obase = is_mu ? base : base + (size_t)BATCH * 20;
#pragma unroll
            for (int mr = 0; mr < 2; ++mr)
#pragma unroll
                for (int v = 0; v < 4; ++v) {
                    int row = bm + wid * 32 + mr * 16 + lq * 4 + v;
                    out[obase + (size_t)row * 20 + ccol] = acc[mr][nf][v] + bv;
                }
        }
    }
}

// ---------------------------------------------------------------------------
// K4: decoder — fc3 + deconv0 + wave-parity deconv1 (packed f32x2 accum,
// SGPR weights via scalar pipe — no LDS weight traffic) + deconv2 + sigmoid
// ---------------------------------------------------------------------------
__global__ __launch_bounds__(256, 4) void decoder_kernel(
    const int* __restrict__ cls,
    const float* __restrict__ fc3_w,  // [392,30]
    const float* __restrict__ fc3_b,  // [392]
    const float* __restrict__ dw0,    // [11,2,3,3]
    const float* __restrict__ dw2p,   // [9] float4 packed
    const float* __restrict__ WF4g,   // 576 floats
    float* __restrict__ out)
{
    __shared__ float  z[32];
    __shared__ float  d0inS[2 * 16 * 17];  // [2][16][17]
    __shared__ float4 d0sp[3][16 * 16];    // per-cblk planes, ch-minor float4
    __shared__ float4 d1s[30 * 30];        // [30][30] (3ch + pad)

    const int b = blockIdx.x;
    const int tid = threadIdx.x;
    const int myc = cls[b];
    const float* mu = out + (size_t)BATCH * IMG + (size_t)b * 20;

    for (int i = tid; i < 2 * 16 * 17; i += 256) d0inS[i] = 0.f;
    for (int i = tid; i < 60; i += 256) {
        int r, c;
        if (i < 16)      { r = 0;  c = i; }
        else if (i < 32) { r = 15; c = i - 16; }
        else if (i < 46) { r = 1 + (i - 32); c = 0; }
        else             { r = 1 + (i - 46); c = 15; }
        int p = r * 16 + c;
        d0sp[0][p] = d0sp[1][p] = d0sp[2][p] = make_float4(0.f, 0.f, 0.f, 0.f);
    }
    for (int i = tid; i < 116; i += 256) {
        int r, c;
        if (i < 30)      { r = 0;  c = i; }
        else if (i < 60) { r = 29; c = i - 30; }
        else if (i < 88) { r = 1 + (i - 60); c = 0; }
        else             { r = 1 + (i - 88); c = 29; }
        d1s[r * 30 + c] = make_float4(0.f, 0.f, 0.f, 0.f);
    }
    if (tid < 20) z[tid] = mu[tid];
    else if (tid < 30) z[tid] = (tid - 20 == myc) ? 1.f : 0.f;
    __syncthreads();

    // fc3: [30] -> [392] + relu -> d0in [2][16][17] padded
    for (int j = tid; j < 392; j += 256) {
        float acc = fc3_b[j];
        const float2* wrow = (const float2*)&fc3_w[j * 30];
#pragma unroll
        for (int k = 0; k < 15; ++k) {
            float2 wv = wrow[k];
            acc += z[2 * k] * wv.x + z[2 * k + 1] * wv.y;
        }
        int ch = j / 196, rem = j % 196;
        d0inS[ch * 272 + (rem / 14 + 1) * 17 + (rem % 14 + 1)] = fmaxf(acc, 0.f);
    }
    __syncthreads();

    // deconv0: one thread per position, all 11 channels; weights -> s_loads
    if (tid < 196) {
        int r = tid / 14, c = tid % 14;
        float a[12] = {};
#pragma unroll
        for (int i = 0; i < 2; ++i)
#pragma unroll
            for (int dr = 0; dr < 3; ++dr)
#pragma unroll
                for (int dc = 0; dc < 3; ++dc) {
                    float v = d0inS[i * 272 + (r + dr) * 17 + (c + dc)];
#pragma unroll
                    for (int o = 0; o < 11; ++o)
                        a[o] += v * dw0[((o * 2 + i) * 3 + dr) * 3 + dc];
                }
        int p = (r + 1) * 16 + (c + 1);
        d0sp[0][p] = make_float4(fmaxf(a[0], 0.f), fmaxf(a[1], 0.f),
                                 fmaxf(a[2], 0.f), fmaxf(a[3], 0.f));
        d0sp[1][p] = make_float4(fmaxf(a[4], 0.f), fmaxf(a[5], 0.f),
                                 fmaxf(a[6], 0.f), fmaxf(a[7], 0.f));
        d0sp[2][p] = make_float4(fmaxf(a[8], 0.f), fmaxf(a[9], 0.f),
                                 fmaxf(a[10], 0.f), 0.f);
    }
    __syncthreads();

    // deconv1: wave w owns parity w. Vertical q-pair per thread; f32x2
    // packed accumulators; weights read through a wave-uniform global
    // pointer -> s_load_dwordx4, consumed as the SGPR operand of v_pk_fma.
    {
        const int wid  = tid >> 6;          // parity, wave-uniform
        const int lane = tid & 63;
        const int pr = wid >> 1, pc = wid & 1;
        // wave-uniform scalar base: weights live in SGPRs, not LDS/VGPR
        const f32x4* wgs = (const f32x4*)(WF4g +
            __builtin_amdgcn_readfirstlane(wid) * 144);
#pragma unroll 1
        for (int pp = 0; pp < 2; ++pp) {
            int pi = pp * 64 + lane;
            if (pi < 98) {
                int qpr = pi / 14, qc = pi - qpr * 14;
                int qr0 = qpr * 2;
                int base = (qr0 + pr) * 16 + qc + pc;
                f32x2 A0[3] = {{0.f, 0.f}, {0.f, 0.f}, {0.f, 0.f}};
                f32x2 A1[3] = {{0.f, 0.f}, {0.f, 0.f}, {0.f, 0.f}};
#pragma unroll
                for (int cb = 0; cb < 3; ++cb) {
                    f32x4 v0 = *(const f32x4*)&d0sp[cb][base];
                    f32x4 v1 = *(const f32x4*)&d0sp[cb][base + 1];
                    f32x4 v2 = *(const f32x4*)&d0sp[cb][base + 16];
                    f32x4 v3 = *(const f32x4*)&d0sp[cb][base + 17];
                    f32x4 v4 = *(const f32x4*)&d0sp[cb][base + 32];
                    f32x4 v5 = *(const f32x4*)&d0sp[cb][base + 33];
#pragma unroll
                    for (int o = 0; o < 3; ++o) {
                        f32x4 w00 = wgs[(o * 4 + 0) * 3 + cb];
                        f32x4 w01 = wgs[(o * 4 + 1) * 3 + cb];
                        f32x4 w10 = wgs[(o * 4 + 2) * 3 + cb];
                        f32x4 w11 = wgs[(o * 4 + 3) * 3 + cb];
                        A0[o] = __builtin_elementwise_fma(v0.lo, w00.lo, A0[o]);
                        A0[o] = __builtin_elementwise_fma(v0.hi, w00.hi, A0[o]);
                        A0[o] = __builtin_elementwise_fma(v1.lo, w01.lo, A0[o]);
                        A0[o] = __builtin_elementwise_fma(v1.hi, w01.hi, A0[o]);
                        A0[o] = __builtin_elementwise_fma(v2.lo, w10.lo, A0[o]);
                        A0[o] = __builtin_elementwise_fma(v2.hi, w10.hi, A0[o]);
                        A0[o] = __builtin_elementwise_fma(v3.lo, w11.lo, A0[o]);
                        A0[o] = __builtin_elementwise_fma(v3.hi, w11.hi, A0[o]);
                        A1[o] = __builtin_elementwise_fma(v2.lo, w00.lo, A1[o]);
                        A1[o] = __builtin_elementwise_fma(v2.hi, w00.hi, A1[o]);
                        A1[o] = __builtin_elementwise_fma(v3.lo, w01.lo, A1[o]);
                        A1[o] = __builtin_elementwise_fma(v3.hi, w01.hi, A1[o]);
                        A1[o] = __builtin_elementwise_fma(v4.lo, w10.lo, A1[o]);
                        A1[o] = __builtin_elementwise_fma(v4.hi, w10.hi, A1[o]);
                        A1[o] = __builtin_elementwise_fma(v5.lo, w11.lo, A1[o]);
                        A1[o] = __builtin_elementwise_fma(v5.hi, w11.hi, A1[o]);
                    }
                }
                int r0 = 2 * qr0 + pr, c = 2 * qc + pc;
                d1s[(r0 + 1) * 30 + c + 1] =
                    make_float4(fmaxf(A0[0].x + A0[0].y, 0.f),
                                fmaxf(A0[1].x + A0[1].y, 0.f),
                                fmaxf(A0[2].x + A0[2].y, 0.f), 0.f);
                d1s[(r0 + 3) * 30 + c + 1] =
                    make_float4(fmaxf(A1[0].x + A1[0].y, 0.f),
                                fmaxf(A1[1].x + A1[1].y, 0.f),
                                fmaxf(A1[2].x + A1[2].y, 0.f), 0.f);
            }
        }
    }
    __syncthreads();

    // deconv2 (3->1, packed per-tap weights) + sigmoid
    const f32x4* dw2v = (const f32x4*)dw2p;
    for (int pix = tid; pix < 784; pix += 256) {
        int r = pix / 28, c = pix % 28;
        f32x4 A = {0.f, 0.f, 0.f, 0.f};
#pragma unroll
        for (int dr = 0; dr < 3; ++dr)
#pragma unroll
            for (int dc = 0; dc < 3; ++dc) {
                f32x4 v = *(const f32x4*)&d1s[(r + dr) * 30 + c + dc];
                A = __builtin_elementwise_fma(v, dw2v[dr * 3 + dc], A);
            }
        float a = A.x + A.y + A.z;
        out[(size_t)b * IMG + pix] = 1.f / (1.f + expf(-a));
    }
}

// ---------------------------------------------------------------------------
extern "C" void kernel_launch(void* const* d_in, const int* in_sizes, int n_in,
                              void* d_out, int out_size, void* d_ws, size_t ws_size,
                              hipStream_t stream) {
    const float* x     = (const float*)d_in[0];
    const int*   cls   = (const int*)d_in[1];
    const float* w0    = (const float*)d_in[2];
    const float* w1    = (const float*)d_in[3];
    const float* fc1_w = (const float*)d_in[4];
    const float* fc1_b = (const float*)d_in[5];
    const float* w21   = (const float*)d_in[6];
    const float* b21   = (const float*)d_in[7];
    const float* w22   = (const float*)d_in[8];
    const float* b22   = (const float*)d_in[9];
    const float* fc3_w = (const float*)d_in[10];
    const float* fc3_b = (const float*)d_in[11];
    const float* dw0   = (const float*)d_in[12];
    const float* dw1   = (const float*)d_in[13];
    const float* dw2   = (const float*)d_in[14];

    float* out = (float*)d_out;
    char*  ws  = (char*)d_ws;
    __hip_bfloat16* h_bf = (__hip_bfloat16*)ws;                       // 8192*800 bf16
    __hip_bfloat16* h1b  = (__hip_bfloat16*)(ws + (size_t)BATCH * KP * 2);  // 8192*416 bf16
    float* T    = (float*)(ws + (size_t)BATCH * KP * 2 + (size_t)BATCH * KP2 * 2);
    float* WF4  = T + 10 * 3 * 784;
    __hip_bfloat16* w_bf  = (__hip_bfloat16*)(WF4 + 576);             // 400*800
    __hip_bfloat16* w2bf  = w_bf + 400 * KP;                          // 48*416
    float* w1p  = (float*)(w2bf + 48 * KP2);                          // 36 floats
    float* dw2p = w1p + 36;                                           // 36 floats

    precompute_kernel<<<59, 256, 0, stream>>>(w0, w1, dw1, dw2, fc1_w, w21, w22,
                                              T, WF4, w1p, dw2p, w_bf, w2bf);
    encoder_kernel<<<BATCH, 256, 0, stream>>>(x, cls, w0, w1p, T, h_bf);
    fc1_mfma<<<dim3(64, 5), 256, 0, stream>>>((const ushort*)h_bf,
                                              (const ushort*)w_bf, fc1_b, h1b);
    fc2_mfma<<<64, 256, 0, stream>>>((const ushort*)h1b, (const ushort*)w2bf,
                                     b21, b22, out);
    decoder_kernel<<<BATCH, 256, 0, stream>>>(cls, fc3_w, fc3_b, dw0, dw2p, WF4, out);
}

// Round 13
// 141.011 us; speedup vs baseline: 5.4551x; 1.0146x over previous
//
#include <hip/hip_runtime.h>
#include <hip/hip_bf16.h>
#include <math.h>

#define BATCH 8192
#define IMG 784   // 28*28
#define KP 800    // fc1 K padded to multiple of 32
#define KP2 416   // fc2 K padded (400 -> 416)

typedef short  bf16x8 __attribute__((ext_vector_type(8)));
typedef float  f32x4  __attribute__((ext_vector_type(4)));
typedef float  f32x2  __attribute__((ext_vector_type(2)));

// ---------------------------------------------------------------------------
// K0: precompute (a) per-class conv0 one-hot tables T[10][3][784],
// (b) parity-folded deconv1 weights WF4 + per-tap packed w1p/dw2p,
// (c) fc1_w -> bf16 [400][800], (d) fc2 weights -> bf16 [48][416].
// ---------------------------------------------------------------------------
__global__ __launch_bounds__(256) void precompute_kernel(
    const float* __restrict__ w0,    // [3,11,3,3]
    const float* __restrict__ w1,    // [1,3,3,3]
    const float* __restrict__ dw1,   // [3,11,3,3]
    const float* __restrict__ dw2,   // [1,3,3,3]
    const float* __restrict__ fc1w,  // [400,784]
    const float* __restrict__ w21,   // [20,400]
    const float* __restrict__ w22,   // [20,400]
    float* __restrict__ T,           // [10,3,784]
    float* __restrict__ WF4,         // 576 floats
    float* __restrict__ w1p,         // [9]*4 floats
    float* __restrict__ dw2p,        // [9]*4 floats
    __hip_bfloat16* __restrict__ wbf,  // [400,800]
    __hip_bfloat16* __restrict__ w2bf) // [48,416]
{
    const int blk = blockIdx.x, tid = threadIdx.x;
    if (blk < 10) {
        const int t = blk;
        for (int idx = tid; idx < 3 * 784; idx += 256) {
            int o = idx / 784, pix = idx % 784;
            int r = pix / 28, c = pix % 28;
            float acc = 0.f;
#pragma unroll
            for (int dr = 0; dr < 3; ++dr)
#pragma unroll
                for (int dc = 0; dc < 3; ++dc) {
                    int rr = r + dr - 1, cc = c + dc - 1;
                    if (rr < 0 || rr > 27 || cc < 0 || cc > 27) continue;
                    int s = rr * 28 + cc;
                    int i = ((4 * (t + 1 - s)) % 11 + 11) % 11;
                    acc += w0[(o * 11 + i) * 9 + dr * 3 + dc];
                }
            T[(t * 3 + o) * 784 + pix] = acc;
        }
    } else if (blk == 10) {
        // WF4 flat idx = (((par*3+o)*4+uv)*3+cb)*4+j ; channel = 4*cb+j
        for (int idx = tid; idx < 576; idx += 256) {
            int j = idx & 3;
            int rest = idx >> 2;
            int cb = rest % 3;
            int rest2 = rest / 3;
            int uv = rest2 % 4;
            int rest3 = rest2 / 4;
            int o = rest3 % 3;
            int par = rest3 / 3;
            int ch = cb * 4 + j;
            float acc = 0.f;
            if (ch < 11) {
                int u = uv >> 1, v = uv & 1;
                int pr = par >> 1, pc = par & 1;
                for (int dr = 0; dr < 3; ++dr) {
                    bool rin = (pr == 0) ? (u == 0 ? dr == 0 : dr >= 1)
                                         : (u == 0 ? dr <= 1 : dr == 2);
                    if (!rin) continue;
                    for (int dc = 0; dc < 3; ++dc) {
                        bool cin = (pc == 0) ? (v == 0 ? dc == 0 : dc >= 1)
                                             : (v == 0 ? dc <= 1 : dc == 2);
                        if (cin) acc += dw1[(o * 11 + ch) * 9 + dr * 3 + dc];
                    }
                }
            }
            WF4[idx] = acc;
        }
        // per-tap packed conv1 / deconv2 weights: {w[t], w[9+t], w[18+t], 0}
        if (tid < 9) {
            w1p[tid * 4 + 0] = w1[tid];
            w1p[tid * 4 + 1] = w1[9 + tid];
            w1p[tid * 4 + 2] = w1[18 + tid];
            w1p[tid * 4 + 3] = 0.f;
        } else if (tid < 18) {
            int t = tid - 9;
            dw2p[t * 4 + 0] = dw2[t];
            dw2p[t * 4 + 1] = dw2[9 + t];
            dw2p[t * 4 + 2] = dw2[18 + t];
            dw2p[t * 4 + 3] = 0.f;
        }
    } else if (blk < 51) {
        // fc1_w fp32 [400,784] -> bf16 [400,800] (cols 784..799 zero)
        const int base = (blk - 11) * 8000;
        for (int i = tid; i < 8000; i += 256) {
            int flat = base + i;
            int n = flat / KP, k = flat % KP;
            float v = (k < 784) ? fc1w[n * 784 + k] : 0.f;
            wbf[flat] = __float2bfloat16(v);
        }
    } else {
        // fc2 weights -> bf16 [48,416]: rows 0-19 w21, 20-39 w22, 40-47 zero
        const int base = (blk - 51) * 2496;
        for (int i = tid; i < 2496; i += 256) {
            int flat = base + i;
            int j = flat / KP2, k = flat % KP2;
            float v = 0.f;
            if (k < 400) {
                if (j < 20)      v = w21[j * 400 + k];
                else if (j < 40) v = w22[(j - 20) * 400 + k];
            }
            w2bf[flat] = __float2bfloat16(v);
        }
    }
}

// ---------------------------------------------------------------------------
// K1: encoder — sparse-x conv0 (9 taps, packed f32) + class table T +
// conv1 (packed f32). writes h as bf16 [B][800]
// ---------------------------------------------------------------------------
__global__ __launch_bounds__(256, 4) void encoder_kernel(
    const float* __restrict__ x, const int* __restrict__ cls,
    const float* __restrict__ w0,    // [3,11,3,3]
    const float* __restrict__ w1p,   // [9] float4 packed
    const float* __restrict__ T,     // [10,3,784]
    __hip_bfloat16* __restrict__ h_bf)  // [B,800]
{
    __shared__ float  xs[30 * 30];      // scattered x image, zero border
    __shared__ float4 hs0[30 * 30];     // conv0 out (3ch + pad), zero border
    __shared__ float4 wt[99];           // [tap][ch] -> (w_o0, w_o1, w_o2, 0)

    const int b = blockIdx.x, tid = threadIdx.x;
    const int myc = cls[b];

    for (int i = tid; i < 116; i += 256) {
        int r, c;
        if (i < 30)      { r = 0;  c = i; }
        else if (i < 60) { r = 29; c = i - 30; }
        else if (i < 88) { r = 1 + (i - 60); c = 0; }
        else             { r = 1 + (i - 88); c = 29; }
        xs[r * 30 + c] = 0.f;
        hs0[r * 30 + c] = make_float4(0.f, 0.f, 0.f, 0.f);
    }
    for (int i = tid; i < 99; i += 256) {
        int tap = i / 11, ch = i % 11;
        wt[i] = make_float4(w0[ch * 9 + tap], w0[(11 + ch) * 9 + tap],
                            w0[(22 + ch) * 9 + tap], 0.f);
    }
    for (int s = tid; s < 784; s += 256) {
        int ch = (7 * s) % 11;
        int p = (ch * 784 + s) / 11;
        xs[(s / 28 + 1) * 30 + s % 28 + 1] = x[(size_t)b * IMG + p];
    }
    if (tid < 16) h_bf[(size_t)b * KP + 784 + tid] = __float2bfloat16(0.f);
    __syncthreads();

    const float* Tc = T + myc * 2352;
    for (int pix = tid; pix < 784; pix += 256) {
        int r = pix / 28, c = pix % 28;
        f32x4 A = {Tc[pix], Tc[784 + pix], Tc[1568 + pix], 0.f};
        int chbase = (9 * r + 7 * c + 6) % 11;
#pragma unroll
        for (int dr = 0; dr < 3; ++dr)
#pragma unroll
            for (int dc = 0; dc < 3; ++dc) {
                const int kk = (9 * dr + 7 * dc) % 11;  // compile-time
                int ch = chbase + kk;
                if (ch >= 11) ch -= 11;
                float v = xs[(r + dr) * 30 + c + dc];
                f32x4 w = *(const f32x4*)&wt[(dr * 3 + dc) * 11 + ch];
                f32x4 vv = {v, v, v, v};
                A = __builtin_elementwise_fma(vv, w, A);
            }
        hs0[(r + 1) * 30 + c + 1] =
            make_float4(fmaxf(A.x, 0.f), fmaxf(A.y, 0.f), fmaxf(A.z, 0.f), 0.f);
    }
    __syncthreads();

    const f32x4* w1v = (const f32x4*)w1p;
    for (int pix = tid; pix < 784; pix += 256) {
        int r = pix / 28, c = pix % 28;
        f32x4 A = {0.f, 0.f, 0.f, 0.f};
#pragma unroll
        for (int dr = 0; dr < 3; ++dr)
#pragma unroll
            for (int dc = 0; dc < 3; ++dc) {
                f32x4 v = *(const f32x4*)&hs0[(r + dr) * 30 + c + dc];
                A = __builtin_elementwise_fma(v, w1v[dr * 3 + dc], A);
            }
        float a = A.x + A.y + A.z;
        h_bf[(size_t)b * KP + pix] = __float2bfloat16(fmaxf(a, 0.f));
    }
}

// ---------------------------------------------------------------------------
// K2: fc1 via bf16 MFMA.  h1b[8192,416] = bf16(relu(h @ w^T + b))
// ---------------------------------------------------------------------------
__global__ __launch_bounds__(256) void fc1_mfma(
    const ushort* __restrict__ h_bf,  // [8192,800] bf16
    const ushort* __restrict__ w_bf,  // [400,800] bf16
    const float* __restrict__ bias,   // [400]
    __hip_bfloat16* __restrict__ h1b) // [8192,416] bf16
{
    __shared__ ushort Bs[80][40];   // B tile [n][k], stride 40 (pad)

    const int tid  = threadIdx.x;
    const int wid  = tid >> 6;
    const int lane = tid & 63;
    const int l15  = lane & 15;
    const int lq   = lane >> 4;       // k-quadrant 0..3
    const int bm   = blockIdx.x * 128;
    const int bn   = blockIdx.y * 80;

    f32x4 acc[2][5] = {};

    const int n0 = tid >> 2;          // 0..63  (staging row)
    const int kq0 = tid & 3;          // staging k-quadrant

    for (int k0 = 0; k0 < KP; k0 += 32) {
        bf16x8 s0 = *(const bf16x8*)&w_bf[(size_t)(bn + n0) * KP + k0 + kq0 * 8];
        bf16x8 s1;
        if (tid < 64)
            s1 = *(const bf16x8*)&w_bf[(size_t)(bn + 64 + n0) * KP + k0 + kq0 * 8];
        bf16x8 a0 = *(const bf16x8*)&h_bf[(size_t)(bm + wid * 32 + l15) * KP + k0 + lq * 8];
        bf16x8 a1 = *(const bf16x8*)&h_bf[(size_t)(bm + wid * 32 + 16 + l15) * KP + k0 + lq * 8];
        __syncthreads();
        *(bf16x8*)&Bs[n0][kq0 * 8] = s0;
        if (tid < 64) *(bf16x8*)&Bs[64 + n0][kq0 * 8] = s1;
        __syncthreads();
#pragma unroll
        for (int nf = 0; nf < 5; ++nf) {
            bf16x8 bfr = *(const bf16x8*)&Bs[nf * 16 + l15][lq * 8];
            acc[0][nf] = __builtin_amdgcn_mfma_f32_16x16x32_bf16(a0, bfr, acc[0][nf], 0, 0, 0);
            acc[1][nf] = __builtin_amdgcn_mfma_f32_16x16x32_bf16(a1, bfr, acc[1][nf], 0, 0, 0);
        }
    }

#pragma unroll
    for (int nf = 0; nf < 5; ++nf) {
        int col = bn + nf * 16 + l15;
        float bv = bias[col];
#pragma unroll
        for (int mr = 0; mr < 2; ++mr)
#pragma unroll
            for (int v = 0; v < 4; ++v) {
                int row = bm + wid * 32 + mr * 16 + lq * 4 + v;
                h1b[(size_t)row * KP2 + col] =
                    __float2bfloat16(fmaxf(acc[mr][nf][v] + bv, 0.f));
            }
    }
    if (blockIdx.y == 4) {
#pragma unroll
        for (int mr = 0; mr < 2; ++mr)
#pragma unroll
            for (int v = 0; v < 4; ++v) {
                int row = bm + wid * 32 + mr * 16 + lq * 4 + v;
                h1b[(size_t)row * KP2 + 400 + l15] = __float2bfloat16(0.f);
            }
    }
}

// ---------------------------------------------------------------------------
// K3: fc21 + fc22 via bf16 MFMA, no LDS.
// ---------------------------------------------------------------------------
__global__ __launch_bounds__(256) void fc2_mfma(
    const ushort* __restrict__ h1b,   // [8192,416] bf16
    const ushort* __restrict__ w2bf,  // [48,416] bf16
    const float* __restrict__ b21, const float* __restrict__ b22,
    float* __restrict__ out)
{
    const int tid  = threadIdx.x;
    const int wid  = tid >> 6;
    const int lane = tid & 63;
    const int l15  = lane & 15;
    const int lq   = lane >> 4;
    const int bm   = blockIdx.x * 128;

    f32x4 acc[2][3] = {};

    for (int k0 = 0; k0 < KP2; k0 += 32) {
        bf16x8 a0 = *(const bf16x8*)&h1b[(size_t)(bm + wid * 32 + l15) * KP2 + k0 + lq * 8];
        bf16x8 a1 = *(const bf16x8*)&h1b[(size_t)(bm + wid * 32 + 16 + l15) * KP2 + k0 + lq * 8];
#pragma unroll
        for (int nf = 0; nf < 3; ++nf) {
            bf16x8 bfr = *(const bf16x8*)&w2bf[(size_t)(nf * 16 + l15) * KP2 + k0 + lq * 8];
            acc[0][nf] = __builtin_amdgcn_mfma_f32_16x16x32_bf16(a0, bfr, acc[0][nf], 0, 0, 0);
            acc[1][nf] = __builtin_amdgcn_mfma_f32_16x16x32_bf16(a1, bfr, acc[1][nf], 0, 0, 0);
        }
    }

    const size_t base = (size_t)BATCH * IMG;
#pragma unroll
    for (int nf = 0; nf < 3; ++nf) {
        int col = nf * 16 + l15;
        if (col < 40) {
            bool is_mu = (col < 20);
            int ccol = is_mu ? col : col - 20;
            float bv = is_mu ? b21[ccol] : b22[ccol];
            size_t obase = is_mu ? base : base + (size_t)BATCH * 20;
#pragma unroll
            for (int mr = 0; mr < 2; ++mr)
#pragma unroll
                for (int v = 0; v < 4; ++v) {
                    int row = bm + wid * 32 + mr * 16 + lq * 4 + v;
                    out[obase + (size_t)row * 20 + ccol] = acc[mr][nf][v] + bv;
                }
        }
    }
}

// ---------------------------------------------------------------------------
// K4: decoder — fc3 + deconv0 + wave-parity deconv1 (packed f32x2, SGPR
// weights) + deconv2 + sigmoid.  d0in aliased onto d1s (disjoint lifetimes)
// -> LDS 26.9KB -> 6 blocks/CU; __launch_bounds__(256,8) for 64-VGPR cap.
// ---------------------------------------------------------------------------
__global__ __launch_bounds__(256, 8) void decoder_kernel(
    const int* __restrict__ cls,
    const float* __restrict__ fc3_w,  // [392,30]
    const float* __restrict__ fc3_b,  // [392]
    const float* __restrict__ dw0,    // [11,2,3,3]
    const float* __restrict__ dw2p,   // [9] float4 packed
    const float* __restrict__ WF4g,   // 576 floats
    float* __restrict__ out)
{
    __shared__ float  z[32];
    __shared__ float4 d0sp[3][16 * 16];    // per-cblk planes, ch-minor float4
    __shared__ float4 d1s[30 * 30];        // [30][30] (3ch + pad); ALSO hosts
                                           // d0in [2][16][17] f32 (first 544
                                           // floats) during fc3/deconv0 phase
    float* d0inS = (float*)d1s;

    const int b = blockIdx.x;
    const int tid = threadIdx.x;
    const int myc = cls[b];
    const float* mu = out + (size_t)BATCH * IMG + (size_t)b * 20;

    // zero d0in fully (lives in d1s region); d0sp borders only
    for (int i = tid; i < 2 * 16 * 17; i += 256) d0inS[i] = 0.f;
    for (int i = tid; i < 60; i += 256) {
        int r, c;
        if (i < 16)      { r = 0;  c = i; }
        else if (i < 32) { r = 15; c = i - 16; }
        else if (i < 46) { r = 1 + (i - 32); c = 0; }
        else             { r = 1 + (i - 46); c = 15; }
        int p = r * 16 + c;
        d0sp[0][p] = d0sp[1][p] = d0sp[2][p] = make_float4(0.f, 0.f, 0.f, 0.f);
    }
    if (tid < 20) z[tid] = mu[tid];
    else if (tid < 30) z[tid] = (tid - 20 == myc) ? 1.f : 0.f;
    __syncthreads();

    // fc3: [30] -> [392] + relu -> d0in [2][16][17] padded
    for (int j = tid; j < 392; j += 256) {
        float acc = fc3_b[j];
        const float2* wrow = (const float2*)&fc3_w[j * 30];
#pragma unroll
        for (int k = 0; k < 15; ++k) {
            float2 wv = wrow[k];
            acc += z[2 * k] * wv.x + z[2 * k + 1] * wv.y;
        }
        int ch = j / 196, rem = j % 196;
        d0inS[ch * 272 + (rem / 14 + 1) * 17 + (rem % 14 + 1)] = fmaxf(acc, 0.f);
    }
    __syncthreads();

    // deconv0: one thread per position, all 11 channels; weights -> s_loads
    if (tid < 196) {
        int r = tid / 14, c = tid % 14;
        float a[12] = {};
#pragma unroll
        for (int i = 0; i < 2; ++i)
#pragma unroll
            for (int dr = 0; dr < 3; ++dr)
#pragma unroll
                for (int dc = 0; dc < 3; ++dc) {
                    float v = d0inS[i * 272 + (r + dr) * 17 + (c + dc)];
#pragma unroll
                    for (int o = 0; o < 11; ++o)
                        a[o] += v * dw0[((o * 2 + i) * 3 + dr) * 3 + dc];
                }
        int p = (r + 1) * 16 + (c + 1);
        d0sp[0][p] = make_float4(fmaxf(a[0], 0.f), fmaxf(a[1], 0.f),
                                 fmaxf(a[2], 0.f), fmaxf(a[3], 0.f));
        d0sp[1][p] = make_float4(fmaxf(a[4], 0.f), fmaxf(a[5], 0.f),
                                 fmaxf(a[6], 0.f), fmaxf(a[7], 0.f));
        d0sp[2][p] = make_float4(fmaxf(a[8], 0.f), fmaxf(a[9], 0.f),
                                 fmaxf(a[10], 0.f), 0.f);
    }
    __syncthreads();   // d0in reads done -> d1s region free for reuse

    // d1s border zeroing, same phase as deconv1 (disjoint addresses)
    for (int i = tid; i < 116; i += 256) {
        int r, c;
        if (i < 30)      { r = 0;  c = i; }
        else if (i < 60) { r = 29; c = i - 30; }
        else if (i < 88) { r = 1 + (i - 60); c = 0; }
        else             { r = 1 + (i - 88); c = 29; }
        d1s[r * 30 + c] = make_float4(0.f, 0.f, 0.f, 0.f);
    }

    // deconv1: wave w owns parity w. Vertical q-pair per thread; f32x2
    // packed accumulators; weights via wave-uniform global -> SGPRs.
    {
        const int wid  = tid >> 6;          // parity, wave-uniform
        const int lane = tid & 63;
        const int pr = wid >> 1, pc = wid & 1;
        const f32x4* wgs = (const f32x4*)(WF4g +
            __builtin_amdgcn_readfirstlane(wid) * 144);
#pragma unroll 1
        for (int pp = 0; pp < 2; ++pp) {
            int pi = pp * 64 + lane;
            if (pi < 98) {
                int qpr = pi / 14, qc = pi - qpr * 14;
                int qr0 = qpr * 2;
                int base = (qr0 + pr) * 16 + qc + pc;
                f32x2 A0[3] = {{0.f, 0.f}, {0.f, 0.f}, {0.f, 0.f}};
                f32x2 A1[3] = {{0.f, 0.f}, {0.f, 0.f}, {0.f, 0.f}};
#pragma unroll
                for (int cb = 0; cb < 3; ++cb) {
                    f32x4 v0 = *(const f32x4*)&d0sp[cb][base];
                    f32x4 v1 = *(const f32x4*)&d0sp[cb][base + 1];
                    f32x4 v2 = *(const f32x4*)&d0sp[cb][base + 16];
                    f32x4 v3 = *(const f32x4*)&d0sp[cb][base + 17];
                    f32x4 v4 = *(const f32x4*)&d0sp[cb][base + 32];
                    f32x4 v5 = *(const f32x4*)&d0sp[cb][base + 33];
#pragma unroll
                    for (int o = 0; o < 3; ++o) {
                        f32x4 w00 = wgs[(o * 4 + 0) * 3 + cb];
                        f32x4 w01 = wgs[(o * 4 + 1) * 3 + cb];
                        f32x4 w10 = wgs[(o * 4 + 2) * 3 + cb];
                        f32x4 w11 = wgs[(o * 4 + 3) * 3 + cb];
                        A0[o] = __builtin_elementwise_fma(v0.lo, w00.lo, A0[o]);
                        A0[o] = __builtin_elementwise_fma(v0.hi, w00.hi, A0[o]);
                        A0[o] = __builtin_elementwise_fma(v1.lo, w01.lo, A0[o]);
                        A0[o] = __builtin_elementwise_fma(v1.hi, w01.hi, A0[o]);
                        A0[o] = __builtin_elementwise_fma(v2.lo, w10.lo, A0[o]);
                        A0[o] = __builtin_elementwise_fma(v2.hi, w10.hi, A0[o]);
                        A0[o] = __builtin_elementwise_fma(v3.lo, w11.lo, A0[o]);
                        A0[o] = __builtin_elementwise_fma(v3.hi, w11.hi, A0[o]);
                        A1[o] = __builtin_elementwise_fma(v2.lo, w00.lo, A1[o]);
                        A1[o] = __builtin_elementwise_fma(v2.hi, w00.hi, A1[o]);
                        A1[o] = __builtin_elementwise_fma(v3.lo, w01.lo, A1[o]);
                        A1[o] = __builtin_elementwise_fma(v3.hi, w01.hi, A1[o]);
                        A1[o] = __builtin_elementwise_fma(v4.lo, w10.lo, A1[o]);
                        A1[o] = __builtin_elementwise_fma(v4.hi, w10.hi, A1[o]);
                        A1[o] = __builtin_elementwise_fma(v5.lo, w11.lo, A1[o]);
                        A1[o] = __builtin_elementwise_fma(v5.hi, w11.hi, A1[o]);
                    }
                }
                int r0 = 2 * qr0 + pr, c = 2 * qc + pc;
                d1s[(r0 + 1) * 30 + c + 1] =
                    make_float4(fmaxf(A0[0].x + A0[0].y, 0.f),
                                fmaxf(A0[1].x + A0[1].y, 0.f),
                                fmaxf(A0[2].x + A0[2].y, 0.f), 0.f);
                d1s[(r0 + 3) * 30 + c + 1] =
                    make_float4(fmaxf(A1[0].x + A1[0].y, 0.f),
                                fmaxf(A1[1].x + A1[1].y, 0.f),
                                fmaxf(A1[2].x + A1[2].y, 0.f), 0.f);
            }
        }
    }
    __syncthreads();

    // deconv2 (3->1, packed per-tap weights) + sigmoid
    const f32x4* dw2v = (const f32x4*)dw2p;
    for (int pix = tid; pix < 784; pix += 256) {
        int r = pix / 28, c = pix % 28;
        f32x4 A = {0.f, 0.f, 0.f, 0.f};
#pragma unroll
        for (int dr = 0; dr < 3; ++dr)
#pragma unroll
            for (int dc = 0; dc < 3; ++dc) {
                f32x4 v = *(const f32x4*)&d1s[(r + dr) * 30 + c + dc];
                A = __builtin_elementwise_fma(v, dw2v[dr * 3 + dc], A);
            }
        float a = A.x + A.y + A.z;
        out[(size_t)b * IMG + pix] = 1.f / (1.f + expf(-a));
    }
}

// ---------------------------------------------------------------------------
extern "C" void kernel_launch(void* const* d_in, const int* in_sizes, int n_in,
                              void* d_out, int out_size, void* d_ws, size_t ws_size,
                              hipStream_t stream) {
    const float* x     = (const float*)d_in[0];
    const int*   cls   = (const int*)d_in[1];
    const float* w0    = (const float*)d_in[2];
    const float* w1    = (const float*)d_in[3];
    const float* fc1_w = (const float*)d_in[4];
    const float* fc1_b = (const float*)d_in[5];
    const float* w21   = (const float*)d_in[6];
    const float* b21   = (const float*)d_in[7];
    const float* w22   = (const float*)d_in[8];
    const float* b22   = (const float*)d_in[9];
    const float* fc3_w = (const float*)d_in[10];
    const float* fc3_b = (const float*)d_in[11];
    const float* dw0   = (const float*)d_in[12];
    const float* dw1   = (const float*)d_in[13];
    const float* dw2   = (const float*)d_in[14];

    float* out = (float*)d_out;
    char*  ws  = (char*)d_ws;
    __hip_bfloat16* h_bf = (__hip_bfloat16*)ws;                       // 8192*800 bf16
    __hip_bfloat16* h1b  = (__hip_bfloat16*)(ws + (size_t)BATCH * KP * 2);  // 8192*416 bf16
    float* T    = (float*)(ws + (size_t)BATCH * KP * 2 + (size_t)BATCH * KP2 * 2);
    float* WF4  = T + 10 * 3 * 784;
    __hip_bfloat16* w_bf  = (__hip_bfloat16*)(WF4 + 576);             // 400*800
    __hip_bfloat16* w2bf  = w_bf + 400 * KP;                          // 48*416
    float* w1p  = (float*)(w2bf + 48 * KP2);                          // 36 floats
    float* dw2p = w1p + 36;                                           // 36 floats

    precompute_kernel<<<59, 256, 0, stream>>>(w0, w1, dw1, dw2, fc1_w, w21, w22,
                                              T, WF4, w1p, dw2p, w_bf, w2bf);
    encoder_kernel<<<BATCH, 256, 0, stream>>>(x, cls, w0, w1p, T, h_bf);
    fc1_mfma<<<dim3(64, 5), 256, 0, stream>>>((const ushort*)h_bf,
                                              (const ushort*)w_bf, fc1_b, h1b);
    fc2_mfma<<<64, 256, 0, stream>>>((const ushort*)h1b, (const ushort*)w2bf,
                                     b21, b22, out);
    decoder_kernel<<<BATCH, 256, 0, stream>>>(cls, fc3_w, fc3_b, dw0, dw2p, WF4, out);
}

// Round 14
// 139.154 us; speedup vs baseline: 5.5279x; 1.0133x over previous
//
#include <hip/hip_runtime.h>
#include <hip/hip_bf16.h>
#include <math.h>

#define BATCH 8192
#define IMG 784   // 28*28
#define KP 800    // fc1 K padded to multiple of 32
#define KP2 416   // fc2 K padded (400 -> 416)

typedef short  bf16x8 __attribute__((ext_vector_type(8)));
typedef float  f32x4  __attribute__((ext_vector_type(4)));
typedef float  f32x2  __attribute__((ext_vector_type(2)));

// ---------------------------------------------------------------------------
// K0: precompute (a) per-class conv0 one-hot tables T[10][3][784],
// (b) parity-folded deconv1 weights WF4 + packed w1p/dw2p/dw0p,
// (c) fc1_w -> bf16 [400][800], (d) fc2 weights -> bf16 [48][416].
// ---------------------------------------------------------------------------
__global__ __launch_bounds__(256) void precompute_kernel(
    const float* __restrict__ w0,    // [3,11,3,3]
    const float* __restrict__ w1,    // [1,3,3,3]
    const float* __restrict__ dw0,   // [11,2,3,3]
    const float* __restrict__ dw1,   // [3,11,3,3]
    const float* __restrict__ dw2,   // [1,3,3,3]
    const float* __restrict__ fc1w,  // [400,784]
    const float* __restrict__ w21,   // [20,400]
    const float* __restrict__ w22,   // [20,400]
    float* __restrict__ T,           // [10,3,784]
    float* __restrict__ WF4,         // 576 floats
    float* __restrict__ w1p,         // [9]*4 floats
    float* __restrict__ dw2p,        // [9]*4 floats
    float* __restrict__ dw0p,        // [2*9*3]*4 = 216 floats
    __hip_bfloat16* __restrict__ wbf,  // [400,800]
    __hip_bfloat16* __restrict__ w2bf) // [48,416]
{
    const int blk = blockIdx.x, tid = threadIdx.x;
    if (blk < 10) {
        const int t = blk;
        for (int idx = tid; idx < 3 * 784; idx += 256) {
            int o = idx / 784, pix = idx % 784;
            int r = pix / 28, c = pix % 28;
            float acc = 0.f;
#pragma unroll
            for (int dr = 0; dr < 3; ++dr)
#pragma unroll
                for (int dc = 0; dc < 3; ++dc) {
                    int rr = r + dr - 1, cc = c + dc - 1;
                    if (rr < 0 || rr > 27 || cc < 0 || cc > 27) continue;
                    int s = rr * 28 + cc;
                    int i = ((4 * (t + 1 - s)) % 11 + 11) % 11;
                    acc += w0[(o * 11 + i) * 9 + dr * 3 + dc];
                }
            T[(t * 3 + o) * 784 + pix] = acc;
        }
    } else if (blk == 10) {
        // WF4 flat idx = (((par*3+o)*4+uv)*3+cb)*4+j ; channel = 4*cb+j
        for (int idx = tid; idx < 576; idx += 256) {
            int j = idx & 3;
            int rest = idx >> 2;
            int cb = rest % 3;
            int rest2 = rest / 3;
            int uv = rest2 % 4;
            int rest3 = rest2 / 4;
            int o = rest3 % 3;
            int par = rest3 / 3;
            int ch = cb * 4 + j;
            float acc = 0.f;
            if (ch < 11) {
                int u = uv >> 1, v = uv & 1;
                int pr = par >> 1, pc = par & 1;
                for (int dr = 0; dr < 3; ++dr) {
                    bool rin = (pr == 0) ? (u == 0 ? dr == 0 : dr >= 1)
                                         : (u == 0 ? dr <= 1 : dr == 2);
                    if (!rin) continue;
                    for (int dc = 0; dc < 3; ++dc) {
                        bool cin = (pc == 0) ? (v == 0 ? dc == 0 : dc >= 1)
                                             : (v == 0 ? dc <= 1 : dc == 2);
                        if (cin) acc += dw1[(o * 11 + ch) * 9 + dr * 3 + dc];
                    }
                }
            }
            WF4[idx] = acc;
        }
        // per-tap packed conv1 / deconv2 weights: {w[t], w[9+t], w[18+t], 0}
        if (tid < 9) {
            w1p[tid * 4 + 0] = w1[tid];
            w1p[tid * 4 + 1] = w1[9 + tid];
            w1p[tid * 4 + 2] = w1[18 + tid];
            w1p[tid * 4 + 3] = 0.f;
        } else if (tid < 18) {
            int t = tid - 9;
            dw2p[t * 4 + 0] = dw2[t];
            dw2p[t * 4 + 1] = dw2[9 + t];
            dw2p[t * 4 + 2] = dw2[18 + t];
            dw2p[t * 4 + 3] = 0.f;
        }
        // deconv0 weights channel-minor: dw0p[(i*9+tap)*12 + ch]
        if (tid >= 32 && tid < 248) {
            int idx = tid - 32;            // 0..215
            int j  = idx & 3;
            int cb = (idx >> 2) % 3;
            int t2 = (idx >> 2) / 3;       // i*9 + tap, 0..17
            int i  = t2 / 9, tap = t2 % 9;
            int ch = cb * 4 + j;
            dw0p[t2 * 12 + cb * 4 + j] =
                (ch < 11) ? dw0[(ch * 2 + i) * 9 + tap] : 0.f;
        }
    } else if (blk < 51) {
        // fc1_w fp32 [400,784] -> bf16 [400,800] (cols 784..799 zero)
        const int base = (blk - 11) * 8000;
        for (int i = tid; i < 8000; i += 256) {
            int flat = base + i;
            int n = flat / KP, k = flat % KP;
            float v = (k < 784) ? fc1w[n * 784 + k] : 0.f;
            wbf[flat] = __float2bfloat16(v);
        }
    } else {
        // fc2 weights -> bf16 [48,416]: rows 0-19 w21, 20-39 w22, 40-47 zero
        const int base = (blk - 51) * 2496;
        for (int i = tid; i < 2496; i += 256) {
            int flat = base + i;
            int j = flat / KP2, k = flat % KP2;
            float v = 0.f;
            if (k < 400) {
                if (j < 20)      v = w21[j * 400 + k];
                else if (j < 40) v = w22[(j - 20) * 400 + k];
            }
            w2bf[flat] = __float2bfloat16(v);
        }
    }
}

// ---------------------------------------------------------------------------
// K1: encoder — sparse-x conv0 (wt2[cls][tap] LUT: no per-tap modular math)
// + class table T + conv1 (packed f32). writes h as bf16 [B][800]
// ---------------------------------------------------------------------------
__global__ __launch_bounds__(256, 4) void encoder_kernel(
    const float* __restrict__ x, const int* __restrict__ cls,
    const float* __restrict__ w0,    // [3,11,3,3]
    const float* __restrict__ w1p,   // [9] float4 packed
    const float* __restrict__ T,     // [10,3,784]
    __hip_bfloat16* __restrict__ h_bf)  // [B,800]
{
    __shared__ float  xs[30 * 30];      // scattered x image, zero border
    __shared__ float4 hs0[30 * 30];     // conv0 out (3ch + pad), zero border
    __shared__ float4 wt2[99];          // [cls 0..10][tap 0..8] pre-permuted

    const int b = blockIdx.x, tid = threadIdx.x;
    const int myc = cls[b];

    for (int i = tid; i < 116; i += 256) {
        int r, c;
        if (i < 30)      { r = 0;  c = i; }
        else if (i < 60) { r = 29; c = i - 30; }
        else if (i < 88) { r = 1 + (i - 60); c = 0; }
        else             { r = 1 + (i - 88); c = 29; }
        xs[r * 30 + c] = 0.f;
        hs0[r * 30 + c] = make_float4(0.f, 0.f, 0.f, 0.f);
    }
    // wt2[cls*9+tap] = w0[:, (cls + kk(tap)) % 11, tap]
    for (int i = tid; i < 99; i += 256) {
        int cl = i / 9, tap = i % 9;
        int kk = (9 * (tap / 3) + 7 * (tap % 3)) % 11;
        int ch = cl + kk;
        if (ch >= 11) ch -= 11;
        wt2[i] = make_float4(w0[ch * 9 + tap], w0[(11 + ch) * 9 + tap],
                             w0[(22 + ch) * 9 + tap], 0.f);
    }
    for (int s = tid; s < 784; s += 256) {
        int ch = (7 * s) % 11;
        int p = (ch * 784 + s) / 11;
        xs[(s / 28 + 1) * 30 + s % 28 + 1] = x[(size_t)b * IMG + p];
    }
    if (tid < 16) h_bf[(size_t)b * KP + 784 + tid] = __float2bfloat16(0.f);
    __syncthreads();

    const float* Tc = T + myc * 2352;
    for (int pix = tid; pix < 784; pix += 256) {
        int r = pix / 28, c = pix % 28;
        f32x4 A = {Tc[pix], Tc[784 + pix], Tc[1568 + pix], 0.f};
        int cl = (9 * r + 7 * c + 6) % 11;        // once per pixel
        const f32x4* wrow = (const f32x4*)&wt2[cl * 9];
#pragma unroll
        for (int dr = 0; dr < 3; ++dr)
#pragma unroll
            for (int dc = 0; dc < 3; ++dc) {
                float v = xs[(r + dr) * 30 + c + dc];
                f32x4 vv = {v, v, v, v};
                A = __builtin_elementwise_fma(vv, wrow[dr * 3 + dc], A);
            }
        hs0[(r + 1) * 30 + c + 1] =
            make_float4(fmaxf(A.x, 0.f), fmaxf(A.y, 0.f), fmaxf(A.z, 0.f), 0.f);
    }
    __syncthreads();

    const f32x4* w1v = (const f32x4*)w1p;
    for (int pix = tid; pix < 784; pix += 256) {
        int r = pix / 28, c = pix % 28;
        f32x4 A = {0.f, 0.f, 0.f, 0.f};
#pragma unroll
        for (int dr = 0; dr < 3; ++dr)
#pragma unroll
            for (int dc = 0; dc < 3; ++dc) {
                f32x4 v = *(const f32x4*)&hs0[(r + dr) * 30 + c + dc];
                A = __builtin_elementwise_fma(v, w1v[dr * 3 + dc], A);
            }
        float a = A.x + A.y + A.z;
        h_bf[(size_t)b * KP + pix] = __float2bfloat16(fmaxf(a, 0.f));
    }
}

// ---------------------------------------------------------------------------
// K2: fc1 via bf16 MFMA.  h1b[8192,416] = bf16(relu(h @ w^T + b))
// ---------------------------------------------------------------------------
__global__ __launch_bounds__(256) void fc1_mfma(
    const ushort* __restrict__ h_bf,  // [8192,800] bf16
    const ushort* __restrict__ w_bf,  // [400,800] bf16
    const float* __restrict__ bias,   // [400]
    __hip_bfloat16* __restrict__ h1b) // [8192,416] bf16
{
    __shared__ ushort Bs[80][40];   // B tile [n][k], stride 40 (pad)

    const int tid  = threadIdx.x;
    const int wid  = tid >> 6;
    const int lane = tid & 63;
    const int l15  = lane & 15;
    const int lq   = lane >> 4;       // k-quadrant 0..3
    const int bm   = blockIdx.x * 128;
    const int bn   = blockIdx.y * 80;

    f32x4 acc[2][5] = {};

    const int n0 = tid >> 2;          // 0..63  (staging row)
    const int kq0 = tid & 3;          // staging k-quadrant

    for (int k0 = 0; k0 < KP; k0 += 32) {
        bf16x8 s0 = *(const bf16x8*)&w_bf[(size_t)(bn + n0) * KP + k0 + kq0 * 8];
        bf16x8 s1;
        if (tid < 64)
            s1 = *(const bf16x8*)&w_bf[(size_t)(bn + 64 + n0) * KP + k0 + kq0 * 8];
        bf16x8 a0 = *(const bf16x8*)&h_bf[(size_t)(bm + wid * 32 + l15) * KP + k0 + lq * 8];
        bf16x8 a1 = *(const bf16x8*)&h_bf[(size_t)(bm + wid * 32 + 16 + l15) * KP + k0 + lq * 8];
        __syncthreads();
        *(bf16x8*)&Bs[n0][kq0 * 8] = s0;
        if (tid < 64) *(bf16x8*)&Bs[64 + n0][kq0 * 8] = s1;
        __syncthreads();
#pragma unroll
        for (int nf = 0; nf < 5; ++nf) {
            bf16x8 bfr = *(const bf16x8*)&Bs[nf * 16 + l15][lq * 8];
            acc[0][nf] = __builtin_amdgcn_mfma_f32_16x16x32_bf16(a0, bfr, acc[0][nf], 0, 0, 0);
            acc[1][nf] = __builtin_amdgcn_mfma_f32_16x16x32_bf16(a1, bfr, acc[1][nf], 0, 0, 0);
        }
    }

#pragma unroll
    for (int nf = 0; nf < 5; ++nf) {
        int col = bn + nf * 16 + l15;
        float bv = bias[col];
#pragma unroll
        for (int mr = 0; mr < 2; ++mr)
#pragma unroll
            for (int v = 0; v < 4; ++v) {
                int row = bm + wid * 32 + mr * 16 + lq * 4 + v;
                h1b[(size_t)row * KP2 + col] =
                    __float2bfloat16(fmaxf(acc[mr][nf][v] + bv, 0.f));
            }
    }
    if (blockIdx.y == 4) {
#pragma unroll
        for (int mr = 0; mr < 2; ++mr)
#pragma unroll
            for (int v = 0; v < 4; ++v) {
                int row = bm + wid * 32 + mr * 16 + lq * 4 + v;
                h1b[(size_t)row * KP2 + 400 + l15] = __float2bfloat16(0.f);
            }
    }
}

// ---------------------------------------------------------------------------
// K3: fc21 + fc22 via bf16 MFMA, no LDS.
// ---------------------------------------------------------------------------
__global__ __launch_bounds__(256) void fc2_mfma(
    const ushort* __restrict__ h1b,   // [8192,416] bf16
    const ushort* __restrict__ w2bf,  // [48,416] bf16
    const float* __restrict__ b21, const float* __restrict__ b22,
    float* __restrict__ out)
{
    const int tid  = threadIdx.x;
    const int wid  = tid >> 6;
    const int lane = tid & 63;
    const int l15  = lane & 15;
    const int lq   = lane >> 4;
    const int bm   = blockIdx.x * 128;

    f32x4 acc[2][3] = {};

    for (int k0 = 0; k0 < KP2; k0 += 32) {
        bf16x8 a0 = *(const bf16x8*)&h1b[(size_t)(bm + wid * 32 + l15) * KP2 + k0 + lq * 8];
        bf16x8 a1 = *(const bf16x8*)&h1b[(size_t)(bm + wid * 32 + 16 + l15) * KP2 + k0 + lq * 8];
#pragma unroll
        for (int nf = 0; nf < 3; ++nf) {
            bf16x8 bfr = *(const bf16x8*)&w2bf[(size_t)(nf * 16 + l15) * KP2 + k0 + lq * 8];
            acc[0][nf] = __builtin_amdgcn_mfma_f32_16x16x32_bf16(a0, bfr, acc[0][nf], 0, 0, 0);
            acc[1][nf] = __builtin_amdgcn_mfma_f32_16x16x32_bf16(a1, bfr, acc[1][nf], 0, 0, 0);
        }
    }

    const size_t base = (size_t)BATCH * IMG;
#pragma unroll
    for (int nf = 0; nf < 3; ++nf) {
        int col = nf * 16 + l15;
        if (col < 40) {
            bool is_mu = (col < 20);
            int ccol = is_mu ? col : col - 20;
            float bv = is_mu ? b21[ccol] : b22[ccol];
            size_t obase = is_mu ? base : base + (size_t)BATCH * 20;
#pragma unroll
            for (int mr = 0; mr < 2; ++mr)
#pragma unroll
                for (int v = 0; v < 4; ++v) {
                    int row = bm + wid * 32 + mr * 16 + lq * 4 + v;
                    out[obase + (size_t)row * 20 + ccol] = acc[mr][nf][v] + bv;
                }
        }
    }
}

// ---------------------------------------------------------------------------
// K4: decoder — fc3 + packed deconv0 + wave-parity deconv1 (packed f32x2,
// SGPR weights) + deconv2 + sigmoid.  d0in aliased onto d1s.
// ---------------------------------------------------------------------------
__global__ __launch_bounds__(256, 8) void decoder_kernel(
    const int* __restrict__ cls,
    const float* __restrict__ fc3_w,  // [392,30]
    const float* __restrict__ fc3_b,  // [392]
    const float* __restrict__ dw0p,   // 216 floats (packed deconv0 weights)
    const float* __restrict__ dw2p,   // [9] float4 packed
    const float* __restrict__ WF4g,   // 576 floats
    float* __restrict__ out)
{
    __shared__ float  z[32];
    __shared__ float4 d0sp[3][16 * 16];    // per-cblk planes, ch-minor float4
    __shared__ float4 d1s[30 * 30];        // [30][30]; also hosts d0in early
    float* d0inS = (float*)d1s;

    const int b = blockIdx.x;
    const int tid = threadIdx.x;
    const int myc = cls[b];
    const float* mu = out + (size_t)BATCH * IMG + (size_t)b * 20;

    for (int i = tid; i < 2 * 16 * 17; i += 256) d0inS[i] = 0.f;
    for (int i = tid; i < 60; i += 256) {
        int r, c;
        if (i < 16)      { r = 0;  c = i; }
        else if (i < 32) { r = 15; c = i - 16; }
        else if (i < 46) { r = 1 + (i - 32); c = 0; }
        else             { r = 1 + (i - 46); c = 15; }
        int p = r * 16 + c;
        d0sp[0][p] = d0sp[1][p] = d0sp[2][p] = make_float4(0.f, 0.f, 0.f, 0.f);
    }
    if (tid < 20) z[tid] = mu[tid];
    else if (tid < 30) z[tid] = (tid - 20 == myc) ? 1.f : 0.f;
    __syncthreads();

    // fc3: [30] -> [392] + relu -> d0in [2][16][17] padded
    for (int j = tid; j < 392; j += 256) {
        float acc = fc3_b[j];
        const float2* wrow = (const float2*)&fc3_w[j * 30];
#pragma unroll
        for (int k = 0; k < 15; ++k) {
            float2 wv = wrow[k];
            acc += z[2 * k] * wv.x + z[2 * k + 1] * wv.y;
        }
        int ch = j / 196, rem = j % 196;
        d0inS[ch * 272 + (rem / 14 + 1) * 17 + (rem % 14 + 1)] = fmaxf(acc, 0.f);
    }
    __syncthreads();

    // deconv0: packed f32x4 accumulation; weights wave-uniform -> s_loads
    if (tid < 196) {
        int r = tid / 14, c = tid % 14;
        f32x4 A[3] = {};
        const f32x4* wps = (const f32x4*)dw0p;
#pragma unroll
        for (int i = 0; i < 2; ++i)
#pragma unroll
            for (int dr = 0; dr < 3; ++dr)
#pragma unroll
                for (int dc = 0; dc < 3; ++dc) {
                    float v = d0inS[i * 272 + (r + dr) * 17 + (c + dc)];
                    f32x4 vv = {v, v, v, v};
                    int t = (i * 9 + dr * 3 + dc) * 3;
#pragma unroll
                    for (int cb = 0; cb < 3; ++cb)
                        A[cb] = __builtin_elementwise_fma(vv, wps[t + cb], A[cb]);
                }
        int p = (r + 1) * 16 + (c + 1);
#pragma unroll
        for (int cb = 0; cb < 3; ++cb) {
            f32x4 zero = {0.f, 0.f, 0.f, 0.f};
            f32x4 m = __builtin_elementwise_max(A[cb], zero);
            d0sp[cb][p] = *(float4*)&m;
        }
    }
    __syncthreads();   // d0in reads done -> d1s region free for reuse

    // d1s border zeroing, same phase as deconv1 (disjoint addresses)
    for (int i = tid; i < 116; i += 256) {
        int r, c;
        if (i < 30)      { r = 0;  c = i; }
        else if (i < 60) { r = 29; c = i - 30; }
        else if (i < 88) { r = 1 + (i - 60); c = 0; }
        else             { r = 1 + (i - 88); c = 29; }
        d1s[r * 30 + c] = make_float4(0.f, 0.f, 0.f, 0.f);
    }

    // deconv1: wave w owns parity w. Vertical q-pair per thread; f32x2
    // packed accumulators; weights via wave-uniform global -> SGPRs.
    {
        const int wid  = tid >> 6;          // parity, wave-uniform
        const int lane = tid & 63;
        const int pr = wid >> 1, pc = wid & 1;
        const f32x4* wgs = (const f32x4*)(WF4g +
            __builtin_amdgcn_readfirstlane(wid) * 144);
#pragma unroll 1
        for (int pp = 0; pp < 2; ++pp) {
            int pi = pp * 64 + lane;
            if (pi < 98) {
                int qpr = pi / 14, qc = pi - qpr * 14;
                int qr0 = qpr * 2;
                int base = (qr0 + pr) * 16 + qc + pc;
                f32x2 A0[3] = {{0.f, 0.f}, {0.f, 0.f}, {0.f, 0.f}};
                f32x2 A1[3] = {{0.f, 0.f}, {0.f, 0.f}, {0.f, 0.f}};
#pragma unroll
                for (int cb = 0; cb < 3; ++cb) {
                    f32x4 v0 = *(const f32x4*)&d0sp[cb][base];
                    f32x4 v1 = *(const f32x4*)&d0sp[cb][base + 1];
                    f32x4 v2 = *(const f32x4*)&d0sp[cb][base + 16];
                    f32x4 v3 = *(const f32x4*)&d0sp[cb][base + 17];
                    f32x4 v4 = *(const f32x4*)&d0sp[cb][base + 32];
                    f32x4 v5 = *(const f32x4*)&d0sp[cb][base + 33];
#pragma unroll
                    for (int o = 0; o < 3; ++o) {
                        f32x4 w00 = wgs[(o * 4 + 0) * 3 + cb];
                        f32x4 w01 = wgs[(o * 4 + 1) * 3 + cb];
                        f32x4 w10 = wgs[(o * 4 + 2) * 3 + cb];
                        f32x4 w11 = wgs[(o * 4 + 3) * 3 + cb];
                        A0[o] = __builtin_elementwise_fma(v0.lo, w00.lo, A0[o]);
                        A0[o] = __builtin_elementwise_fma(v0.hi, w00.hi, A0[o]);
                        A0[o] = __builtin_elementwise_fma(v1.lo, w01.lo, A0[o]);
                        A0[o] = __builtin_elementwise_fma(v1.hi, w01.hi, A0[o]);
                        A0[o] = __builtin_elementwise_fma(v2.lo, w10.lo, A0[o]);
                        A0[o] = __builtin_elementwise_fma(v2.hi, w10.hi, A0[o]);
                        A0[o] = __builtin_elementwise_fma(v3.lo, w11.lo, A0[o]);
                        A0[o] = __builtin_elementwise_fma(v3.hi, w11.hi, A0[o]);
                        A1[o] = __builtin_elementwise_fma(v2.lo, w00.lo, A1[o]);
                        A1[o] = __builtin_elementwise_fma(v2.hi, w00.hi, A1[o]);
                        A1[o] = __builtin_elementwise_fma(v3.lo, w01.lo, A1[o]);
                        A1[o] = __builtin_elementwise_fma(v3.hi, w01.hi, A1[o]);
                        A1[o] = __builtin_elementwise_fma(v4.lo, w10.lo, A1[o]);
                        A1[o] = __builtin_elementwise_fma(v4.hi, w10.hi, A1[o]);
                        A1[o] = __builtin_elementwise_fma(v5.lo, w11.lo, A1[o]);
                        A1[o] = __builtin_elementwise_fma(v5.hi, w11.hi, A1[o]);
                    }
                }
                int r0 = 2 * qr0 + pr, c = 2 * qc + pc;
                d1s[(r0 + 1) * 30 + c + 1] =
                    make_float4(fmaxf(A0[0].x + A0[0].y, 0.f),
                                fmaxf(A0[1].x + A0[1].y, 0.f),
                                fmaxf(A0[2].x + A0[2].y, 0.f), 0.f);
                d1s[(r0 + 3) * 30 + c + 1] =
                    make_float4(fmaxf(A1[0].x + A1[0].y, 0.f),
                                fmaxf(A1[1].x + A1[1].y, 0.f),
                                fmaxf(A1[2].x + A1[2].y, 0.f), 0.f);
            }
        }
    }
    __syncthreads();

    // deconv2 (3->1, packed per-tap weights) + sigmoid
    const f32x4* dw2v = (const f32x4*)dw2p;
    for (int pix = tid; pix < 784; pix += 256) {
        int r = pix / 28, c = pix % 28;
        f32x4 A = {0.f, 0.f, 0.f, 0.f};
#pragma unroll
        for (int dr = 0; dr < 3; ++dr)
#pragma unroll
            for (int dc = 0; dc < 3; ++dc) {
                f32x4 v = *(const f32x4*)&d1s[(r + dr) * 30 + c + dc];
                A = __builtin_elementwise_fma(v, dw2v[dr * 3 + dc], A);
            }
        float a = A.x + A.y + A.z;
        out[(size_t)b * IMG + pix] = 1.f / (1.f + expf(-a));
    }
}

// ---------------------------------------------------------------------------
extern "C" void kernel_launch(void* const* d_in, const int* in_sizes, int n_in,
                              void* d_out, int out_size, void* d_ws, size_t ws_size,
                              hipStream_t stream) {
    const float* x     = (const float*)d_in[0];
    const int*   cls   = (const int*)d_in[1];
    const float* w0    = (const float*)d_in[2];
    const float* w1    = (const float*)d_in[3];
    const float* fc1_w = (const float*)d_in[4];
    const float* fc1_b = (const float*)d_in[5];
    const float* w21   = (const float*)d_in[6];
    const float* b21   = (const float*)d_in[7];
    const float* w22   = (const float*)d_in[8];
    const float* b22   = (const float*)d_in[9];
    const float* fc3_w = (const float*)d_in[10];
    const float* fc3_b = (const float*)d_in[11];
    const float* dw0   = (const float*)d_in[12];
    const float* dw1   = (const float*)d_in[13];
    const float* dw2   = (const float*)d_in[14];

    float* out = (float*)d_out;
    char*  ws  = (char*)d_ws;
    __hip_bfloat16* h_bf = (__hip_bfloat16*)ws;                       // 8192*800 bf16
    __hip_bfloat16* h1b  = (__hip_bfloat16*)(ws + (size_t)BATCH * KP * 2);  // 8192*416 bf16
    float* T    = (float*)(ws + (size_t)BATCH * KP * 2 + (size_t)BATCH * KP2 * 2);
    float* WF4  = T + 10 * 3 * 784;
    __hip_bfloat16* w_bf  = (__hip_bfloat16*)(WF4 + 576);             // 400*800
    __hip_bfloat16* w2bf  = w_bf + 400 * KP;                          // 48*416
    float* w1p  = (float*)(w2bf + 48 * KP2);                          // 36 floats
    float* dw2p = w1p + 36;                                           // 36 floats
    float* dw0p = dw2p + 36;                                          // 216 floats

    precompute_kernel<<<59, 256, 0, stream>>>(w0, w1, dw0, dw1, dw2, fc1_w,
                                              w21, w22, T, WF4, w1p, dw2p,
                                              dw0p, w_bf, w2bf);
    encoder_kernel<<<BATCH, 256, 0, stream>>>(x, cls, w0, w1p, T, h_bf);
    fc1_mfma<<<dim3(64, 5), 256, 0, stream>>>((const ushort*)h_bf,
                                              (const ushort*)w_bf, fc1_b, h1b);
    fc2_mfma<<<64, 256, 0, stream>>>((const ushort*)h1b, (const ushort*)w2bf,
                                     b21, b22, out);
    decoder_kernel<<<BATCH, 256, 0, stream>>>(cls, fc3_w, fc3_b, dw0p, dw2p,
                                              WF4, out);
}

// Round 15
// 133.908 us; speedup vs baseline: 5.7444x; 1.0392x over previous
//
#include <hip/hip_runtime.h>
#include <hip/hip_bf16.h>
#include <math.h>

#define BATCH 8192
#define IMG 784   // 28*28
#define KP 800    // fc1 K padded to multiple of 32
#define KP2 416   // fc2 K padded (400 -> 416)

typedef short  bf16x8 __attribute__((ext_vector_type(8)));
typedef float  f32x4  __attribute__((ext_vector_type(4)));
typedef float  f32x2  __attribute__((ext_vector_type(2)));

// ---------------------------------------------------------------------------
// K0: precompute (a) per-class conv0 one-hot tables T[10][3][784],
// (b) parity-folded deconv1 weights WF4 + packed w1p/dw2p/dw0p,
// (c) fc1_w -> bf16 [400][800], (d) fc2 weights -> bf16 [48][416].
// ---------------------------------------------------------------------------
__global__ __launch_bounds__(256) void precompute_kernel(
    const float* __restrict__ w0,    // [3,11,3,3]
    const float* __restrict__ w1,    // [1,3,3,3]
    const float* __restrict__ dw0,   // [11,2,3,3]
    const float* __restrict__ dw1,   // [3,11,3,3]
    const float* __restrict__ dw2,   // [1,3,3,3]
    const float* __restrict__ fc1w,  // [400,784]
    const float* __restrict__ w21,   // [20,400]
    const float* __restrict__ w22,   // [20,400]
    float* __restrict__ T,           // [10,3,784]
    float* __restrict__ WF4,         // 576 floats
    float* __restrict__ w1p,         // [9]*4 floats
    float* __restrict__ dw2p,        // [9]*4 floats
    float* __restrict__ dw0p,        // [2*9*3]*4 = 216 floats
    __hip_bfloat16* __restrict__ wbf,  // [400,800]
    __hip_bfloat16* __restrict__ w2bf) // [48,416]
{
    const int blk = blockIdx.x, tid = threadIdx.x;
    if (blk < 10) {
        const int t = blk;
        for (int idx = tid; idx < 3 * 784; idx += 256) {
            int o = idx / 784, pix = idx % 784;
            int r = pix / 28, c = pix % 28;
            float acc = 0.f;
#pragma unroll
            for (int dr = 0; dr < 3; ++dr)
#pragma unroll
                for (int dc = 0; dc < 3; ++dc) {
                    int rr = r + dr - 1, cc = c + dc - 1;
                    if (rr < 0 || rr > 27 || cc < 0 || cc > 27) continue;
                    int s = rr * 28 + cc;
                    int i = ((4 * (t + 1 - s)) % 11 + 11) % 11;
                    acc += w0[(o * 11 + i) * 9 + dr * 3 + dc];
                }
            T[(t * 3 + o) * 784 + pix] = acc;
        }
    } else if (blk == 10) {
        // WF4 flat idx = (((par*3+o)*4+uv)*3+cb)*4+j ; channel = 4*cb+j
        for (int idx = tid; idx < 576; idx += 256) {
            int j = idx & 3;
            int rest = idx >> 2;
            int cb = rest % 3;
            int rest2 = rest / 3;
            int uv = rest2 % 4;
            int rest3 = rest2 / 4;
            int o = rest3 % 3;
            int par = rest3 / 3;
            int ch = cb * 4 + j;
            float acc = 0.f;
            if (ch < 11) {
                int u = uv >> 1, v = uv & 1;
                int pr = par >> 1, pc = par & 1;
                for (int dr = 0; dr < 3; ++dr) {
                    bool rin = (pr == 0) ? (u == 0 ? dr == 0 : dr >= 1)
                                         : (u == 0 ? dr <= 1 : dr == 2);
                    if (!rin) continue;
                    for (int dc = 0; dc < 3; ++dc) {
                        bool cin = (pc == 0) ? (v == 0 ? dc == 0 : dc >= 1)
                                             : (v == 0 ? dc <= 1 : dc == 2);
                        if (cin) acc += dw1[(o * 11 + ch) * 9 + dr * 3 + dc];
                    }
                }
            }
            WF4[idx] = acc;
        }
        // per-tap packed conv1 / deconv2 weights: {w[t], w[9+t], w[18+t], 0}
        if (tid < 9) {
            w1p[tid * 4 + 0] = w1[tid];
            w1p[tid * 4 + 1] = w1[9 + tid];
            w1p[tid * 4 + 2] = w1[18 + tid];
            w1p[tid * 4 + 3] = 0.f;
        } else if (tid < 18) {
            int t = tid - 9;
            dw2p[t * 4 + 0] = dw2[t];
            dw2p[t * 4 + 1] = dw2[9 + t];
            dw2p[t * 4 + 2] = dw2[18 + t];
            dw2p[t * 4 + 3] = 0.f;
        }
        // deconv0 weights channel-minor: dw0p[(i*9+tap)*12 + ch]
        if (tid >= 32 && tid < 248) {
            int idx = tid - 32;            // 0..215
            int j  = idx & 3;
            int cb = (idx >> 2) % 3;
            int t2 = (idx >> 2) / 3;       // i*9 + tap, 0..17
            int i  = t2 / 9, tap = t2 % 9;
            int ch = cb * 4 + j;
            dw0p[t2 * 12 + cb * 4 + j] =
                (ch < 11) ? dw0[(ch * 2 + i) * 9 + tap] : 0.f;
        }
    } else if (blk < 51) {
        // fc1_w fp32 [400,784] -> bf16 [400,800] (cols 784..799 zero)
        const int base = (blk - 11) * 8000;
        for (int i = tid; i < 8000; i += 256) {
            int flat = base + i;
            int n = flat / KP, k = flat % KP;
            float v = (k < 784) ? fc1w[n * 784 + k] : 0.f;
            wbf[flat] = __float2bfloat16(v);
        }
    } else {
        // fc2 weights -> bf16 [48,416]: rows 0-19 w21, 20-39 w22, 40-47 zero
        const int base = (blk - 51) * 2496;
        for (int i = tid; i < 2496; i += 256) {
            int flat = base + i;
            int j = flat / KP2, k = flat % KP2;
            float v = 0.f;
            if (k < 400) {
                if (j < 20)      v = w21[j * 400 + k];
                else if (j < 40) v = w22[(j - 20) * 400 + k];
            }
            w2bf[flat] = __float2bfloat16(v);
        }
    }
}

// ---------------------------------------------------------------------------
// K1: encoder — sparse-x conv0 + conv1, both with VERTICAL 2-PIXEL PAIRING
// (shared 4x3 window: 12 reads / 2 pixels; 2 loop iterations not 4).
// writes h as bf16 [B][800]
// ---------------------------------------------------------------------------
__global__ __launch_bounds__(256, 4) void encoder_kernel(
    const float* __restrict__ x, const int* __restrict__ cls,
    const float* __restrict__ w0,    // [3,11,3,3]
    const float* __restrict__ w1p,   // [9] float4 packed
    const float* __restrict__ T,     // [10,3,784]
    __hip_bfloat16* __restrict__ h_bf)  // [B,800]
{
    __shared__ float  xs[30 * 30];      // scattered x image, zero border
    __shared__ float4 hs0[30 * 30];     // conv0 out (3ch + pad), zero border
    __shared__ float4 wt2[99];          // [cls 0..10][tap 0..8] pre-permuted

    const int b = blockIdx.x, tid = threadIdx.x;
    const int myc = cls[b];

    for (int i = tid; i < 116; i += 256) {
        int r, c;
        if (i < 30)      { r = 0;  c = i; }
        else if (i < 60) { r = 29; c = i - 30; }
        else if (i < 88) { r = 1 + (i - 60); c = 0; }
        else             { r = 1 + (i - 88); c = 29; }
        xs[r * 30 + c] = 0.f;
        hs0[r * 30 + c] = make_float4(0.f, 0.f, 0.f, 0.f);
    }
    // wt2[cls*9+tap] = w0[:, (cls + kk(tap)) % 11, tap]
    for (int i = tid; i < 99; i += 256) {
        int cl = i / 9, tap = i % 9;
        int kk = (9 * (tap / 3) + 7 * (tap % 3)) % 11;
        int ch = cl + kk;
        if (ch >= 11) ch -= 11;
        wt2[i] = make_float4(w0[ch * 9 + tap], w0[(11 + ch) * 9 + tap],
                             w0[(22 + ch) * 9 + tap], 0.f);
    }
    for (int s = tid; s < 784; s += 256) {
        int ch = (7 * s) % 11;
        int p = (ch * 784 + s) / 11;
        xs[(s / 28 + 1) * 30 + s % 28 + 1] = x[(size_t)b * IMG + p];
    }
    if (tid < 16) h_bf[(size_t)b * KP + 784 + tid] = __float2bfloat16(0.f);
    __syncthreads();

    const float* Tc = T + myc * 2352;
    // conv0: vertical pairs (r0, c), (r0+1, c); r0 even
    for (int pi = tid; pi < 392; pi += 256) {
        int rp = pi / 28, c = pi % 28;
        int r0 = rp * 2;
        float w[4][3];
#pragma unroll
        for (int i = 0; i < 4; ++i)
#pragma unroll
            for (int j = 0; j < 3; ++j)
                w[i][j] = xs[(r0 + i) * 30 + c + j];
        int pixA = r0 * 28 + c;
        f32x4 A = {Tc[pixA], Tc[784 + pixA], Tc[1568 + pixA], 0.f};
        f32x4 Bq = {Tc[pixA + 28], Tc[812 + pixA], Tc[1596 + pixA], 0.f};
        int clA = (9 * r0 + 7 * c + 6) % 11;
        int clB = clA + 9; if (clB >= 11) clB -= 11;
        const f32x4* wrA = (const f32x4*)&wt2[clA * 9];
        const f32x4* wrB = (const f32x4*)&wt2[clB * 9];
#pragma unroll
        for (int dr = 0; dr < 3; ++dr)
#pragma unroll
            for (int dc = 0; dc < 3; ++dc) {
                int tap = dr * 3 + dc;
                float va = w[dr][dc], vb = w[dr + 1][dc];
                f32x4 vva = {va, va, va, va};
                f32x4 vvb = {vb, vb, vb, vb};
                A  = __builtin_elementwise_fma(vva, wrA[tap], A);
                Bq = __builtin_elementwise_fma(vvb, wrB[tap], Bq);
            }
        hs0[(r0 + 1) * 30 + c + 1] =
            make_float4(fmaxf(A.x, 0.f), fmaxf(A.y, 0.f), fmaxf(A.z, 0.f), 0.f);
        hs0[(r0 + 2) * 30 + c + 1] =
            make_float4(fmaxf(Bq.x, 0.f), fmaxf(Bq.y, 0.f), fmaxf(Bq.z, 0.f), 0.f);
    }
    __syncthreads();

    // conv1: vertical pairs, pixel-independent packed weights
    const f32x4* w1v = (const f32x4*)w1p;
    for (int pi = tid; pi < 392; pi += 256) {
        int rp = pi / 28, c = pi % 28;
        int r0 = rp * 2;
        f32x4 A = {0.f, 0.f, 0.f, 0.f};
        f32x4 Bq = {0.f, 0.f, 0.f, 0.f};
#pragma unroll
        for (int dr = 0; dr < 4; ++dr)
#pragma unroll
            for (int dc = 0; dc < 3; ++dc) {
                f32x4 v = *(const f32x4*)&hs0[(r0 + dr) * 30 + c + dc];
                if (dr < 3)
                    A = __builtin_elementwise_fma(v, w1v[dr * 3 + dc], A);
                if (dr > 0)
                    Bq = __builtin_elementwise_fma(v, w1v[(dr - 1) * 3 + dc], Bq);
            }
        float a = A.x + A.y + A.z;
        float bv = Bq.x + Bq.y + Bq.z;
        h_bf[(size_t)b * KP + r0 * 28 + c] = __float2bfloat16(fmaxf(a, 0.f));
        h_bf[(size_t)b * KP + (r0 + 1) * 28 + c] = __float2bfloat16(fmaxf(bv, 0.f));
    }
}

// ---------------------------------------------------------------------------
// K2: fc1 via bf16 MFMA.  h1b[8192,416] = bf16(relu(h @ w^T + b))
// ---------------------------------------------------------------------------
__global__ __launch_bounds__(256) void fc1_mfma(
    const ushort* __restrict__ h_bf,  // [8192,800] bf16
    const ushort* __restrict__ w_bf,  // [400,800] bf16
    const float* __restrict__ bias,   // [400]
    __hip_bfloat16* __restrict__ h1b) // [8192,416] bf16
{
    __shared__ ushort Bs[80][40];   // B tile [n][k], stride 40 (pad)

    const int tid  = threadIdx.x;
    const int wid  = tid >> 6;
    const int lane = tid & 63;
    const int l15  = lane & 15;
    const int lq   = lane >> 4;       // k-quadrant 0..3
    const int bm   = blockIdx.x * 128;
    const int bn   = blockIdx.y * 80;

    f32x4 acc[2][5] = {};

    const int n0 = tid >> 2;          // 0..63  (staging row)
    const int kq0 = tid & 3;          // staging k-quadrant

    for (int k0 = 0; k0 < KP; k0 += 32) {
        bf16x8 s0 = *(const bf16x8*)&w_bf[(size_t)(bn + n0) * KP + k0 + kq0 * 8];
        bf16x8 s1;
        if (tid < 64)
            s1 = *(const bf16x8*)&w_bf[(size_t)(bn + 64 + n0) * KP + k0 + kq0 * 8];
        bf16x8 a0 = *(const bf16x8*)&h_bf[(size_t)(bm + wid * 32 + l15) * KP + k0 + lq * 8];
        bf16x8 a1 = *(const bf16x8*)&h_bf[(size_t)(bm + wid * 32 + 16 + l15) * KP + k0 + lq * 8];
        __syncthreads();
        *(bf16x8*)&Bs[n0][kq0 * 8] = s0;
        if (tid < 64) *(bf16x8*)&Bs[64 + n0][kq0 * 8] = s1;
        __syncthreads();
#pragma unroll
        for (int nf = 0; nf < 5; ++nf) {
            bf16x8 bfr = *(const bf16x8*)&Bs[nf * 16 + l15][lq * 8];
            acc[0][nf] = __builtin_amdgcn_mfma_f32_16x16x32_bf16(a0, bfr, acc[0][nf], 0, 0, 0);
            acc[1][nf] = __builtin_amdgcn_mfma_f32_16x16x32_bf16(a1, bfr, acc[1][nf], 0, 0, 0);
        }
    }

#pragma unroll
    for (int nf = 0; nf < 5; ++nf) {
        int col = bn + nf * 16 + l15;
        float bv = bias[col];
#pragma unroll
        for (int mr = 0; mr < 2; ++mr)
#pragma unroll
            for (int v = 0; v < 4; ++v) {
                int row = bm + wid * 32 + mr * 16 + lq * 4 + v;
                h1b[(size_t)row * KP2 + col] =
                    __float2bfloat16(fmaxf(acc[mr][nf][v] + bv, 0.f));
            }
    }
    if (blockIdx.y == 4) {
#pragma unroll
        for (int mr = 0; mr < 2; ++mr)
#pragma unroll
            for (int v = 0; v < 4; ++v) {
                int row = bm + wid * 32 + mr * 16 + lq * 4 + v;
                h1b[(size_t)row * KP2 + 400 + l15] = __float2bfloat16(0.f);
            }
    }
}

// ---------------------------------------------------------------------------
// K3: fc21 + fc22 via bf16 MFMA, no LDS.
// ---------------------------------------------------------------------------
__global__ __launch_bounds__(256) void fc2_mfma(
    const ushort* __restrict__ h1b,   // [8192,416] bf16
    const ushort* __restrict__ w2bf,  // [48,416] bf16
    const float* __restrict__ b21, const float* __restrict__ b22,
    float* __restrict__ out)
{
    const int tid  = threadIdx.x;
    const int wid  = tid >> 6;
    const int lane = tid & 63;
    const int l15  = lane & 15;
    const int lq   = lane >> 4;
    const int bm   = blockIdx.x * 128;

    f32x4 acc[2][3] = {};

    for (int k0 = 0; k0 < KP2; k0 += 32) {
        bf16x8 a0 = *(const bf16x8*)&h1b[(size_t)(bm + wid * 32 + l15) * KP2 + k0 + lq * 8];
        bf16x8 a1 = *(const bf16x8*)&h1b[(size_t)(bm + wid * 32 + 16 + l15) * KP2 + k0 + lq * 8];
#pragma unroll
        for (int nf = 0; nf < 3; ++nf) {
            bf16x8 bfr = *(const bf16x8*)&w2bf[(size_t)(nf * 16 + l15) * KP2 + k0 + lq * 8];
            acc[0][nf] = __builtin_amdgcn_mfma_f32_16x16x32_bf16(a0, bfr, acc[0][nf], 0, 0, 0);
            acc[1][nf] = __builtin_amdgcn_mfma_f32_16x16x32_bf16(a1, bfr, acc[1][nf], 0, 0, 0);
        }
    }

    const size_t base = (size_t)BATCH * IMG;
#pragma unroll
    for (int nf = 0; nf < 3; ++nf) {
        int col = nf * 16 + l15;
        if (col < 40) {
            bool is_mu = (col < 20);
            int ccol = is_mu ? col : col - 20;
            float bv = is_mu ? b21[ccol] : b22[ccol];
            size_t obase = is_mu ? base : base + (size_t)BATCH * 20;
#pragma unroll
            for (int mr = 0; mr < 2; ++mr)
#pragma unroll
                for (int v = 0; v < 4; ++v) {
                    int row = bm + wid * 32 + mr * 16 + lq * 4 + v;
                    out[obase + (size_t)row * 20 + ccol] = acc[mr][nf][v] + bv;
                }
        }
    }
}

// ---------------------------------------------------------------------------
// K4: decoder — fc3 + packed deconv0 + wave-parity deconv1 (TWISTED d0sp
// layout: slot(r,c) = r*16 + ((c+r)&15) kills the 5-way bank conflict) +
// deconv2 (+__expf sigmoid).  d0in aliased onto d1s.
// ---------------------------------------------------------------------------
__global__ __launch_bounds__(256, 8) void decoder_kernel(
    const int* __restrict__ cls,
    const float* __restrict__ fc3_w,  // [392,30]
    const float* __restrict__ fc3_b,  // [392]
    const float* __restrict__ dw0p,   // 216 floats (packed deconv0 weights)
    const float* __restrict__ dw2p,   // [9] float4 packed
    const float* __restrict__ WF4g,   // 576 floats
    float* __restrict__ out)
{
    __shared__ float  z[32];
    __shared__ float4 d0sp[3][16 * 16];    // per-cblk planes, TWISTED layout
    __shared__ float4 d1s[30 * 30];        // [30][30]; also hosts d0in early
    float* d0inS = (float*)d1s;

#define SLOT(R, C) ((R) * 16 + (((C) + (R)) & 15))

    const int b = blockIdx.x;
    const int tid = threadIdx.x;
    const int myc = cls[b];
    const float* mu = out + (size_t)BATCH * IMG + (size_t)b * 20;

    for (int i = tid; i < 2 * 16 * 17; i += 256) d0inS[i] = 0.f;
    for (int i = tid; i < 60; i += 256) {
        int r, c;
        if (i < 16)      { r = 0;  c = i; }
        else if (i < 32) { r = 15; c = i - 16; }
        else if (i < 46) { r = 1 + (i - 32); c = 0; }
        else             { r = 1 + (i - 46); c = 15; }
        int p = SLOT(r, c);
        d0sp[0][p] = d0sp[1][p] = d0sp[2][p] = make_float4(0.f, 0.f, 0.f, 0.f);
    }
    if (tid < 20) z[tid] = mu[tid];
    else if (tid < 30) z[tid] = (tid - 20 == myc) ? 1.f : 0.f;
    __syncthreads();

    // fc3: [30] -> [392] + relu -> d0in [2][16][17] padded
    for (int j = tid; j < 392; j += 256) {
        float acc = fc3_b[j];
        const float2* wrow = (const float2*)&fc3_w[j * 30];
#pragma unroll
        for (int k = 0; k < 15; ++k) {
            float2 wv = wrow[k];
            acc += z[2 * k] * wv.x + z[2 * k + 1] * wv.y;
        }
        int ch = j / 196, rem = j % 196;
        d0inS[ch * 272 + (rem / 14 + 1) * 17 + (rem % 14 + 1)] = fmaxf(acc, 0.f);
    }
    __syncthreads();

    // deconv0: packed f32x4 accumulation; weights wave-uniform -> s_loads
    if (tid < 196) {
        int r = tid / 14, c = tid % 14;
        f32x4 A[3] = {};
        const f32x4* wps = (const f32x4*)dw0p;
#pragma unroll
        for (int i = 0; i < 2; ++i)
#pragma unroll
            for (int dr = 0; dr < 3; ++dr)
#pragma unroll
                for (int dc = 0; dc < 3; ++dc) {
                    float v = d0inS[i * 272 + (r + dr) * 17 + (c + dc)];
                    f32x4 vv = {v, v, v, v};
                    int t = (i * 9 + dr * 3 + dc) * 3;
#pragma unroll
                    for (int cb = 0; cb < 3; ++cb)
                        A[cb] = __builtin_elementwise_fma(vv, wps[t + cb], A[cb]);
                }
        int p = SLOT(r + 1, c + 1);
#pragma unroll
        for (int cb = 0; cb < 3; ++cb) {
            f32x4 zero = {0.f, 0.f, 0.f, 0.f};
            f32x4 m = __builtin_elementwise_max(A[cb], zero);
            d0sp[cb][p] = *(float4*)&m;
        }
    }
    __syncthreads();   // d0in reads done -> d1s region free for reuse

    // d1s border zeroing, same phase as deconv1 (disjoint addresses)
    for (int i = tid; i < 116; i += 256) {
        int r, c;
        if (i < 30)      { r = 0;  c = i; }
        else if (i < 60) { r = 29; c = i - 30; }
        else if (i < 88) { r = 1 + (i - 60); c = 0; }
        else             { r = 1 + (i - 88); c = 29; }
        d1s[r * 30 + c] = make_float4(0.f, 0.f, 0.f, 0.f);
    }

    // deconv1: wave w owns parity w. Vertical q-pair per thread; f32x2
    // packed accumulators; weights via wave-uniform global -> SGPRs.
    {
        const int wid  = tid >> 6;          // parity, wave-uniform
        const int lane = tid & 63;
        const int pr = wid >> 1, pc = wid & 1;
        const f32x4* wgs = (const f32x4*)(WF4g +
            __builtin_amdgcn_readfirstlane(wid) * 144);
#pragma unroll 1
        for (int pp = 0; pp < 2; ++pp) {
            int pi = pp * 64 + lane;
            if (pi < 98) {
                int qpr = pi / 14, qc = pi - qpr * 14;
                int qr0 = qpr * 2;
                int R0 = qr0 + pr, C0 = qc + pc;
                int t0 = C0 + R0;
                int rb = R0 * 16;
                int s00 = rb + (t0 & 15);
                int s01 = rb + ((t0 + 1) & 15);
                int s10 = rb + 16 + ((t0 + 1) & 15);
                int s11 = rb + 16 + ((t0 + 2) & 15);
                int s20 = rb + 32 + ((t0 + 2) & 15);
                int s21 = rb + 32 + ((t0 + 3) & 15);
                f32x2 A0[3] = {{0.f, 0.f}, {0.f, 0.f}, {0.f, 0.f}};
                f32x2 A1[3] = {{0.f, 0.f}, {0.f, 0.f}, {0.f, 0.f}};
#pragma unroll
                for (int cb = 0; cb < 3; ++cb) {
                    f32x4 v0 = *(const f32x4*)&d0sp[cb][s00];
                    f32x4 v1 = *(const f32x4*)&d0sp[cb][s01];
                    f32x4 v2 = *(const f32x4*)&d0sp[cb][s10];
                    f32x4 v3 = *(const f32x4*)&d0sp[cb][s11];
                    f32x4 v4 = *(const f32x4*)&d0sp[cb][s20];
                    f32x4 v5 = *(const f32x4*)&d0sp[cb][s21];
#pragma unroll
                    for (int o = 0; o < 3; ++o) {
                        f32x4 w00 = wgs[(o * 4 + 0) * 3 + cb];
                        f32x4 w01 = wgs[(o * 4 + 1) * 3 + cb];
                        f32x4 w10 = wgs[(o * 4 + 2) * 3 + cb];
                        f32x4 w11 = wgs[(o * 4 + 3) * 3 + cb];
                        A0[o] = __builtin_elementwise_fma(v0.lo, w00.lo, A0[o]);
                        A0[o] = __builtin_elementwise_fma(v0.hi, w00.hi, A0[o]);
                        A0[o] = __builtin_elementwise_fma(v1.lo, w01.lo, A0[o]);
                        A0[o] = __builtin_elementwise_fma(v1.hi, w01.hi, A0[o]);
                        A0[o] = __builtin_elementwise_fma(v2.lo, w10.lo, A0[o]);
                        A0[o] = __builtin_elementwise_fma(v2.hi, w10.hi, A0[o]);
                        A0[o] = __builtin_elementwise_fma(v3.lo, w11.lo, A0[o]);
                        A0[o] = __builtin_elementwise_fma(v3.hi, w11.hi, A0[o]);
                        A1[o] = __builtin_elementwise_fma(v2.lo, w00.lo, A1[o]);
                        A1[o] = __builtin_elementwise_fma(v2.hi, w00.hi, A1[o]);
                        A1[o] = __builtin_elementwise_fma(v3.lo, w01.lo, A1[o]);
                        A1[o] = __builtin_elementwise_fma(v3.hi, w01.hi, A1[o]);
                        A1[o] = __builtin_elementwise_fma(v4.lo, w10.lo, A1[o]);
                        A1[o] = __builtin_elementwise_fma(v4.hi, w10.hi, A1[o]);
                        A1[o] = __builtin_elementwise_fma(v5.lo, w11.lo, A1[o]);
                        A1[o] = __builtin_elementwise_fma(v5.hi, w11.hi, A1[o]);
                    }
                }
                int r0 = 2 * qr0 + pr, c = 2 * qc + pc;
                d1s[(r0 + 1) * 30 + c + 1] =
                    make_float4(fmaxf(A0[0].x + A0[0].y, 0.f),
                                fmaxf(A0[1].x + A0[1].y, 0.f),
                                fmaxf(A0[2].x + A0[2].y, 0.f), 0.f);
                d1s[(r0 + 3) * 30 + c + 1] =
                    make_float4(fmaxf(A1[0].x + A1[0].y, 0.f),
                                fmaxf(A1[1].x + A1[1].y, 0.f),
                                fmaxf(A1[2].x + A1[2].y, 0.f), 0.f);
            }
        }
    }
    __syncthreads();

    // deconv2 (3->1, packed per-tap weights) + fast sigmoid
    const f32x4* dw2v = (const f32x4*)dw2p;
    for (int pix = tid; pix < 784; pix += 256) {
        int r = pix / 28, c = pix % 28;
        f32x4 A = {0.f, 0.f, 0.f, 0.f};
#pragma unroll
        for (int dr = 0; dr < 3; ++dr)
#pragma unroll
            for (int dc = 0; dc < 3; ++dc) {
                f32x4 v = *(const f32x4*)&d1s[(r + dr) * 30 + c + dc];
                A = __builtin_elementwise_fma(v, dw2v[dr * 3 + dc], A);
            }
        float a = A.x + A.y + A.z;
        out[(size_t)b * IMG + pix] = 1.f / (1.f + __expf(-a));
    }
#undef SLOT
}

// ---------------------------------------------------------------------------
extern "C" void kernel_launch(void* const* d_in, const int* in_sizes, int n_in,
                              void* d_out, int out_size, void* d_ws, size_t ws_size,
                              hipStream_t stream) {
    const float* x     = (const float*)d_in[0];
    const int*   cls   = (const int*)d_in[1];
    const float* w0    = (const float*)d_in[2];
    const float* w1    = (const float*)d_in[3];
    const float* fc1_w = (const float*)d_in[4];
    const float* fc1_b = (const float*)d_in[5];
    const float* w21   = (const float*)d_in[6];
    const float* b21   = (const float*)d_in[7];
    const float* w22   = (const float*)d_in[8];
    const float* b22   = (const float*)d_in[9];
    const float* fc3_w = (const float*)d_in[10];
    const float* fc3_b = (const float*)d_in[11];
    const float* dw0   = (const float*)d_in[12];
    const float* dw1   = (const float*)d_in[13];
    const float* dw2   = (const float*)d_in[14];

    float* out = (float*)d_out;
    char*  ws  = (char*)d_ws;
    __hip_bfloat16* h_bf = (__hip_bfloat16*)ws;                       // 8192*800 bf16
    __hip_bfloat16* h1b  = (__hip_bfloat16*)(ws + (size_t)BATCH * KP * 2);  // 8192*416 bf16
    float* T    = (float*)(ws + (size_t)BATCH * KP * 2 + (size_t)BATCH * KP2 * 2);
    float* WF4  = T + 10 * 3 * 784;
    __hip_bfloat16* w_bf  = (__hip_bfloat16*)(WF4 + 576);             // 400*800
    __hip_bfloat16* w2bf  = w_bf + 400 * KP;                          // 48*416
    float* w1p  = (float*)(w2bf + 48 * KP2);                          // 36 floats
    float* dw2p = w1p + 36;                                           // 36 floats
    float* dw0p = dw2p + 36;                                          // 216 floats

    precompute_kernel<<<59, 256, 0, stream>>>(w0, w1, dw0, dw1, dw2, fc1_w,
                                              w21, w22, T, WF4, w1p, dw2p,
                                              dw0p, w_bf, w2bf);
    encoder_kernel<<<BATCH, 256, 0, stream>>>(x, cls, w0, w1p, T, h_bf);
    fc1_mfma<<<dim3(64, 5), 256, 0, stream>>>((const ushort*)h_bf,
                                              (const ushort*)w_bf, fc1_b, h1b);
    fc2_mfma<<<64, 256, 0, stream>>>((const ushort*)h1b, (const ushort*)w2bf,
                                     b21, b22, out);
    decoder_kernel<<<BATCH, 256, 0, stream>>>(cls, fc3_w, fc3_b, dw0p, dw2p,
                                              WF4, out);
}

// Round 16
// 127.919 us; speedup vs baseline: 6.0134x; 1.0468x over previous
//
#include <hip/hip_runtime.h>
#include <hip/hip_bf16.h>
#include <math.h>

#define BATCH 8192
#define IMG 784   // 28*28
#define KP 800    // fc1 K padded to multiple of 32
#define KP2 416   // fc2 K padded (400 -> 416)

typedef short  bf16x8 __attribute__((ext_vector_type(8)));
typedef float  f32x4  __attribute__((ext_vector_type(4)));
typedef float  f32x2  __attribute__((ext_vector_type(2)));

// ---------------------------------------------------------------------------
// K0: precompute (a) per-class conv0 one-hot tables T[10][3][784],
// (b) parity-folded deconv1 weights WF4 + packed w1p/dw2p/dw0p,
// (c) fc1_w -> bf16 [400][800], (d) fc2 weights -> bf16 [48][416].
// ---------------------------------------------------------------------------
__global__ __launch_bounds__(256) void precompute_kernel(
    const float* __restrict__ w0,    // [3,11,3,3]
    const float* __restrict__ w1,    // [1,3,3,3]
    const float* __restrict__ dw0,   // [11,2,3,3]
    const float* __restrict__ dw1,   // [3,11,3,3]
    const float* __restrict__ dw2,   // [1,3,3,3]
    const float* __restrict__ fc1w,  // [400,784]
    const float* __restrict__ w21,   // [20,400]
    const float* __restrict__ w22,   // [20,400]
    float* __restrict__ T,           // [10,3,784]
    float* __restrict__ WF4,         // 576 floats
    float* __restrict__ w1p,         // [9]*4 floats
    float* __restrict__ dw2p,        // [9]*4 floats
    float* __restrict__ dw0p,        // [2*9*3]*4 = 216 floats
    __hip_bfloat16* __restrict__ wbf,  // [400,800]
    __hip_bfloat16* __restrict__ w2bf) // [48,416]
{
    const int blk = blockIdx.x, tid = threadIdx.x;
    if (blk < 10) {
        const int t = blk;
        for (int idx = tid; idx < 3 * 784; idx += 256) {
            int o = idx / 784, pix = idx % 784;
            int r = pix / 28, c = pix % 28;
            float acc = 0.f;
#pragma unroll
            for (int dr = 0; dr < 3; ++dr)
#pragma unroll
                for (int dc = 0; dc < 3; ++dc) {
                    int rr = r + dr - 1, cc = c + dc - 1;
                    if (rr < 0 || rr > 27 || cc < 0 || cc > 27) continue;
                    int s = rr * 28 + cc;
                    int i = ((4 * (t + 1 - s)) % 11 + 11) % 11;
                    acc += w0[(o * 11 + i) * 9 + dr * 3 + dc];
                }
            T[(t * 3 + o) * 784 + pix] = acc;
        }
    } else if (blk == 10) {
        // WF4 flat idx = (((par*3+o)*4+uv)*3+cb)*4+j ; channel = 4*cb+j
        for (int idx = tid; idx < 576; idx += 256) {
            int j = idx & 3;
            int rest = idx >> 2;
            int cb = rest % 3;
            int rest2 = rest / 3;
            int uv = rest2 % 4;
            int rest3 = rest2 / 4;
            int o = rest3 % 3;
            int par = rest3 / 3;
            int ch = cb * 4 + j;
            float acc = 0.f;
            if (ch < 11) {
                int u = uv >> 1, v = uv & 1;
                int pr = par >> 1, pc = par & 1;
                for (int dr = 0; dr < 3; ++dr) {
                    bool rin = (pr == 0) ? (u == 0 ? dr == 0 : dr >= 1)
                                         : (u == 0 ? dr <= 1 : dr == 2);
                    if (!rin) continue;
                    for (int dc = 0; dc < 3; ++dc) {
                        bool cin = (pc == 0) ? (v == 0 ? dc == 0 : dc >= 1)
                                             : (v == 0 ? dc <= 1 : dc == 2);
                        if (cin) acc += dw1[(o * 11 + ch) * 9 + dr * 3 + dc];
                    }
                }
            }
            WF4[idx] = acc;
        }
        // per-tap packed conv1 / deconv2 weights: {w[t], w[9+t], w[18+t], 0}
        if (tid < 9) {
            w1p[tid * 4 + 0] = w1[tid];
            w1p[tid * 4 + 1] = w1[9 + tid];
            w1p[tid * 4 + 2] = w1[18 + tid];
            w1p[tid * 4 + 3] = 0.f;
        } else if (tid < 18) {
            int t = tid - 9;
            dw2p[t * 4 + 0] = dw2[t];
            dw2p[t * 4 + 1] = dw2[9 + t];
            dw2p[t * 4 + 2] = dw2[18 + t];
            dw2p[t * 4 + 3] = 0.f;
        }
        // deconv0 weights channel-minor: dw0p[(i*9+tap)*12 + ch]
        if (tid >= 32 && tid < 248) {
            int idx = tid - 32;            // 0..215
            int j  = idx & 3;
            int cb = (idx >> 2) % 3;
            int t2 = (idx >> 2) / 3;       // i*9 + tap, 0..17
            int i  = t2 / 9, tap = t2 % 9;
            int ch = cb * 4 + j;
            dw0p[t2 * 12 + cb * 4 + j] =
                (ch < 11) ? dw0[(ch * 2 + i) * 9 + tap] : 0.f;
        }
    } else if (blk < 51) {
        // fc1_w fp32 [400,784] -> bf16 [400,800] (cols 784..799 zero)
        const int base = (blk - 11) * 8000;
        for (int i = tid; i < 8000; i += 256) {
            int flat = base + i;
            int n = flat / KP, k = flat % KP;
            float v = (k < 784) ? fc1w[n * 784 + k] : 0.f;
            wbf[flat] = __float2bfloat16(v);
        }
    } else {
        // fc2 weights -> bf16 [48,416]: rows 0-19 w21, 20-39 w22, 40-47 zero
        const int base = (blk - 51) * 2496;
        for (int i = tid; i < 2496; i += 256) {
            int flat = base + i;
            int j = flat / KP2, k = flat % KP2;
            float v = 0.f;
            if (k < 400) {
                if (j < 20)      v = w21[j * 400 + k];
                else if (j < 40) v = w22[(j - 20) * 400 + k];
            }
            w2bf[flat] = __float2bfloat16(v);
        }
    }
}

// ---------------------------------------------------------------------------
// K1: encoder — sparse-x conv0 + conv1, both with VERTICAL 2-PIXEL PAIRING
// (shared 4x3 window: 12 reads / 2 pixels; 2 loop iterations not 4).
// writes h as bf16 [B][800]
// ---------------------------------------------------------------------------
__global__ __launch_bounds__(256, 4) void encoder_kernel(
    const float* __restrict__ x, const int* __restrict__ cls,
    const float* __restrict__ w0,    // [3,11,3,3]
    const float* __restrict__ w1p,   // [9] float4 packed
    const float* __restrict__ T,     // [10,3,784]
    __hip_bfloat16* __restrict__ h_bf)  // [B,800]
{
    __shared__ float  xs[30 * 30];      // scattered x image, zero border
    __shared__ float4 hs0[30 * 30];     // conv0 out (3ch + pad), zero border
    __shared__ float4 wt2[99];          // [cls 0..10][tap 0..8] pre-permuted

    const int b = blockIdx.x, tid = threadIdx.x;
    const int myc = cls[b];

    for (int i = tid; i < 116; i += 256) {
        int r, c;
        if (i < 30)      { r = 0;  c = i; }
        else if (i < 60) { r = 29; c = i - 30; }
        else if (i < 88) { r = 1 + (i - 60); c = 0; }
        else             { r = 1 + (i - 88); c = 29; }
        xs[r * 30 + c] = 0.f;
        hs0[r * 30 + c] = make_float4(0.f, 0.f, 0.f, 0.f);
    }
    // wt2[cls*9+tap] = w0[:, (cls + kk(tap)) % 11, tap]
    for (int i = tid; i < 99; i += 256) {
        int cl = i / 9, tap = i % 9;
        int kk = (9 * (tap / 3) + 7 * (tap % 3)) % 11;
        int ch = cl + kk;
        if (ch >= 11) ch -= 11;
        wt2[i] = make_float4(w0[ch * 9 + tap], w0[(11 + ch) * 9 + tap],
                             w0[(22 + ch) * 9 + tap], 0.f);
    }
    for (int s = tid; s < 784; s += 256) {
        int ch = (7 * s) % 11;
        int p = (ch * 784 + s) / 11;
        xs[(s / 28 + 1) * 30 + s % 28 + 1] = x[(size_t)b * IMG + p];
    }
    if (tid < 16) h_bf[(size_t)b * KP + 784 + tid] = __float2bfloat16(0.f);
    __syncthreads();

    const float* Tc = T + myc * 2352;
    // conv0: vertical pairs (r0, c), (r0+1, c); r0 even
    for (int pi = tid; pi < 392; pi += 256) {
        int rp = pi / 28, c = pi % 28;
        int r0 = rp * 2;
        float w[4][3];
#pragma unroll
        for (int i = 0; i < 4; ++i)
#pragma unroll
            for (int j = 0; j < 3; ++j)
                w[i][j] = xs[(r0 + i) * 30 + c + j];
        int pixA = r0 * 28 + c;
        f32x4 A = {Tc[pixA], Tc[784 + pixA], Tc[1568 + pixA], 0.f};
        f32x4 Bq = {Tc[pixA + 28], Tc[812 + pixA], Tc[1596 + pixA], 0.f};
        int clA = (9 * r0 + 7 * c + 6) % 11;
        int clB = clA + 9; if (clB >= 11) clB -= 11;
        const f32x4* wrA = (const f32x4*)&wt2[clA * 9];
        const f32x4* wrB = (const f32x4*)&wt2[clB * 9];
#pragma unroll
        for (int dr = 0; dr < 3; ++dr)
#pragma unroll
            for (int dc = 0; dc < 3; ++dc) {
                int tap = dr * 3 + dc;
                float va = w[dr][dc], vb = w[dr + 1][dc];
                f32x4 vva = {va, va, va, va};
                f32x4 vvb = {vb, vb, vb, vb};
                A  = __builtin_elementwise_fma(vva, wrA[tap], A);
                Bq = __builtin_elementwise_fma(vvb, wrB[tap], Bq);
            }
        hs0[(r0 + 1) * 30 + c + 1] =
            make_float4(fmaxf(A.x, 0.f), fmaxf(A.y, 0.f), fmaxf(A.z, 0.f), 0.f);
        hs0[(r0 + 2) * 30 + c + 1] =
            make_float4(fmaxf(Bq.x, 0.f), fmaxf(Bq.y, 0.f), fmaxf(Bq.z, 0.f), 0.f);
    }
    __syncthreads();

    // conv1: vertical pairs, pixel-independent packed weights
    const f32x4* w1v = (const f32x4*)w1p;
    for (int pi = tid; pi < 392; pi += 256) {
        int rp = pi / 28, c = pi % 28;
        int r0 = rp * 2;
        f32x4 A = {0.f, 0.f, 0.f, 0.f};
        f32x4 Bq = {0.f, 0.f, 0.f, 0.f};
#pragma unroll
        for (int dr = 0; dr < 4; ++dr)
#pragma unroll
            for (int dc = 0; dc < 3; ++dc) {
                f32x4 v = *(const f32x4*)&hs0[(r0 + dr) * 30 + c + dc];
                if (dr < 3)
                    A = __builtin_elementwise_fma(v, w1v[dr * 3 + dc], A);
                if (dr > 0)
                    Bq = __builtin_elementwise_fma(v, w1v[(dr - 1) * 3 + dc], Bq);
            }
        float a = A.x + A.y + A.z;
        float bv = Bq.x + Bq.y + Bq.z;
        h_bf[(size_t)b * KP + r0 * 28 + c] = __float2bfloat16(fmaxf(a, 0.f));
        h_bf[(size_t)b * KP + (r0 + 1) * 28 + c] = __float2bfloat16(fmaxf(bv, 0.f));
    }
}

// ---------------------------------------------------------------------------
// K2: fc1 via bf16 MFMA.  h1b[8192,416] = bf16(relu(h @ w^T + b))
// ---------------------------------------------------------------------------
__global__ __launch_bounds__(256) void fc1_mfma(
    const ushort* __restrict__ h_bf,  // [8192,800] bf16
    const ushort* __restrict__ w_bf,  // [400,800] bf16
    const float* __restrict__ bias,   // [400]
    __hip_bfloat16* __restrict__ h1b) // [8192,416] bf16
{
    __shared__ ushort Bs[80][40];   // B tile [n][k], stride 40 (pad)

    const int tid  = threadIdx.x;
    const int wid  = tid >> 6;
    const int lane = tid & 63;
    const int l15  = lane & 15;
    const int lq   = lane >> 4;       // k-quadrant 0..3
    const int bm   = blockIdx.x * 128;
    const int bn   = blockIdx.y * 80;

    f32x4 acc[2][5] = {};

    const int n0 = tid >> 2;          // 0..63  (staging row)
    const int kq0 = tid & 3;          // staging k-quadrant

    for (int k0 = 0; k0 < KP; k0 += 32) {
        bf16x8 s0 = *(const bf16x8*)&w_bf[(size_t)(bn + n0) * KP + k0 + kq0 * 8];
        bf16x8 s1;
        if (tid < 64)
            s1 = *(const bf16x8*)&w_bf[(size_t)(bn + 64 + n0) * KP + k0 + kq0 * 8];
        bf16x8 a0 = *(const bf16x8*)&h_bf[(size_t)(bm + wid * 32 + l15) * KP + k0 + lq * 8];
        bf16x8 a1 = *(const bf16x8*)&h_bf[(size_t)(bm + wid * 32 + 16 + l15) * KP + k0 + lq * 8];
        __syncthreads();
        *(bf16x8*)&Bs[n0][kq0 * 8] = s0;
        if (tid < 64) *(bf16x8*)&Bs[64 + n0][kq0 * 8] = s1;
        __syncthreads();
#pragma unroll
        for (int nf = 0; nf < 5; ++nf) {
            bf16x8 bfr = *(const bf16x8*)&Bs[nf * 16 + l15][lq * 8];
            acc[0][nf] = __builtin_amdgcn_mfma_f32_16x16x32_bf16(a0, bfr, acc[0][nf], 0, 0, 0);
            acc[1][nf] = __builtin_amdgcn_mfma_f32_16x16x32_bf16(a1, bfr, acc[1][nf], 0, 0, 0);
        }
    }

#pragma unroll
    for (int nf = 0; nf < 5; ++nf) {
        int col = bn + nf * 16 + l15;
        float bv = bias[col];
#pragma unroll
        for (int mr = 0; mr < 2; ++mr)
#pragma unroll
            for (int v = 0; v < 4; ++v) {
                int row = bm + wid * 32 + mr * 16 + lq * 4 + v;
                h1b[(size_t)row * KP2 + col] =
                    __float2bfloat16(fmaxf(acc[mr][nf][v] + bv, 0.f));
            }
    }
    if (blockIdx.y == 4) {
#pragma unroll
        for (int mr = 0; mr < 2; ++mr)
#pragma unroll
            for (int v = 0; v < 4; ++v) {
                int row = bm + wid * 32 + mr * 16 + lq * 4 + v;
                h1b[(size_t)row * KP2 + 400 + l15] = __float2bfloat16(0.f);
            }
    }
}

// ---------------------------------------------------------------------------
// K3: fc21 + fc22 via bf16 MFMA, no LDS.
// ---------------------------------------------------------------------------
__global__ __launch_bounds__(256) void fc2_mfma(
    const ushort* __restrict__ h1b,   // [8192,416] bf16
    const ushort* __restrict__ w2bf,  // [48,416] bf16
    const float* __restrict__ b21, const float* __restrict__ b22,
    float* __restrict__ out)
{
    const int tid  = threadIdx.x;
    const int wid  = tid >> 6;
    const int lane = tid & 63;
    const int l15  = lane & 15;
    const int lq   = lane >> 4;
    const int bm   = blockIdx.x * 128;

    f32x4 acc[2][3] = {};

    for (int k0 = 0; k0 < KP2; k0 += 32) {
        bf16x8 a0 = *(const bf16x8*)&h1b[(size_t)(bm + wid * 32 + l15) * KP2 + k0 + lq * 8];
        bf16x8 a1 = *(const bf16x8*)&h1b[(size_t)(bm + wid * 32 + 16 + l15) * KP2 + k0 + lq * 8];
#pragma unroll
        for (int nf = 0; nf < 3; ++nf) {
            bf16x8 bfr = *(const bf16x8*)&w2bf[(size_t)(nf * 16 + l15) * KP2 + k0 + lq * 8];
            acc[0][nf] = __builtin_amdgcn_mfma_f32_16x16x32_bf16(a0, bfr, acc[0][nf], 0, 0, 0);
            acc[1][nf] = __builtin_amdgcn_mfma_f32_16x16x32_bf16(a1, bfr, acc[1][nf], 0, 0, 0);
        }
    }

    const size_t base = (size_t)BATCH * IMG;
#pragma unroll
    for (int nf = 0; nf < 3; ++nf) {
        int col = nf * 16 + l15;
        if (col < 40) {
            bool is_mu = (col < 20);
            int ccol = is_mu ? col : col - 20;
            float bv = is_mu ? b21[ccol] : b22[ccol];
            size_t obase = is_mu ? base : base + (size_t)BATCH * 20;
#pragma unroll
            for (int mr = 0; mr < 2; ++mr)
#pragma unroll
                for (int v = 0; v < 4; ++v) {
                    int row = bm + wid * 32 + mr * 16 + lq * 4 + v;
                    out[obase + (size_t)row * 20 + ccol] = acc[mr][nf][v] + bv;
                }
        }
    }
}

// ---------------------------------------------------------------------------
// K4: decoder — fc3 + PAIRED deconv0 + wave-parity deconv1 (plain d0sp
// layout) + PAIRED deconv2 (+__expf sigmoid).  d0in aliased onto d1s.
// ---------------------------------------------------------------------------
__global__ __launch_bounds__(256, 8) void decoder_kernel(
    const int* __restrict__ cls,
    const float* __restrict__ fc3_w,  // [392,30]
    const float* __restrict__ fc3_b,  // [392]
    const float* __restrict__ dw0p,   // 216 floats (packed deconv0 weights)
    const float* __restrict__ dw2p,   // [9] float4 packed
    const float* __restrict__ WF4g,   // 576 floats
    float* __restrict__ out)
{
    __shared__ float  z[32];
    __shared__ float4 d0sp[3][16 * 16];    // per-cblk planes, plain layout
    __shared__ float4 d1s[30 * 30];        // [30][30]; also hosts d0in early
    float* d0inS = (float*)d1s;

    const int b = blockIdx.x;
    const int tid = threadIdx.x;
    const int myc = cls[b];
    const float* mu = out + (size_t)BATCH * IMG + (size_t)b * 20;

    for (int i = tid; i < 2 * 16 * 17; i += 256) d0inS[i] = 0.f;
    for (int i = tid; i < 60; i += 256) {
        int r, c;
        if (i < 16)      { r = 0;  c = i; }
        else if (i < 32) { r = 15; c = i - 16; }
        else if (i < 46) { r = 1 + (i - 32); c = 0; }
        else             { r = 1 + (i - 46); c = 15; }
        int p = r * 16 + c;
        d0sp[0][p] = d0sp[1][p] = d0sp[2][p] = make_float4(0.f, 0.f, 0.f, 0.f);
    }
    if (tid < 20) z[tid] = mu[tid];
    else if (tid < 30) z[tid] = (tid - 20 == myc) ? 1.f : 0.f;
    __syncthreads();

    // fc3: [30] -> [392] + relu -> d0in [2][16][17] padded
    for (int j = tid; j < 392; j += 256) {
        float acc = fc3_b[j];
        const float2* wrow = (const float2*)&fc3_w[j * 30];
#pragma unroll
        for (int k = 0; k < 15; ++k) {
            float2 wv = wrow[k];
            acc += z[2 * k] * wv.x + z[2 * k + 1] * wv.y;
        }
        int ch = j / 196, rem = j % 196;
        d0inS[ch * 272 + (rem / 14 + 1) * 17 + (rem % 14 + 1)] = fmaxf(acc, 0.f);
    }
    __syncthreads();

    // deconv0: VERTICAL PAIR per thread (98 threads), shared 4x3x2 window:
    // 24 LDS reads / 2 positions (vs 36). weights wave-uniform -> s_loads.
    if (tid < 98) {
        int rp = tid / 14, c = tid % 14;
        int r0 = rp * 2;
        f32x4 A0[3] = {};
        f32x4 A1[3] = {};
        const f32x4* wps = (const f32x4*)dw0p;
#pragma unroll
        for (int i = 0; i < 2; ++i)
#pragma unroll
            for (int dr = 0; dr < 4; ++dr)
#pragma unroll
                for (int dc = 0; dc < 3; ++dc) {
                    float v = d0inS[i * 272 + (r0 + dr) * 17 + (c + dc)];
                    f32x4 vv = {v, v, v, v};
                    if (dr < 3) {
                        int t = (i * 9 + dr * 3 + dc) * 3;
#pragma unroll
                        for (int cb = 0; cb < 3; ++cb)
                            A0[cb] = __builtin_elementwise_fma(vv, wps[t + cb], A0[cb]);
                    }
                    if (dr > 0) {
                        int t = (i * 9 + (dr - 1) * 3 + dc) * 3;
#pragma unroll
                        for (int cb = 0; cb < 3; ++cb)
                            A1[cb] = __builtin_elementwise_fma(vv, wps[t + cb], A1[cb]);
                    }
                }
        int p0 = (r0 + 1) * 16 + (c + 1);
        int p1 = (r0 + 2) * 16 + (c + 1);
        f32x4 zero = {0.f, 0.f, 0.f, 0.f};
#pragma unroll
        for (int cb = 0; cb < 3; ++cb) {
            f32x4 m0 = __builtin_elementwise_max(A0[cb], zero);
            f32x4 m1 = __builtin_elementwise_max(A1[cb], zero);
            d0sp[cb][p0] = *(float4*)&m0;
            d0sp[cb][p1] = *(float4*)&m1;
        }
    }
    __syncthreads();   // d0in reads done -> d1s region free for reuse

    // d1s border zeroing, same phase as deconv1 (disjoint addresses)
    for (int i = tid; i < 116; i += 256) {
        int r, c;
        if (i < 30)      { r = 0;  c = i; }
        else if (i < 60) { r = 29; c = i - 30; }
        else if (i < 88) { r = 1 + (i - 60); c = 0; }
        else             { r = 1 + (i - 88); c = 29; }
        d1s[r * 30 + c] = make_float4(0.f, 0.f, 0.f, 0.f);
    }

    // deconv1: wave w owns parity w. Vertical q-pair per thread; f32x2
    // packed accumulators; weights via wave-uniform global -> SGPRs.
    {
        const int wid  = tid >> 6;          // parity, wave-uniform
        const int lane = tid & 63;
        const int pr = wid >> 1, pc = wid & 1;
        const f32x4* wgs = (const f32x4*)(WF4g +
            __builtin_amdgcn_readfirstlane(wid) * 144);
#pragma unroll 1
        for (int pp = 0; pp < 2; ++pp) {
            int pi = pp * 64 + lane;
            if (pi < 98) {
                int qpr = pi / 14, qc = pi - qpr * 14;
                int qr0 = qpr * 2;
                int base = (qr0 + pr) * 16 + qc + pc;
                f32x2 A0[3] = {{0.f, 0.f}, {0.f, 0.f}, {0.f, 0.f}};
                f32x2 A1[3] = {{0.f, 0.f}, {0.f, 0.f}, {0.f, 0.f}};
#pragma unroll
                for (int cb = 0; cb < 3; ++cb) {
                    f32x4 v0 = *(const f32x4*)&d0sp[cb][base];
                    f32x4 v1 = *(const f32x4*)&d0sp[cb][base + 1];
                    f32x4 v2 = *(const f32x4*)&d0sp[cb][base + 16];
                    f32x4 v3 = *(const f32x4*)&d0sp[cb][base + 17];
                    f32x4 v4 = *(const f32x4*)&d0sp[cb][base + 32];
                    f32x4 v5 = *(const f32x4*)&d0sp[cb][base + 33];
#pragma unroll
                    for (int o = 0; o < 3; ++o) {
                        f32x4 w00 = wgs[(o * 4 + 0) * 3 + cb];
                        f32x4 w01 = wgs[(o * 4 + 1) * 3 + cb];
                        f32x4 w10 = wgs[(o * 4 + 2) * 3 + cb];
                        f32x4 w11 = wgs[(o * 4 + 3) * 3 + cb];
                        A0[o] = __builtin_elementwise_fma(v0.lo, w00.lo, A0[o]);
                        A0[o] = __builtin_elementwise_fma(v0.hi, w00.hi, A0[o]);
                        A0[o] = __builtin_elementwise_fma(v1.lo, w01.lo, A0[o]);
                        A0[o] = __builtin_elementwise_fma(v1.hi, w01.hi, A0[o]);
                        A0[o] = __builtin_elementwise_fma(v2.lo, w10.lo, A0[o]);
                        A0[o] = __builtin_elementwise_fma(v2.hi, w10.hi, A0[o]);
                        A0[o] = __builtin_elementwise_fma(v3.lo, w11.lo, A0[o]);
                        A0[o] = __builtin_elementwise_fma(v3.hi, w11.hi, A0[o]);
                        A1[o] = __builtin_elementwise_fma(v2.lo, w00.lo, A1[o]);
                        A1[o] = __builtin_elementwise_fma(v2.hi, w00.hi, A1[o]);
                        A1[o] = __builtin_elementwise_fma(v3.lo, w01.lo, A1[o]);
                        A1[o] = __builtin_elementwise_fma(v3.hi, w01.hi, A1[o]);
                        A1[o] = __builtin_elementwise_fma(v4.lo, w10.lo, A1[o]);
                        A1[o] = __builtin_elementwise_fma(v4.hi, w10.hi, A1[o]);
                        A1[o] = __builtin_elementwise_fma(v5.lo, w11.lo, A1[o]);
                        A1[o] = __builtin_elementwise_fma(v5.hi, w11.hi, A1[o]);
                    }
                }
                int r0 = 2 * qr0 + pr, c = 2 * qc + pc;
                d1s[(r0 + 1) * 30 + c + 1] =
                    make_float4(fmaxf(A0[0].x + A0[0].y, 0.f),
                                fmaxf(A0[1].x + A0[1].y, 0.f),
                                fmaxf(A0[2].x + A0[2].y, 0.f), 0.f);
                d1s[(r0 + 3) * 30 + c + 1] =
                    make_float4(fmaxf(A1[0].x + A1[0].y, 0.f),
                                fmaxf(A1[1].x + A1[1].y, 0.f),
                                fmaxf(A1[2].x + A1[2].y, 0.f), 0.f);
            }
        }
    }
    __syncthreads();

    // deconv2: VERTICAL PAIR per thread (392 pairs), shared 4x3 window
    // (12 b128 reads / 2 pixels vs 18) + fast sigmoid
    const f32x4* dw2v = (const f32x4*)dw2p;
    for (int pi = tid; pi < 392; pi += 256) {
        int rp = pi / 28, c = pi % 28;
        int r0 = rp * 2;
        f32x4 A = {0.f, 0.f, 0.f, 0.f};
        f32x4 Bq = {0.f, 0.f, 0.f, 0.f};
#pragma unroll
        for (int dr = 0; dr < 4; ++dr)
#pragma unroll
            for (int dc = 0; dc < 3; ++dc) {
                f32x4 v = *(const f32x4*)&d1s[(r0 + dr) * 30 + c + dc];
                if (dr < 3)
                    A = __builtin_elementwise_fma(v, dw2v[dr * 3 + dc], A);
                if (dr > 0)
                    Bq = __builtin_elementwise_fma(v, dw2v[(dr - 1) * 3 + dc], Bq);
            }
        float a = A.x + A.y + A.z;
        float bv = Bq.x + Bq.y + Bq.z;
        out[(size_t)b * IMG + r0 * 28 + c] = 1.f / (1.f + __expf(-a));
        out[(size_t)b * IMG + (r0 + 1) * 28 + c] = 1.f / (1.f + __expf(-bv));
    }
}

// ---------------------------------------------------------------------------
extern "C" void kernel_launch(void* const* d_in, const int* in_sizes, int n_in,
                              void* d_out, int out_size, void* d_ws, size_t ws_size,
                              hipStream_t stream) {
    const float* x     = (const float*)d_in[0];
    const int*   cls   = (const int*)d_in[1];
    const float* w0    = (const float*)d_in[2];
    const float* w1    = (const float*)d_in[3];
    const float* fc1_w = (const float*)d_in[4];
    const float* fc1_b = (const float*)d_in[5];
    const float* w21   = (const float*)d_in[6];
    const float* b21   = (const float*)d_in[7];
    const float* w22   = (const float*)d_in[8];
    const float* b22   = (const float*)d_in[9];
    const float* fc3_w = (const float*)d_in[10];
    const float* fc3_b = (const float*)d_in[11];
    const float* dw0   = (const float*)d_in[12];
    const float* dw1   = (const float*)d_in[13];
    const float* dw2   = (const float*)d_in[14];

    float* out = (float*)d_out;
    char*  ws  = (char*)d_ws;
    __hip_bfloat16* h_bf = (__hip_bfloat16*)ws;                       // 8192*800 bf16
    __hip_bfloat16* h1b  = (__hip_bfloat16*)(ws + (size_t)BATCH * KP * 2);  // 8192*416 bf16
    float* T    = (float*)(ws + (size_t)BATCH * KP * 2 + (size_t)BATCH * KP2 * 2);
    float* WF4  = T + 10 * 3 * 784;
    __hip_bfloat16* w_bf  = (__hip_bfloat16*)(WF4 + 576);             // 400*800
    __hip_bfloat16* w2bf  = w_bf + 400 * KP;                          // 48*416
    float* w1p  = (float*)(w2bf + 48 * KP2);                          // 36 floats
    float* dw2p = w1p + 36;                                           // 36 floats
    float* dw0p = dw2p + 36;                                          // 216 floats

    precompute_kernel<<<59, 256, 0, stream>>>(w0, w1, dw0, dw1, dw2, fc1_w,
                                              w21, w22, T, WF4, w1p, dw2p,
                                              dw0p, w_bf, w2bf);
    encoder_kernel<<<BATCH, 256, 0, stream>>>(x, cls, w0, w1p, T, h_bf);
    fc1_mfma<<<dim3(64, 5), 256, 0, stream>>>((const ushort*)h_bf,
                                              (const ushort*)w_bf, fc1_b, h1b);
    fc2_mfma<<<64, 256, 0, stream>>>((const ushort*)h1b, (const ushort*)w2bf,
                                     b21, b22, out);
    decoder_kernel<<<BATCH, 256, 0, stream>>>(cls, fc3_w, fc3_b, dw0p, dw2p,
                                              WF4, out);
}